// Round 3
// baseline (3659.523 us; speedup 1.0000x reference)
//
#include <hip/hip_runtime.h>
#include <math.h>
#include <stdint.h>

typedef __attribute__((ext_vector_type(8))) short    bf16x8;
typedef __attribute__((ext_vector_type(4))) float    f32x4;
typedef __attribute__((ext_vector_type(8))) uint16_t u16x8;

#define LSTR 40   // LDS row stride (bf16 elems) for MFMA tiles: 80B rows -> 2-way banks (free)

__device__ __forceinline__ uint16_t f2bf(float f) {
    union { float f; uint32_t u; } v; v.f = f;
    uint32_t r = v.u + 0x7FFFu + ((v.u >> 16) & 1u);
    return (uint16_t)(r >> 16);
}

__device__ __forceinline__ float sigm(float x) { return 1.f / (1.f + expf(-x)); }

// ---------------------------------------------------------------------------
// prep: f_t (fp32 flat NCHW) -> bf16 flat (fc1 A rows 256..511)
// ---------------------------------------------------------------------------
__global__ __launch_bounds__(256) void cvt_flat_kernel(
    const float* __restrict__ src, uint16_t* __restrict__ dst, int n)
{
    int i = (blockIdx.x * 256 + threadIdx.x) * 8;
    if (i >= n) return;
    float4 a = *(const float4*)(src + i);
    float4 b = *(const float4*)(src + i + 4);
    u16x8 o;
    o[0] = f2bf(a.x); o[1] = f2bf(a.y); o[2] = f2bf(a.z); o[3] = f2bf(a.w);
    o[4] = f2bf(b.x); o[5] = f2bf(b.y); o[6] = f2bf(b.z); o[7] = f2bf(b.w);
    *(u16x8*)(dst + i) = o;
}

// ---------------------------------------------------------------------------
// prep: concat(f_t, f_t_1) NCHW fp32 -> NHWC bf16 [bt][y][x][128]
// ---------------------------------------------------------------------------
__global__ __launch_bounds__(256) void nhwc_kernel(
    const float* __restrict__ f_t, const float* __restrict__ f_t_1,
    uint16_t* __restrict__ dst)
{
    __shared__ float lds[32][258];
    const int bt  = blockIdx.y;
    const int c0  = (blockIdx.x >> 2) * 32;
    const int px0 = (blockIdx.x & 3) * 256;
    const int t   = threadIdx.x;

    const int lc  = t & 31;
    const int lpx = (t >> 5) * 32;
    const int c   = c0 + lc;
    const float* src = (c < 64)
        ? (f_t   + ((size_t)bt * 64 + c) * 1024)
        : (f_t_1 + ((size_t)bt * 64 + (c - 64)) * 1024);
#pragma unroll
    for (int j = 0; j < 32; j += 4) {
        float4 v = *(const float4*)(src + px0 + lpx + j);
        lds[lc][lpx + j + 0] = v.x;
        lds[lc][lpx + j + 1] = v.y;
        lds[lc][lpx + j + 2] = v.z;
        lds[lc][lpx + j + 3] = v.w;
    }
    __syncthreads();
    uint16_t* op = dst + ((size_t)bt * 1024 + px0 + t) * 128 + c0;
#pragma unroll
    for (int u0 = 0; u0 < 32; u0 += 8) {
        u16x8 o;
#pragma unroll
        for (int u = 0; u < 8; ++u) o[u] = f2bf(lds[u0 + u][t]);
        *(u16x8*)(op + u0) = o;
    }
}

// ---------------------------------------------------------------------------
// prep: conv weights -> packed bf16 [oc][(ky*3+kx)*IC + c]
// ---------------------------------------------------------------------------
__global__ __launch_bounds__(256) void wpack_kernel(
    const float* __restrict__ w1, const float* __restrict__ w2,
    uint16_t* __restrict__ p1, uint16_t* __restrict__ p2)
{
    int i = blockIdx.x * 256 + threadIdx.x;
    if (i < 64 * 1152) {
        int oc = i / 1152, k = i - oc * 1152;
        int s = k >> 7, c = k & 127;
        int ky = s / 3, kx = s - ky * 3;
        p1[i] = f2bf(w1[((oc * 128 + c) * 3 + ky) * 3 + kx]);
    }
    if (i < 64 * 576) {
        int oc = i / 576, k = i - oc * 576;
        int s = k >> 6, c = k & 63;
        int ky = s / 3, kx = s - ky * 3;
        p2[i] = f2bf(w2[((oc * 64 + c) * 3 + ky) * 3 + kx]);
    }
}

// ---------------------------------------------------------------------------
// conv3x3 + bias + relu as implicit-GEMM MFMA (pad-40 LDS rows).
// ---------------------------------------------------------------------------
template<int IC, bool SWAP>
__global__ __launch_bounds__(256) void conv_mfma_kernel(
    const uint16_t* __restrict__ in_nhwc,
    const uint16_t* __restrict__ wpack,
    const float* __restrict__ bias,
    uint16_t* __restrict__ out)
{
    constexpr int KT  = 9 * IC;
    constexpr int CPS = IC / 32;
    constexpr int MF  = SWAP ? 4 : 2;
    constexpr int NF  = SWAP ? 2 : 4;

    __shared__ __align__(16) uint16_t Apx[128 * LSTR];
    __shared__ __align__(16) uint16_t Bw[64 * LSTR];

    const int bt  = blockIdx.y;
    const int px0 = blockIdx.x * 128;
    const int t   = threadIdx.x;
    const int w   = t >> 6, l = t & 63;

    const int m = t >> 1, chalf = (t & 1) * 16;
    const int y = (px0 + m) >> 5, x = m & 31;
    const int oc_s = t >> 2, kslot = t & 3;

    f32x4 acc[MF][NF] = {};

    for (int q = 0; q < 9 * CPS; ++q) {
        const int s  = q / CPS, cc = (q - s * CPS) * 32;
        const int ky = s / 3,  kx = s - ky * 3;
        const int yy = y + ky - 1, xx = x + kx - 1;
        const bool ok = (yy >= 0) & (yy < 32) & (xx >= 0) & (xx < 32);
        u16x8 a0 = {}, a1 = {};
        if (ok) {
            const uint16_t* sp = in_nhwc
                + (((size_t)bt * 1024) + yy * 32 + xx) * IC + cc + chalf;
            a0 = *(const u16x8*)sp;
            a1 = *(const u16x8*)(sp + 8);
        }
        u16x8 b0 = *(const u16x8*)(wpack + (size_t)oc_s * KT + q * 32 + kslot * 8);

        __syncthreads();
        *(u16x8*)(Apx + m * LSTR + chalf)      = a0;
        *(u16x8*)(Apx + m * LSTR + chalf + 8)  = a1;
        *(u16x8*)(Bw + oc_s * LSTR + kslot * 8) = b0;
        __syncthreads();

        const int row = l & 15, kg = (l >> 4) * 8;
        if (!SWAP) {
            bf16x8 af[2], bf[4];
#pragma unroll
            for (int i = 0; i < 2; ++i)
                af[i] = *(const bf16x8*)(Apx + (w * 32 + i * 16 + row) * LSTR + kg);
#pragma unroll
            for (int j = 0; j < 4; ++j)
                bf[j] = *(const bf16x8*)(Bw + (j * 16 + row) * LSTR + kg);
#pragma unroll
            for (int i = 0; i < MF; ++i)
#pragma unroll
                for (int j = 0; j < NF; ++j)
                    acc[i][j] = __builtin_amdgcn_mfma_f32_16x16x32_bf16(
                        af[i], bf[j], acc[i][j], 0, 0, 0);
        } else {
            bf16x8 af[4], bf[2];
#pragma unroll
            for (int i = 0; i < 4; ++i)
                af[i] = *(const bf16x8*)(Bw + (i * 16 + row) * LSTR + kg);
#pragma unroll
            for (int j = 0; j < 2; ++j)
                bf[j] = *(const bf16x8*)(Apx + (w * 32 + j * 16 + row) * LSTR + kg);
#pragma unroll
            for (int i = 0; i < MF; ++i)
#pragma unroll
                for (int j = 0; j < NF; ++j)
                    acc[i][j] = __builtin_amdgcn_mfma_f32_16x16x32_bf16(
                        af[i], bf[j], acc[i][j], 0, 0, 0);
        }
    }

    const int col = l & 15, rg = (l >> 4) * 4;
    if (!SWAP) {
#pragma unroll
        for (int i = 0; i < 2; ++i)
#pragma unroll
            for (int j = 0; j < 4; ++j) {
                const int ocb = j * 16 + col;
                const float bv = bias[ocb];
#pragma unroll
                for (int r = 0; r < 4; ++r) {
                    const int px = px0 + w * 32 + i * 16 + rg + r;
                    float v = acc[i][j][r] + bv; v = v > 0.f ? v : 0.f;
                    out[((size_t)bt * 1024 + px) * 64 + ocb] = f2bf(v);
                }
            }
    } else {
#pragma unroll
        for (int i = 0; i < 4; ++i)
#pragma unroll
            for (int j = 0; j < 2; ++j)
#pragma unroll
                for (int r = 0; r < 4; ++r) {
                    const int oc = i * 16 + rg + r;
                    const int px = px0 + w * 32 + j * 16 + col;
                    float v = acc[i][j][r] + bias[oc]; v = v > 0.f ? v : 0.f;
                    out[((size_t)bt * 64 + oc) * 1024 + px] = f2bf(v);
                }
    }
}

// ---------------------------------------------------------------------------
// fc1 MFMA split-K=16, 1D grid (512) with XCD-chunked swizzle, pad-40 LDS.
// ---------------------------------------------------------------------------
__global__ __launch_bounds__(256) void fc1_mfma_kernel(
    const uint16_t* __restrict__ Am, const uint16_t* __restrict__ Af,
    const float* __restrict__ Wf, float* __restrict__ part)
{
    __shared__ __align__(16) uint16_t Aa[128 * LSTR];
    __shared__ __align__(16) uint16_t Bb[128 * LSTR];

    // swizzle: 64 consecutive virtual ids per XCD (512 blocks, %8==0 -> bijective)
    const int id  = blockIdx.x;
    const int swz = (id & 7) * 64 + (id >> 3);
    const int bx  = swz & 3;           // row tile (4)
    const int by  = (swz >> 2) & 7;    // col tile (8)
    const int ks  = swz >> 5;          // k split  (16)

    const int row0 = bx * 128;
    const int col0 = by * 128;
    const size_t kbase = (size_t)ks * 4096;
    const uint16_t* Abase = (row0 < 256) ? (Am + (size_t)row0 * 65536)
                                         : (Af + (size_t)(row0 - 256) * 65536);

    const int t = threadIdx.x;
    const int w = t >> 6, l = t & 63;
    const int wr = (w >> 1) * 64, wc = (w & 1) * 64;

    const int srow  = t >> 1;
    const int shalf = (t & 1) * 16;
    const uint16_t* ap = Abase + (size_t)srow * 65536 + kbase + shalf;
    const float*    bp = Wf + (size_t)(col0 + srow) * 65536 + kbase + shalf;
    uint16_t* awr = Aa + srow * LSTR + shalf;
    uint16_t* bwr = Bb + srow * LSTR + shalf;

    f32x4 acc[4][4] = {};

    for (int kk = 0; kk < 4096; kk += 32) {
        u16x8 a0 = *(const u16x8*)(ap + kk);
        u16x8 a1 = *(const u16x8*)(ap + kk + 8);
        float4 f0 = *(const float4*)(bp + kk);
        float4 f1 = *(const float4*)(bp + kk + 4);
        float4 f2 = *(const float4*)(bp + kk + 8);
        float4 f3 = *(const float4*)(bp + kk + 12);
        u16x8 b0, b1;
        b0[0] = f2bf(f0.x); b0[1] = f2bf(f0.y); b0[2] = f2bf(f0.z); b0[3] = f2bf(f0.w);
        b0[4] = f2bf(f1.x); b0[5] = f2bf(f1.y); b0[6] = f2bf(f1.z); b0[7] = f2bf(f1.w);
        b1[0] = f2bf(f2.x); b1[1] = f2bf(f2.y); b1[2] = f2bf(f2.z); b1[3] = f2bf(f2.w);
        b1[4] = f2bf(f3.x); b1[5] = f2bf(f3.y); b1[6] = f2bf(f3.z); b1[7] = f2bf(f3.w);

        __syncthreads();
        *(u16x8*)awr       = a0;
        *(u16x8*)(awr + 8) = a1;
        *(u16x8*)bwr       = b0;
        *(u16x8*)(bwr + 8) = b1;
        __syncthreads();

        const int row = l & 15, kg = (l >> 4) * 8;
        bf16x8 afr[4], bfr[4];
#pragma unroll
        for (int i = 0; i < 4; ++i)
            afr[i] = *(const bf16x8*)(Aa + (wr + i * 16 + row) * LSTR + kg);
#pragma unroll
        for (int j = 0; j < 4; ++j)
            bfr[j] = *(const bf16x8*)(Bb + (wc + j * 16 + row) * LSTR + kg);
#pragma unroll
        for (int i = 0; i < 4; ++i)
#pragma unroll
            for (int j = 0; j < 4; ++j)
                acc[i][j] = __builtin_amdgcn_mfma_f32_16x16x32_bf16(
                    afr[i], bfr[j], acc[i][j], 0, 0, 0);
    }

    const int col = l & 15, rg = (l >> 4) * 4;
#pragma unroll
    for (int i = 0; i < 4; ++i)
#pragma unroll
        for (int r = 0; r < 4; ++r) {
            const int grow = row0 + wr + i * 16 + rg + r;
            float* op = part + ((size_t)ks * 512 + grow) * 1024 + col0 + wc + col;
#pragma unroll
            for (int j = 0; j < 4; ++j) op[j * 16] = acc[i][j][r];
        }
}

__global__ __launch_bounds__(256) void fc1_reduce_kernel(
    const float* __restrict__ part, const float* __restrict__ bias,
    float* __restrict__ h)
{
    int idx = blockIdx.x * 256 + threadIdx.x;
    int j = idx & 1023;
    float s = bias[j];
#pragma unroll
    for (int ks = 0; ks < 16; ++ks) s += part[(size_t)ks * 524288 + idx];
    h[idx] = s > 0.f ? s : 0.f;
}

// ---------------------------------------------------------------------------
// fc2 MFMA (fp32 in, bf16 mfma) + attention epilogue.
// M=512 (mot 0..255, app 256..511), N=512, K=1024.  grid (4,4).
// ---------------------------------------------------------------------------
__global__ __launch_bounds__(256) void fc2_att_mfma_kernel(
    const float* __restrict__ h, const float* __restrict__ wf,
    const float* __restrict__ bias,
    const float* __restrict__ att1, const float* __restrict__ att2,
    float* __restrict__ alpha_out, float* __restrict__ inm, float* __restrict__ ina)
{
    __shared__ __align__(16) uint16_t Aa[128 * LSTR];
    __shared__ __align__(16) uint16_t Bb[128 * LSTR];

    const int row0 = blockIdx.x * 128;
    const int col0 = blockIdx.y * 128;

    const int t = threadIdx.x;
    const int w = t >> 6, l = t & 63;
    const int wr = (w >> 1) * 64, wc = (w & 1) * 64;

    const int srow  = t >> 1;
    const int shalf = (t & 1) * 16;
    const float* ap = h  + (size_t)(row0 + srow) * 1024 + shalf;
    const float* bp = wf + (size_t)(col0 + srow) * 1024 + shalf;
    uint16_t* awr = Aa + srow * LSTR + shalf;
    uint16_t* bwr = Bb + srow * LSTR + shalf;

    f32x4 acc[4][4] = {};

    for (int kk = 0; kk < 1024; kk += 32) {
        float4 a0 = *(const float4*)(ap + kk);
        float4 a1 = *(const float4*)(ap + kk + 4);
        float4 a2 = *(const float4*)(ap + kk + 8);
        float4 a3 = *(const float4*)(ap + kk + 12);
        float4 f0 = *(const float4*)(bp + kk);
        float4 f1 = *(const float4*)(bp + kk + 4);
        float4 f2 = *(const float4*)(bp + kk + 8);
        float4 f3 = *(const float4*)(bp + kk + 12);
        u16x8 av0, av1, b0, b1;
        av0[0]=f2bf(a0.x); av0[1]=f2bf(a0.y); av0[2]=f2bf(a0.z); av0[3]=f2bf(a0.w);
        av0[4]=f2bf(a1.x); av0[5]=f2bf(a1.y); av0[6]=f2bf(a1.z); av0[7]=f2bf(a1.w);
        av1[0]=f2bf(a2.x); av1[1]=f2bf(a2.y); av1[2]=f2bf(a2.z); av1[3]=f2bf(a2.w);
        av1[4]=f2bf(a3.x); av1[5]=f2bf(a3.y); av1[6]=f2bf(a3.z); av1[7]=f2bf(a3.w);
        b0[0]=f2bf(f0.x); b0[1]=f2bf(f0.y); b0[2]=f2bf(f0.z); b0[3]=f2bf(f0.w);
        b0[4]=f2bf(f1.x); b0[5]=f2bf(f1.y); b0[6]=f2bf(f1.z); b0[7]=f2bf(f1.w);
        b1[0]=f2bf(f2.x); b1[1]=f2bf(f2.y); b1[2]=f2bf(f2.z); b1[3]=f2bf(f2.w);
        b1[4]=f2bf(f3.x); b1[5]=f2bf(f3.y); b1[6]=f2bf(f3.z); b1[7]=f2bf(f3.w);

        __syncthreads();
        *(u16x8*)awr       = av0;
        *(u16x8*)(awr + 8) = av1;
        *(u16x8*)bwr       = b0;
        *(u16x8*)(bwr + 8) = b1;
        __syncthreads();

        const int row = l & 15, kg = (l >> 4) * 8;
        bf16x8 afr[4], bfr[4];
#pragma unroll
        for (int i = 0; i < 4; ++i)
            afr[i] = *(const bf16x8*)(Aa + (wr + i * 16 + row) * LSTR + kg);
#pragma unroll
        for (int j = 0; j < 4; ++j)
            bfr[j] = *(const bf16x8*)(Bb + (wc + j * 16 + row) * LSTR + kg);
#pragma unroll
        for (int i = 0; i < 4; ++i)
#pragma unroll
            for (int j = 0; j < 4; ++j)
                acc[i][j] = __builtin_amdgcn_mfma_f32_16x16x32_bf16(
                    afr[i], bfr[j], acc[i][j], 0, 0, 0);
    }

    const int col = l & 15, rg = (l >> 4) * 4;
#pragma unroll
    for (int i = 0; i < 4; ++i)
#pragma unroll
        for (int r = 0; r < 4; ++r) {
            const int row = row0 + wr + i * 16 + rg + r;
            const int bt  = row & 255;
            const int b = bt >> 4, tt = bt & 15;
            const size_t ibase = ((size_t)tt * 16 + b) * 1024;
#pragma unroll
            for (int j = 0; j < 4; ++j) {
                const int jj = col0 + wc + j * 16 + col;
                float v = acc[i][j][r] + bias[jj];
                if (row < 256) {
                    float al = sigm(att1[b * 512 + jj] * v);
                    alpha_out[(size_t)bt * 512 + jj] = al;
                    inm[ibase + jj]       = al * v;
                    inm[ibase + 512 + jj] = v;
                } else {
                    float be = sigm(att2[b * 512 + jj] * v);
                    ina[ibase + jj]       = be * v;
                    ina[ibase + 512 + jj] = v;
                }
            }
        }
}

// ---------------------------------------------------------------------------
// gx MFMA: gates x-projection, M=256, N=2048, K=1024, grid (2,16,2 paths).
// ---------------------------------------------------------------------------
__global__ __launch_bounds__(256) void gx_mfma_kernel(
    const float* __restrict__ inm, const float* __restrict__ ina,
    const float* __restrict__ wih_m, const float* __restrict__ bih_m, const float* __restrict__ bhh_m,
    const float* __restrict__ wih_a, const float* __restrict__ bih_a, const float* __restrict__ bhh_a,
    float* __restrict__ gxm, float* __restrict__ gxa)
{
    __shared__ __align__(16) uint16_t Aa[128 * LSTR];
    __shared__ __align__(16) uint16_t Bb[128 * LSTR];

    const int row0 = blockIdx.x * 128;
    const int col0 = blockIdx.y * 128;
    const int path = blockIdx.z;

    const float* A  = path ? ina : inm;
    const float* W  = path ? wih_a : wih_m;
    const float* bi = path ? bih_a : bih_m;
    const float* bh = path ? bhh_a : bhh_m;
    float* out = path ? gxa : gxm;

    const int t = threadIdx.x;
    const int w = t >> 6, l = t & 63;
    const int wr = (w >> 1) * 64, wc = (w & 1) * 64;

    const int srow  = t >> 1;
    const int shalf = (t & 1) * 16;
    const float* ap = A + (size_t)(row0 + srow) * 1024 + shalf;
    const float* bp = W + (size_t)(col0 + srow) * 1024 + shalf;
    uint16_t* awr = Aa + srow * LSTR + shalf;
    uint16_t* bwr = Bb + srow * LSTR + shalf;

    f32x4 acc[4][4] = {};

    for (int kk = 0; kk < 1024; kk += 32) {
        float4 a0 = *(const float4*)(ap + kk);
        float4 a1 = *(const float4*)(ap + kk + 4);
        float4 a2 = *(const float4*)(ap + kk + 8);
        float4 a3 = *(const float4*)(ap + kk + 12);
        float4 f0 = *(const float4*)(bp + kk);
        float4 f1 = *(const float4*)(bp + kk + 4);
        float4 f2 = *(const float4*)(bp + kk + 8);
        float4 f3 = *(const float4*)(bp + kk + 12);
        u16x8 av0, av1, b0, b1;
        av0[0]=f2bf(a0.x); av0[1]=f2bf(a0.y); av0[2]=f2bf(a0.z); av0[3]=f2bf(a0.w);
        av0[4]=f2bf(a1.x); av0[5]=f2bf(a1.y); av0[6]=f2bf(a1.z); av0[7]=f2bf(a1.w);
        av1[0]=f2bf(a2.x); av1[1]=f2bf(a2.y); av1[2]=f2bf(a2.z); av1[3]=f2bf(a2.w);
        av1[4]=f2bf(a3.x); av1[5]=f2bf(a3.y); av1[6]=f2bf(a3.z); av1[7]=f2bf(a3.w);
        b0[0]=f2bf(f0.x); b0[1]=f2bf(f0.y); b0[2]=f2bf(f0.z); b0[3]=f2bf(f0.w);
        b0[4]=f2bf(f1.x); b0[5]=f2bf(f1.y); b0[6]=f2bf(f1.z); b0[7]=f2bf(f1.w);
        b1[0]=f2bf(f2.x); b1[1]=f2bf(f2.y); b1[2]=f2bf(f2.z); b1[3]=f2bf(f2.w);
        b1[4]=f2bf(f3.x); b1[5]=f2bf(f3.y); b1[6]=f2bf(f3.z); b1[7]=f2bf(f3.w);

        __syncthreads();
        *(u16x8*)awr       = av0;
        *(u16x8*)(awr + 8) = av1;
        *(u16x8*)bwr       = b0;
        *(u16x8*)(bwr + 8) = b1;
        __syncthreads();

        const int row = l & 15, kg = (l >> 4) * 8;
        bf16x8 afr[4], bfr[4];
#pragma unroll
        for (int i = 0; i < 4; ++i)
            afr[i] = *(const bf16x8*)(Aa + (wr + i * 16 + row) * LSTR + kg);
#pragma unroll
        for (int j = 0; j < 4; ++j)
            bfr[j] = *(const bf16x8*)(Bb + (wc + j * 16 + row) * LSTR + kg);
#pragma unroll
        for (int i = 0; i < 4; ++i)
#pragma unroll
            for (int j = 0; j < 4; ++j)
                acc[i][j] = __builtin_amdgcn_mfma_f32_16x16x32_bf16(
                    afr[i], bfr[j], acc[i][j], 0, 0, 0);
    }

    const int col = l & 15, rg = (l >> 4) * 4;
#pragma unroll
    for (int i = 0; i < 4; ++i)
#pragma unroll
        for (int r = 0; r < 4; ++r) {
            const int grow = row0 + wr + i * 16 + rg + r;
#pragma unroll
            for (int j = 0; j < 4; ++j) {
                const int jj = col0 + wc + j * 16 + col;
                out[(size_t)grow * 2048 + jj] = acc[i][j][r] + bi[jj] + bh[jj];
            }
        }
}

// cell2m has x == h: pre-sum wih+whh, bih+bhh.
__global__ void w2sum_kernel(const float* __restrict__ a, const float* __restrict__ b,
                             const float* __restrict__ ba, const float* __restrict__ bb,
                             float* __restrict__ w, float* __restrict__ bs)
{
    int i = blockIdx.x * 256 + threadIdx.x;
    if (i < 2048 * 512) w[i] = a[i] + b[i];
    if (i < 2048) bs[i] = ba[i] + bb[i];
}

// ---------------------------------------------------------------------------
// Persistent LSTM scan: 64 blocks x 256 threads, one grid barrier per step.
// Stage1: 16384 items (2 paths x 512 j x 16 b), 1 per thread.
// Stage2: blocks 0-31 = m path (x==h), 32-63 = a path (2 dots).
// Weights become L2-resident after step 0 (block->CU pinning).
// ---------------------------------------------------------------------------
__device__ __forceinline__ void grid_barrier(int* cnt, int target) {
    __syncthreads();
    if (threadIdx.x == 0) {
        __threadfence();
        __hip_atomic_fetch_add(cnt, 1, __ATOMIC_ACQ_REL, __HIP_MEMORY_SCOPE_AGENT);
        while (__hip_atomic_load(cnt, __ATOMIC_ACQUIRE, __HIP_MEMORY_SCOPE_AGENT) < target)
            __builtin_amdgcn_s_sleep(2);
    }
    __syncthreads();
}

__device__ __forceinline__ void stage_lds(float dst[16][516], const float* __restrict__ src, int tid) {
    for (int idx = tid; idx < 2048; idx += 256) {
        float4 v = *(const float4*)(src + idx * 4);
        int flat = idx * 4;
        *(float4*)&dst[flat >> 9][flat & 511] = v;
    }
}

__device__ __forceinline__ float dot512(const float* __restrict__ hrow,
                                        const float* __restrict__ w0,
                                        const float* __restrict__ w1,
                                        const float* __restrict__ w2,
                                        const float* __restrict__ w3,
                                        float g[4])
{
    for (int k = 0; k < 512; k += 4) {
        float hv[4], v0[4], v1[4], v2[4], v3[4];
        *(float4*)hv = *(const float4*)(hrow + k);
        *(float4*)v0 = *(const float4*)(w0 + k);
        *(float4*)v1 = *(const float4*)(w1 + k);
        *(float4*)v2 = *(const float4*)(w2 + k);
        *(float4*)v3 = *(const float4*)(w3 + k);
#pragma unroll
        for (int u = 0; u < 4; ++u) {
            g[0] = fmaf(hv[u], v0[u], g[0]);
            g[1] = fmaf(hv[u], v1[u], g[1]);
            g[2] = fmaf(hv[u], v2[u], g[2]);
            g[3] = fmaf(hv[u], v3[u], g[3]);
        }
    }
    return 0.f;
}

__global__ __launch_bounds__(256, 1) void lstm_scan_kernel(
    const float* __restrict__ gxm, const float* __restrict__ gxa,
    const float* __restrict__ whh_m, const float* __restrict__ whh_a,
    const float* __restrict__ w2m, const float* __restrict__ b2m,
    const float* __restrict__ w2a_ih, const float* __restrict__ w2a_hh,
    const float* __restrict__ b2a_ih, const float* __restrict__ b2a_hh,
    float* __restrict__ states, int* __restrict__ bar,
    float* __restrict__ out)
{
    __shared__ __align__(16) float xs[16][516];
    __shared__ __align__(16) float hs[16][516];

    const int bk   = blockIdx.x;          // 0..63
    const int tid  = threadIdx.x;
    const int path = bk >> 5;             // 0=m, 1=a
    const int j0   = (bk & 31) * 16;
    const int b    = tid >> 4;
    const int j    = j0 + (tid & 15);

    float* s1m = states;                  // [2][8192]
    float* s1a = s1m + 16384;
    float* s2a = s1a + 16384;
    float* c1m = s2a + 16384;             // [8192] each
    float* c1a = c1m + 8192;
    float* c2m = c1a + 8192;
    float* c2a = c2m + 8192;

    // stage1 constants for this thread
    const float* gx1   = path ? gxa : gxm;
    const float* whh1  = path ? whh_a : whh_m;
    float* c1 = path ? c1a : c1m;
    const float* w1_0 = whh1 + (size_t)(0 * 512 + j) * 512;
    const float* w1_1 = whh1 + (size_t)(1 * 512 + j) * 512;
    const float* w1_2 = whh1 + (size_t)(2 * 512 + j) * 512;
    const float* w1_3 = whh1 + (size_t)(3 * 512 + j) * 512;

    // stage2 constants
    const float* wx2  = path ? w2a_ih : w2m;
    const float* w2_0 = wx2 + (size_t)(0 * 512 + j) * 512;
    const float* w2_1 = wx2 + (size_t)(1 * 512 + j) * 512;
    const float* w2_2 = wx2 + (size_t)(2 * 512 + j) * 512;
    const float* w2_3 = wx2 + (size_t)(3 * 512 + j) * 512;
    const float* h2_0 = w2a_hh + (size_t)(0 * 512 + j) * 512;
    const float* h2_1 = w2a_hh + (size_t)(1 * 512 + j) * 512;
    const float* h2_2 = w2a_hh + (size_t)(2 * 512 + j) * 512;
    const float* h2_3 = w2a_hh + (size_t)(3 * 512 + j) * 512;
    float gb2[4];
#pragma unroll
    for (int q = 0; q < 4; ++q)
        gb2[q] = path ? (b2a_ih[q * 512 + j] + b2a_hh[q * 512 + j]) : b2m[q * 512 + j];

    float c1v = 0.f, c2v = 0.f;

    for (int t = 0; t < 16; ++t) {
        // ---- stage1: s1 = cell1(x=gx[t], h=s1_old) ----
        const float* sin1 = (path ? s1a : s1m) + (t & 1) * 8192;
        float*       so1  = (path ? s1a : s1m) + ((t + 1) & 1) * 8192;

        __syncthreads();                      // protect xs from prior stage2 reads
        stage_lds(xs, sin1, tid);
        __syncthreads();

        float g[4];
#pragma unroll
        for (int q = 0; q < 4; ++q)
            g[q] = gx1[((size_t)(t * 16 + b)) * 2048 + q * 512 + j];
        dot512(&xs[b][0], w1_0, w1_1, w1_2, w1_3, g);

        float i_ = sigm(g[0]), f_ = sigm(g[1]), gg = tanhf(g[2]), o_ = sigm(g[3]);
        c1v = f_ * c1v + i_ * gg;
        float h1 = o_ * tanhf(c1v);
        so1[b * 512 + j] = h1;
        size_t obase = path ? 0 : 262144;
        out[obase + ((size_t)b * 16 + t) * 1024 + j] = h1;

        grid_barrier(bar, 64 * (t + 1));

        // ---- stage2 ----
        const float* xsrc = (path ? s1a : s1m) + ((t + 1) & 1) * 8192;
        stage_lds(xs, xsrc, tid);
        if (path) stage_lds(hs, s2a + (t & 1) * 8192, tid);
        __syncthreads();

        float g2[4] = { gb2[0], gb2[1], gb2[2], gb2[3] };
        dot512(&xs[b][0], w2_0, w2_1, w2_2, w2_3, g2);
        if (path) dot512(&hs[b][0], h2_0, h2_1, h2_2, h2_3, g2);

        float i2 = sigm(g2[0]), f2 = sigm(g2[1]), g2g = tanhf(g2[2]), o2 = sigm(g2[3]);
        c2v = f2 * c2v + i2 * g2g;
        float h2 = o2 * tanhf(c2v);
        if (path) s2a[((t + 1) & 1) * 8192 + b * 512 + j] = h2;
        out[obase + ((size_t)b * 16 + t) * 1024 + 512 + j] = h2;
        // next stage1 only reads s1 (synced at this step's barrier) -> no bar here
    }
}

// ---------------------------------------------------------------------------
extern "C" void kernel_launch(void* const* d_in, const int* in_sizes, int n_in,
                              void* d_out, int out_size, void* d_ws, size_t ws_size,
                              hipStream_t stream)
{
    (void)in_sizes; (void)n_in; (void)out_size; (void)ws_size;
    const float* f_t     = (const float*)d_in[0];
    const float* f_t_1   = (const float*)d_in[1];
    const float* att1    = (const float*)d_in[2];
    const float* att2    = (const float*)d_in[3];
    const float* conv1_w = (const float*)d_in[4];
    const float* conv1_b = (const float*)d_in[5];
    const float* conv2_w = (const float*)d_in[6];
    const float* conv2_b = (const float*)d_in[7];
    const float* l1a_wih = (const float*)d_in[8];
    const float* l1a_whh = (const float*)d_in[9];
    const float* l1a_bih = (const float*)d_in[10];
    const float* l1a_bhh = (const float*)d_in[11];
    const float* l2a_wih = (const float*)d_in[12];
    const float* l2a_whh = (const float*)d_in[13];
    const float* l2a_bih = (const float*)d_in[14];
    const float* l2a_bhh = (const float*)d_in[15];
    const float* l1m_wih = (const float*)d_in[16];
    const float* l1m_whh = (const float*)d_in[17];
    const float* l1m_bih = (const float*)d_in[18];
    const float* l1m_bhh = (const float*)d_in[19];
    const float* l2m_wih = (const float*)d_in[20];
    const float* l2m_whh = (const float*)d_in[21];
    const float* l2m_bih = (const float*)d_in[22];
    const float* l2m_bhh = (const float*)d_in[23];
    const float* fc1_w   = (const float*)d_in[24];
    const float* fc1_b   = (const float*)d_in[25];
    const float* fc2_w   = (const float*)d_in[26];
    const float* fc2_b   = (const float*)d_in[27];

    char* p = (char*)d_ws;
    uint16_t* in1_nhwc = (uint16_t*)p;             // 64MB [256][1024][128] bf16
    float*    part     = (float*)p;                // 32MB alias (after conv1 consumes nhwc)
    p += (size_t)64 << 20;
    uint16_t* c1out    = (uint16_t*)p; p += (size_t)32 << 20;   // [256][1024][64] NHWC bf16
    uint16_t* mbuf16   = (uint16_t*)p; p += (size_t)32 << 20;   // [256][64][1024] NCHW bf16
    uint16_t* ftflat16 = (uint16_t*)p; p += (size_t)32 << 20;   // [256][65536] bf16
    uint16_t* wpack1   = (uint16_t*)p; p += 256 * 1024;
    uint16_t* wpack2   = (uint16_t*)p; p += 128 * 1024;
    float* hbuf = (float*)p; p += (size_t)2 << 20;              // [512][1024]
    float* inm  = (float*)p; p += (size_t)1 << 20;
    float* ina  = (float*)p; p += (size_t)1 << 20;
    float* gxm  = (float*)p; p += (size_t)2 << 20;
    float* gxa  = (float*)p; p += (size_t)2 << 20;
    float* w2m  = (float*)p; p += (size_t)4 << 20;
    float* b2m  = (float*)p; p += 8192;
    float* st   = (float*)p; p += 81920 * 4;                    // states
    int*   bar  = (int*)p;  p += 256;

    float* outp = (float*)d_out;
    float* alpha_out = outp + 524288;

    hipMemsetAsync(st, 0, 81920 * sizeof(float), stream);
    hipMemsetAsync(bar, 0, sizeof(int), stream);

    // prep
    cvt_flat_kernel<<<8192, 256, 0, stream>>>(f_t, ftflat16, 16777216);
    nhwc_kernel<<<dim3(16, 256), 256, 0, stream>>>(f_t, f_t_1, in1_nhwc);
    wpack_kernel<<<288, 256, 0, stream>>>(conv1_w, conv2_w, wpack1, wpack2);

    // convs
    conv_mfma_kernel<128, false><<<dim3(8, 256), 256, 0, stream>>>(
        in1_nhwc, wpack1, conv1_b, c1out);
    conv_mfma_kernel<64, true><<<dim3(8, 256), 256, 0, stream>>>(
        c1out, wpack2, conv2_b, mbuf16);

    // fc1 (split-K=16, XCD-swizzled 1D grid)
    fc1_mfma_kernel<<<512, 256, 0, stream>>>(mbuf16, ftflat16, fc1_w, part);
    fc1_reduce_kernel<<<2048, 256, 0, stream>>>(part, fc1_b, hbuf);

    // fc2 + attention (MFMA)
    fc2_att_mfma_kernel<<<dim3(4, 4), 256, 0, stream>>>(hbuf, fc2_w, fc2_b, att1, att2,
                                                        alpha_out, inm, ina);

    // gates x-projection (MFMA)
    gx_mfma_kernel<<<dim3(2, 16, 2), 256, 0, stream>>>(inm, ina,
                                                       l1m_wih, l1m_bih, l1m_bhh,
                                                       l1a_wih, l1a_bih, l1a_bhh,
                                                       gxm, gxa);
    w2sum_kernel<<<4096, 256, 0, stream>>>(l2m_wih, l2m_whh, l2m_bih, l2m_bhh, w2m, b2m);

    // persistent LSTM scan (64 blocks, 16 grid barriers)
    lstm_scan_kernel<<<64, 256, 0, stream>>>(
        gxm, gxa, l1m_whh, l1a_whh, w2m, b2m,
        l2a_wih, l2a_whh, l2a_bih, l2a_bhh,
        st, bar, outp);
}

// Round 4
// 796.046 us; speedup vs baseline: 4.5971x; 4.5971x over previous
//
#include <hip/hip_runtime.h>
#include <math.h>
#include <stdint.h>

typedef __attribute__((ext_vector_type(8))) short    bf16x8;
typedef __attribute__((ext_vector_type(4))) float    f32x4;
typedef __attribute__((ext_vector_type(8))) uint16_t u16x8;

#define LSTR 40   // LDS row stride (bf16) for GEMM tiles: 80B rows -> 2-way banks (free)
#define NBLK 160  // persistent LSTM blocks

__device__ __forceinline__ uint16_t f2bf(float f) {
    union { float f; uint32_t u; } v; v.f = f;
    uint32_t r = v.u + 0x7FFFu + ((v.u >> 16) & 1u);
    return (uint16_t)(r >> 16);
}

__device__ __forceinline__ float sigm(float x) { return 1.f / (1.f + expf(-x)); }

// ---------------------------------------------------------------------------
// prep: f_t (fp32 flat NCHW) -> bf16 flat (fc1 A rows 256..511)
// ---------------------------------------------------------------------------
__global__ __launch_bounds__(256) void cvt_flat_kernel(
    const float* __restrict__ src, uint16_t* __restrict__ dst, int n)
{
    int i = (blockIdx.x * 256 + threadIdx.x) * 8;
    if (i >= n) return;
    float4 a = *(const float4*)(src + i);
    float4 b = *(const float4*)(src + i + 4);
    u16x8 o;
    o[0] = f2bf(a.x); o[1] = f2bf(a.y); o[2] = f2bf(a.z); o[3] = f2bf(a.w);
    o[4] = f2bf(b.x); o[5] = f2bf(b.y); o[6] = f2bf(b.z); o[7] = f2bf(b.w);
    *(u16x8*)(dst + i) = o;
}

// ---------------------------------------------------------------------------
// prep: concat(f_t, f_t_1) NCHW fp32 -> NHWC bf16 [bt][y][x][128]
// ---------------------------------------------------------------------------
__global__ __launch_bounds__(256) void nhwc_kernel(
    const float* __restrict__ f_t, const float* __restrict__ f_t_1,
    uint16_t* __restrict__ dst)
{
    __shared__ float lds[32][258];
    const int bt  = blockIdx.y;
    const int c0  = (blockIdx.x >> 2) * 32;
    const int px0 = (blockIdx.x & 3) * 256;
    const int t   = threadIdx.x;

    const int lc  = t & 31;
    const int lpx = (t >> 5) * 32;
    const int c   = c0 + lc;
    const float* src = (c < 64)
        ? (f_t   + ((size_t)bt * 64 + c) * 1024)
        : (f_t_1 + ((size_t)bt * 64 + (c - 64)) * 1024);
#pragma unroll
    for (int j = 0; j < 32; j += 4) {
        float4 v = *(const float4*)(src + px0 + lpx + j);
        lds[lc][lpx + j + 0] = v.x;
        lds[lc][lpx + j + 1] = v.y;
        lds[lc][lpx + j + 2] = v.z;
        lds[lc][lpx + j + 3] = v.w;
    }
    __syncthreads();
    uint16_t* op = dst + ((size_t)bt * 1024 + px0 + t) * 128 + c0;
#pragma unroll
    for (int u0 = 0; u0 < 32; u0 += 8) {
        u16x8 o;
#pragma unroll
        for (int u = 0; u < 8; ++u) o[u] = f2bf(lds[u0 + u][t]);
        *(u16x8*)(op + u0) = o;
    }
}

// ---------------------------------------------------------------------------
// prep: conv weights -> packed bf16 [oc][(ky*3+kx)*IC + c]
// ---------------------------------------------------------------------------
__global__ __launch_bounds__(256) void wpack_kernel(
    const float* __restrict__ w1, const float* __restrict__ w2,
    uint16_t* __restrict__ p1, uint16_t* __restrict__ p2)
{
    int i = blockIdx.x * 256 + threadIdx.x;
    if (i < 64 * 1152) {
        int oc = i / 1152, k = i - oc * 1152;
        int s = k >> 7, c = k & 127;
        int ky = s / 3, kx = s - ky * 3;
        p1[i] = f2bf(w1[((oc * 128 + c) * 3 + ky) * 3 + kx]);
    }
    if (i < 64 * 576) {
        int oc = i / 576, k = i - oc * 576;
        int s = k >> 6, c = k & 63;
        int ky = s / 3, kx = s - ky * 3;
        p2[i] = f2bf(w2[((oc * 64 + c) * 3 + ky) * 3 + kx]);
    }
}

// ---------------------------------------------------------------------------
// prep: LSTM weights -> bf16, tiled for the persistent scan kernel.
// pw1 [path][tile32][r=(j&15)*4+g][512]        (whh of cell1, both paths)
// pw2m[tile32][r=(j&15)*4+g][512]              (l2m wih+whh summed, x==h)
// pw2a[tile64][mat2][r=(j&7)*4+g][512]         (l2a wih, whh)
// b2m_s / b2a_s: bih+bhh sums.
// ---------------------------------------------------------------------------
__global__ __launch_bounds__(256) void lstm_pack_kernel(
    const float* __restrict__ whh_m, const float* __restrict__ whh_a,
    const float* __restrict__ m_wih, const float* __restrict__ m_whh,
    const float* __restrict__ a_wih, const float* __restrict__ a_whh,
    const float* __restrict__ m_bih, const float* __restrict__ m_bhh,
    const float* __restrict__ a_bih, const float* __restrict__ a_bhh,
    uint16_t* __restrict__ pw1, uint16_t* __restrict__ pw2m,
    uint16_t* __restrict__ pw2a,
    float* __restrict__ b2m_s, float* __restrict__ b2a_s)
{
    int id = blockIdx.x * 256 + threadIdx.x;
    if (id < 2048) {
        b2m_s[id] = m_bih[id] + m_bhh[id];
        b2a_s[id] = a_bih[id] + a_bhh[id];
    }
    if (id < 262144) {                       // pw1
        int kc = id & 63, g = (id >> 6) & 3, j = (id >> 8) & 511, p = id >> 17;
        const float* src = (p ? whh_a : whh_m) + ((size_t)(g * 512 + j)) * 512 + kc * 8;
        uint16_t* dst = pw1 + ((((size_t)p * 32 + (j >> 4)) * 64 + (j & 15) * 4 + g) * 512) + kc * 8;
        float4 a = *(const float4*)src; float4 b = *(const float4*)(src + 4);
        u16x8 o;
        o[0]=f2bf(a.x); o[1]=f2bf(a.y); o[2]=f2bf(a.z); o[3]=f2bf(a.w);
        o[4]=f2bf(b.x); o[5]=f2bf(b.y); o[6]=f2bf(b.z); o[7]=f2bf(b.w);
        *(u16x8*)dst = o;
    } else if (id < 393216) {                // pw2m (sum)
        int id2 = id - 262144;
        int kc = id2 & 63, g = (id2 >> 6) & 3, j = id2 >> 8;
        size_t off = ((size_t)(g * 512 + j)) * 512 + kc * 8;
        const float* s1 = m_wih + off; const float* s2 = m_whh + off;
        uint16_t* dst = pw2m + (((size_t)(j >> 4)) * 64 + (j & 15) * 4 + g) * 512 + kc * 8;
        u16x8 o;
#pragma unroll
        for (int u = 0; u < 8; ++u) o[u] = f2bf(s1[u] + s2[u]);
        *(u16x8*)dst = o;
    } else if (id < 655360) {                // pw2a
        int id3 = id - 393216;
        int kc = id3 & 63, g = (id3 >> 6) & 3, j = (id3 >> 8) & 511, mat = id3 >> 17;
        const float* src = (mat ? a_whh : a_wih) + ((size_t)(g * 512 + j)) * 512 + kc * 8;
        uint16_t* dst = pw2a + ((((size_t)(j >> 3)) * 2 + mat) * 32 + (j & 7) * 4 + g) * 512 + kc * 8;
        float4 a = *(const float4*)src; float4 b = *(const float4*)(src + 4);
        u16x8 o;
        o[0]=f2bf(a.x); o[1]=f2bf(a.y); o[2]=f2bf(a.z); o[3]=f2bf(a.w);
        o[4]=f2bf(b.x); o[5]=f2bf(b.y); o[6]=f2bf(b.z); o[7]=f2bf(b.w);
        *(u16x8*)dst = o;
    }
}

// ---------------------------------------------------------------------------
// conv3x3 + bias + relu as implicit-GEMM MFMA (pad-40 LDS rows).
// ---------------------------------------------------------------------------
template<int IC, bool SWAP>
__global__ __launch_bounds__(256) void conv_mfma_kernel(
    const uint16_t* __restrict__ in_nhwc,
    const uint16_t* __restrict__ wpack,
    const float* __restrict__ bias,
    uint16_t* __restrict__ out)
{
    constexpr int KT  = 9 * IC;
    constexpr int CPS = IC / 32;
    constexpr int MF  = SWAP ? 4 : 2;
    constexpr int NF  = SWAP ? 2 : 4;

    __shared__ __align__(16) uint16_t Apx[128 * LSTR];
    __shared__ __align__(16) uint16_t Bw[64 * LSTR];

    const int bt  = blockIdx.y;
    const int px0 = blockIdx.x * 128;
    const int t   = threadIdx.x;
    const int w   = t >> 6, l = t & 63;

    const int m = t >> 1, chalf = (t & 1) * 16;
    const int y = (px0 + m) >> 5, x = m & 31;
    const int oc_s = t >> 2, kslot = t & 3;

    f32x4 acc[MF][NF] = {};

    for (int q = 0; q < 9 * CPS; ++q) {
        const int s  = q / CPS, cc = (q - s * CPS) * 32;
        const int ky = s / 3,  kx = s - ky * 3;
        const int yy = y + ky - 1, xx = x + kx - 1;
        const bool ok = (yy >= 0) & (yy < 32) & (xx >= 0) & (xx < 32);
        u16x8 a0 = {}, a1 = {};
        if (ok) {
            const uint16_t* sp = in_nhwc
                + (((size_t)bt * 1024) + yy * 32 + xx) * IC + cc + chalf;
            a0 = *(const u16x8*)sp;
            a1 = *(const u16x8*)(sp + 8);
        }
        u16x8 b0 = *(const u16x8*)(wpack + (size_t)oc_s * KT + q * 32 + kslot * 8);

        __syncthreads();
        *(u16x8*)(Apx + m * LSTR + chalf)      = a0;
        *(u16x8*)(Apx + m * LSTR + chalf + 8)  = a1;
        *(u16x8*)(Bw + oc_s * LSTR + kslot * 8) = b0;
        __syncthreads();

        const int row = l & 15, kg = (l >> 4) * 8;
        if (!SWAP) {
            bf16x8 af[2], bf[4];
#pragma unroll
            for (int i = 0; i < 2; ++i)
                af[i] = *(const bf16x8*)(Apx + (w * 32 + i * 16 + row) * LSTR + kg);
#pragma unroll
            for (int j = 0; j < 4; ++j)
                bf[j] = *(const bf16x8*)(Bw + (j * 16 + row) * LSTR + kg);
#pragma unroll
            for (int i = 0; i < MF; ++i)
#pragma unroll
                for (int j = 0; j < NF; ++j)
                    acc[i][j] = __builtin_amdgcn_mfma_f32_16x16x32_bf16(
                        af[i], bf[j], acc[i][j], 0, 0, 0);
        } else {
            bf16x8 af[4], bf[2];
#pragma unroll
            for (int i = 0; i < 4; ++i)
                af[i] = *(const bf16x8*)(Bw + (i * 16 + row) * LSTR + kg);
#pragma unroll
            for (int j = 0; j < 2; ++j)
                bf[j] = *(const bf16x8*)(Apx + (w * 32 + j * 16 + row) * LSTR + kg);
#pragma unroll
            for (int i = 0; i < MF; ++i)
#pragma unroll
                for (int j = 0; j < NF; ++j)
                    acc[i][j] = __builtin_amdgcn_mfma_f32_16x16x32_bf16(
                        af[i], bf[j], acc[i][j], 0, 0, 0);
        }
    }

    const int col = l & 15, rg = (l >> 4) * 4;
    if (!SWAP) {
#pragma unroll
        for (int i = 0; i < 2; ++i)
#pragma unroll
            for (int j = 0; j < 4; ++j) {
                const int ocb = j * 16 + col;
                const float bv = bias[ocb];
#pragma unroll
                for (int r = 0; r < 4; ++r) {
                    const int px = px0 + w * 32 + i * 16 + rg + r;
                    float v = acc[i][j][r] + bv; v = v > 0.f ? v : 0.f;
                    out[((size_t)bt * 1024 + px) * 64 + ocb] = f2bf(v);
                }
            }
    } else {
#pragma unroll
        for (int i = 0; i < 4; ++i)
#pragma unroll
            for (int j = 0; j < 2; ++j)
#pragma unroll
                for (int r = 0; r < 4; ++r) {
                    const int oc = i * 16 + rg + r;
                    const int px = px0 + w * 32 + j * 16 + col;
                    float v = acc[i][j][r] + bias[oc]; v = v > 0.f ? v : 0.f;
                    out[((size_t)bt * 64 + oc) * 1024 + px] = f2bf(v);
                }
    }
}

// ---------------------------------------------------------------------------
// fc1 MFMA split-K=16, 1D grid (512) with XCD-chunked swizzle, pad-40 LDS.
// ---------------------------------------------------------------------------
__global__ __launch_bounds__(256) void fc1_mfma_kernel(
    const uint16_t* __restrict__ Am, const uint16_t* __restrict__ Af,
    const float* __restrict__ Wf, float* __restrict__ part)
{
    __shared__ __align__(16) uint16_t Aa[128 * LSTR];
    __shared__ __align__(16) uint16_t Bb[128 * LSTR];

    const int id  = blockIdx.x;
    const int swz = (id & 7) * 64 + (id >> 3);
    const int bx  = swz & 3;
    const int by  = (swz >> 2) & 7;
    const int ks  = swz >> 5;

    const int row0 = bx * 128;
    const int col0 = by * 128;
    const size_t kbase = (size_t)ks * 4096;
    const uint16_t* Abase = (row0 < 256) ? (Am + (size_t)row0 * 65536)
                                         : (Af + (size_t)(row0 - 256) * 65536);

    const int t = threadIdx.x;
    const int w = t >> 6, l = t & 63;
    const int wr = (w >> 1) * 64, wc = (w & 1) * 64;

    const int srow  = t >> 1;
    const int shalf = (t & 1) * 16;
    const uint16_t* ap = Abase + (size_t)srow * 65536 + kbase + shalf;
    const float*    bp = Wf + (size_t)(col0 + srow) * 65536 + kbase + shalf;
    uint16_t* awr = Aa + srow * LSTR + shalf;
    uint16_t* bwr = Bb + srow * LSTR + shalf;

    f32x4 acc[4][4] = {};

    for (int kk = 0; kk < 4096; kk += 32) {
        u16x8 a0 = *(const u16x8*)(ap + kk);
        u16x8 a1 = *(const u16x8*)(ap + kk + 8);
        float4 f0 = *(const float4*)(bp + kk);
        float4 f1 = *(const float4*)(bp + kk + 4);
        float4 f2 = *(const float4*)(bp + kk + 8);
        float4 f3 = *(const float4*)(bp + kk + 12);
        u16x8 b0, b1;
        b0[0] = f2bf(f0.x); b0[1] = f2bf(f0.y); b0[2] = f2bf(f0.z); b0[3] = f2bf(f0.w);
        b0[4] = f2bf(f1.x); b0[5] = f2bf(f1.y); b0[6] = f2bf(f1.z); b0[7] = f2bf(f1.w);
        b1[0] = f2bf(f2.x); b1[1] = f2bf(f2.y); b1[2] = f2bf(f2.z); b1[3] = f2bf(f2.w);
        b1[4] = f2bf(f3.x); b1[5] = f2bf(f3.y); b1[6] = f2bf(f3.z); b1[7] = f2bf(f3.w);

        __syncthreads();
        *(u16x8*)awr       = a0;
        *(u16x8*)(awr + 8) = a1;
        *(u16x8*)bwr       = b0;
        *(u16x8*)(bwr + 8) = b1;
        __syncthreads();

        const int row = l & 15, kg = (l >> 4) * 8;
        bf16x8 afr[4], bfr[4];
#pragma unroll
        for (int i = 0; i < 4; ++i)
            afr[i] = *(const bf16x8*)(Aa + (wr + i * 16 + row) * LSTR + kg);
#pragma unroll
        for (int j = 0; j < 4; ++j)
            bfr[j] = *(const bf16x8*)(Bb + (wc + j * 16 + row) * LSTR + kg);
#pragma unroll
        for (int i = 0; i < 4; ++i)
#pragma unroll
            for (int j = 0; j < 4; ++j)
                acc[i][j] = __builtin_amdgcn_mfma_f32_16x16x32_bf16(
                    afr[i], bfr[j], acc[i][j], 0, 0, 0);
    }

    const int col = l & 15, rg = (l >> 4) * 4;
#pragma unroll
    for (int i = 0; i < 4; ++i)
#pragma unroll
        for (int r = 0; r < 4; ++r) {
            const int grow = row0 + wr + i * 16 + rg + r;
            float* op = part + ((size_t)ks * 512 + grow) * 1024 + col0 + wc + col;
#pragma unroll
            for (int j = 0; j < 4; ++j) op[j * 16] = acc[i][j][r];
        }
}

__global__ __launch_bounds__(256) void fc1_reduce_kernel(
    const float* __restrict__ part, const float* __restrict__ bias,
    float* __restrict__ h)
{
    int idx = blockIdx.x * 256 + threadIdx.x;
    int j = idx & 1023;
    float s = bias[j];
#pragma unroll
    for (int ks = 0; ks < 16; ++ks) s += part[(size_t)ks * 524288 + idx];
    h[idx] = s > 0.f ? s : 0.f;
}

// ---------------------------------------------------------------------------
// fc2 MFMA + attention epilogue.
// ---------------------------------------------------------------------------
__global__ __launch_bounds__(256) void fc2_att_mfma_kernel(
    const float* __restrict__ h, const float* __restrict__ wf,
    const float* __restrict__ bias,
    const float* __restrict__ att1, const float* __restrict__ att2,
    float* __restrict__ alpha_out, float* __restrict__ inm, float* __restrict__ ina)
{
    __shared__ __align__(16) uint16_t Aa[128 * LSTR];
    __shared__ __align__(16) uint16_t Bb[128 * LSTR];

    const int row0 = blockIdx.x * 128;
    const int col0 = blockIdx.y * 128;

    const int t = threadIdx.x;
    const int w = t >> 6, l = t & 63;
    const int wr = (w >> 1) * 64, wc = (w & 1) * 64;

    const int srow  = t >> 1;
    const int shalf = (t & 1) * 16;
    const float* ap = h  + (size_t)(row0 + srow) * 1024 + shalf;
    const float* bp = wf + (size_t)(col0 + srow) * 1024 + shalf;
    uint16_t* awr = Aa + srow * LSTR + shalf;
    uint16_t* bwr = Bb + srow * LSTR + shalf;

    f32x4 acc[4][4] = {};

    for (int kk = 0; kk < 1024; kk += 32) {
        float4 a0 = *(const float4*)(ap + kk);
        float4 a1 = *(const float4*)(ap + kk + 4);
        float4 a2 = *(const float4*)(ap + kk + 8);
        float4 a3 = *(const float4*)(ap + kk + 12);
        float4 f0 = *(const float4*)(bp + kk);
        float4 f1 = *(const float4*)(bp + kk + 4);
        float4 f2 = *(const float4*)(bp + kk + 8);
        float4 f3 = *(const float4*)(bp + kk + 12);
        u16x8 av0, av1, b0, b1;
        av0[0]=f2bf(a0.x); av0[1]=f2bf(a0.y); av0[2]=f2bf(a0.z); av0[3]=f2bf(a0.w);
        av0[4]=f2bf(a1.x); av0[5]=f2bf(a1.y); av0[6]=f2bf(a1.z); av0[7]=f2bf(a1.w);
        av1[0]=f2bf(a2.x); av1[1]=f2bf(a2.y); av1[2]=f2bf(a2.z); av1[3]=f2bf(a2.w);
        av1[4]=f2bf(a3.x); av1[5]=f2bf(a3.y); av1[6]=f2bf(a3.z); av1[7]=f2bf(a3.w);
        b0[0]=f2bf(f0.x); b0[1]=f2bf(f0.y); b0[2]=f2bf(f0.z); b0[3]=f2bf(f0.w);
        b0[4]=f2bf(f1.x); b0[5]=f2bf(f1.y); b0[6]=f2bf(f1.z); b0[7]=f2bf(f1.w);
        b1[0]=f2bf(f2.x); b1[1]=f2bf(f2.y); b1[2]=f2bf(f2.z); b1[3]=f2bf(f2.w);
        b1[4]=f2bf(f3.x); b1[5]=f2bf(f3.y); b1[6]=f2bf(f3.z); b1[7]=f2bf(f3.w);

        __syncthreads();
        *(u16x8*)awr       = av0;
        *(u16x8*)(awr + 8) = av1;
        *(u16x8*)bwr       = b0;
        *(u16x8*)(bwr + 8) = b1;
        __syncthreads();

        const int row = l & 15, kg = (l >> 4) * 8;
        bf16x8 afr[4], bfr[4];
#pragma unroll
        for (int i = 0; i < 4; ++i)
            afr[i] = *(const bf16x8*)(Aa + (wr + i * 16 + row) * LSTR + kg);
#pragma unroll
        for (int j = 0; j < 4; ++j)
            bfr[j] = *(const bf16x8*)(Bb + (wc + j * 16 + row) * LSTR + kg);
#pragma unroll
        for (int i = 0; i < 4; ++i)
#pragma unroll
            for (int j = 0; j < 4; ++j)
                acc[i][j] = __builtin_amdgcn_mfma_f32_16x16x32_bf16(
                    afr[i], bfr[j], acc[i][j], 0, 0, 0);
    }

    const int col = l & 15, rg = (l >> 4) * 4;
#pragma unroll
    for (int i = 0; i < 4; ++i)
#pragma unroll
        for (int r = 0; r < 4; ++r) {
            const int row = row0 + wr + i * 16 + rg + r;
            const int bt  = row & 255;
            const int b = bt >> 4, tt = bt & 15;
            const size_t ibase = ((size_t)tt * 16 + b) * 1024;
#pragma unroll
            for (int j = 0; j < 4; ++j) {
                const int jj = col0 + wc + j * 16 + col;
                float v = acc[i][j][r] + bias[jj];
                if (row < 256) {
                    float al = sigm(att1[b * 512 + jj] * v);
                    alpha_out[(size_t)bt * 512 + jj] = al;
                    inm[ibase + jj]       = al * v;
                    inm[ibase + 512 + jj] = v;
                } else {
                    float be = sigm(att2[b * 512 + jj] * v);
                    ina[ibase + jj]       = be * v;
                    ina[ibase + 512 + jj] = v;
                }
            }
        }
}

// ---------------------------------------------------------------------------
// gx MFMA: gates x-projection, M=256, N=2048, K=1024, grid (2,16,2 paths).
// ---------------------------------------------------------------------------
__global__ __launch_bounds__(256) void gx_mfma_kernel(
    const float* __restrict__ inm, const float* __restrict__ ina,
    const float* __restrict__ wih_m, const float* __restrict__ bih_m, const float* __restrict__ bhh_m,
    const float* __restrict__ wih_a, const float* __restrict__ bih_a, const float* __restrict__ bhh_a,
    float* __restrict__ gxm, float* __restrict__ gxa)
{
    __shared__ __align__(16) uint16_t Aa[128 * LSTR];
    __shared__ __align__(16) uint16_t Bb[128 * LSTR];

    const int row0 = blockIdx.x * 128;
    const int col0 = blockIdx.y * 128;
    const int path = blockIdx.z;

    const float* A  = path ? ina : inm;
    const float* W  = path ? wih_a : wih_m;
    const float* bi = path ? bih_a : bih_m;
    const float* bh = path ? bhh_a : bhh_m;
    float* out = path ? gxa : gxm;

    const int t = threadIdx.x;
    const int w = t >> 6, l = t & 63;
    const int wr = (w >> 1) * 64, wc = (w & 1) * 64;

    const int srow  = t >> 1;
    const int shalf = (t & 1) * 16;
    const float* ap = A + (size_t)(row0 + srow) * 1024 + shalf;
    const float* bp = W + (size_t)(col0 + srow) * 1024 + shalf;
    uint16_t* awr = Aa + srow * LSTR + shalf;
    uint16_t* bwr = Bb + srow * LSTR + shalf;

    f32x4 acc[4][4] = {};

    for (int kk = 0; kk < 1024; kk += 32) {
        float4 a0 = *(const float4*)(ap + kk);
        float4 a1 = *(const float4*)(ap + kk + 4);
        float4 a2 = *(const float4*)(ap + kk + 8);
        float4 a3 = *(const float4*)(ap + kk + 12);
        float4 f0 = *(const float4*)(bp + kk);
        float4 f1 = *(const float4*)(bp + kk + 4);
        float4 f2 = *(const float4*)(bp + kk + 8);
        float4 f3 = *(const float4*)(bp + kk + 12);
        u16x8 av0, av1, b0, b1;
        av0[0]=f2bf(a0.x); av0[1]=f2bf(a0.y); av0[2]=f2bf(a0.z); av0[3]=f2bf(a0.w);
        av0[4]=f2bf(a1.x); av0[5]=f2bf(a1.y); av0[6]=f2bf(a1.z); av0[7]=f2bf(a1.w);
        av1[0]=f2bf(a2.x); av1[1]=f2bf(a2.y); av1[2]=f2bf(a2.z); av1[3]=f2bf(a2.w);
        av1[4]=f2bf(a3.x); av1[5]=f2bf(a3.y); av1[6]=f2bf(a3.z); av1[7]=f2bf(a3.w);
        b0[0]=f2bf(f0.x); b0[1]=f2bf(f0.y); b0[2]=f2bf(f0.z); b0[3]=f2bf(f0.w);
        b0[4]=f2bf(f1.x); b0[5]=f2bf(f1.y); b0[6]=f2bf(f1.z); b0[7]=f2bf(f1.w);
        b1[0]=f2bf(f2.x); b1[1]=f2bf(f2.y); b1[2]=f2bf(f2.z); b1[3]=f2bf(f2.w);
        b1[4]=f2bf(f3.x); b1[5]=f2bf(f3.y); b1[6]=f2bf(f3.z); b1[7]=f2bf(f3.w);

        __syncthreads();
        *(u16x8*)awr       = av0;
        *(u16x8*)(awr + 8) = av1;
        *(u16x8*)bwr       = b0;
        *(u16x8*)(bwr + 8) = b1;
        __syncthreads();

        const int row = l & 15, kg = (l >> 4) * 8;
        bf16x8 afr[4], bfr[4];
#pragma unroll
        for (int i = 0; i < 4; ++i)
            afr[i] = *(const bf16x8*)(Aa + (wr + i * 16 + row) * LSTR + kg);
#pragma unroll
        for (int j = 0; j < 4; ++j)
            bfr[j] = *(const bf16x8*)(Bb + (wc + j * 16 + row) * LSTR + kg);
#pragma unroll
        for (int i = 0; i < 4; ++i)
#pragma unroll
            for (int j = 0; j < 4; ++j)
                acc[i][j] = __builtin_amdgcn_mfma_f32_16x16x32_bf16(
                    afr[i], bfr[j], acc[i][j], 0, 0, 0);
    }

    const int col = l & 15, rg = (l >> 4) * 4;
#pragma unroll
    for (int i = 0; i < 4; ++i)
#pragma unroll
        for (int r = 0; r < 4; ++r) {
            const int grow = row0 + wr + i * 16 + rg + r;
#pragma unroll
            for (int j = 0; j < 4; ++j) {
                const int jj = col0 + wc + j * 16 + col;
                out[(size_t)grow * 2048 + jj] = acc[i][j][r] + bi[jj] + bh[jj];
            }
        }
}

// ---------------------------------------------------------------------------
// Persistent LSTM scan v2: 160 blocks, weights resident in LDS (bf16),
// MFMA gate GEMMs, 16 grid barriers, phases: {stage1(p) || stage2(p-1)}.
//   blocks [0,64):   stage1, path = bk>>5, 16-j tile
//   blocks [64,96):  stage2-m (x==h), 16-j tile
//   blocks [96,160): stage2-a (ih+hh), 8-j tile
// ---------------------------------------------------------------------------
__device__ __forceinline__ void grid_barrier(int* cnt, int target) {
    __syncthreads();
    if (threadIdx.x == 0) {
        __threadfence();
        __hip_atomic_fetch_add(cnt, 1, __ATOMIC_ACQ_REL, __HIP_MEMORY_SCOPE_AGENT);
        while (__hip_atomic_load(cnt, __ATOMIC_ACQUIRE, __HIP_MEMORY_SCOPE_AGENT) < target)
            __builtin_amdgcn_s_sleep(2);
        __threadfence();
    }
    __syncthreads();
}

__global__ __launch_bounds__(256, 1) void lstm_scan2_kernel(
    const float* __restrict__ gxm, const float* __restrict__ gxa,
    const uint16_t* __restrict__ pw1, const uint16_t* __restrict__ pw2m,
    const uint16_t* __restrict__ pw2a,
    const float* __restrict__ b2m_s, const float* __restrict__ b2a_s,
    uint16_t* __restrict__ s1bf,   // [buf2][path2][16][512] bf16
    uint16_t* __restrict__ s2abf,  // [buf2][16][512] bf16
    int* __restrict__ bar, float* __restrict__ out)
{
    __shared__ __align__(16) uint16_t wlds[64 * 520];   // 65 KB
    __shared__ __align__(16) uint16_t xs[16 * 520];     // 16.25 KB
    __shared__ __align__(16) uint16_t hs[16 * 520];     // 16.25 KB
    __shared__ float gbuf[2][16][68];                   // 8.5 KB

    const int bk  = blockIdx.x;
    const int tid = threadIdx.x;
    const int w   = tid >> 6, l = tid & 63;
    const int lrow = l & 15, kg = (l >> 4) * 8;

    const int role = (bk < 64) ? 0 : (bk < 96) ? 1 : 2;   // S1, S2M, S2A
    const int path = (role == 0) ? (bk >> 5) : (role == 1 ? 0 : 1);
    const int tile = (role == 0) ? (bk & 31) : (role == 1 ? bk - 64 : bk - 96);
    const int j0   = tile * ((role == 2) ? 8 : 16);

    // ---- stage weights into LDS (once) ----
    const uint16_t* wsrc =
        (role == 0) ? pw1 + ((size_t)path * 32 + tile) * 64 * 512 :
        (role == 1) ? pw2m + (size_t)tile * 64 * 512
                    : pw2a + (size_t)tile * 64 * 512;
    for (int idx = tid; idx < 64 * 64; idx += 256) {
        int row = idx >> 6, c = idx & 63;
        *(u16x8*)(wlds + row * 520 + c * 8) = *(const u16x8*)(wsrc + row * 512 + c * 8);
    }

    float cv = 0.f;    // c-state for this thread's (b,j)
    const float* gx1 = path ? gxa : gxm;

    for (int p = 0; p <= 16; ++p) {
        bool active = (role == 0) ? (p < 16) : (p >= 1);
        if (active) {
            const int t = (role == 0) ? p : p - 1;

            // ---- stage x (and h for S2A) into LDS ----
            const uint16_t* xsrc = s1bf + (((size_t)(p & 1) * 2) + path) * 8192;
            for (int idx = tid; idx < 1024; idx += 256) {
                int row = idx >> 6, c = idx & 63;
                *(u16x8*)(xs + row * 520 + c * 8) = *(const u16x8*)(xsrc + row * 512 + c * 8);
            }
            if (role == 2) {
                const uint16_t* hsrc = s2abf + (size_t)(t & 1) * 8192;
                for (int idx = tid; idx < 1024; idx += 256) {
                    int row = idx >> 6, c = idx & 63;
                    *(u16x8*)(hs + row * 520 + c * 8) = *(const u16x8*)(hsrc + row * 512 + c * 8);
                }
            }
            __syncthreads();

            // ---- MFMA gate GEMM [16b x rows] ----
            f32x4 acc = {};
            if (role != 2) {
                // 64 rows, wave w -> rows w*16..
#pragma unroll
                for (int kk = 0; kk < 512; kk += 32) {
                    bf16x8 a = *(const bf16x8*)(xs + lrow * 520 + kk + kg);
                    bf16x8 b = *(const bf16x8*)(wlds + (w * 16 + lrow) * 520 + kk + kg);
                    acc = __builtin_amdgcn_mfma_f32_16x16x32_bf16(a, b, acc, 0, 0, 0);
                }
#pragma unroll
                for (int r = 0; r < 4; ++r)
                    gbuf[0][(l >> 4) * 4 + r][w * 16 + lrow] = acc[r];
            } else {
                // 32 rows; waves 0,1 = ih (x), waves 2,3 = hh (h)
                const uint16_t* src = (w < 2) ? xs : hs;
                const int wt = (w < 2) ? w : w - 2;
                const int wb = (w < 2) ? 0 : 32 * 520;
#pragma unroll
                for (int kk = 0; kk < 512; kk += 32) {
                    bf16x8 a = *(const bf16x8*)(src + lrow * 520 + kk + kg);
                    bf16x8 b = *(const bf16x8*)(wlds + wb + (wt * 16 + lrow) * 520 + kk + kg);
                    acc = __builtin_amdgcn_mfma_f32_16x16x32_bf16(a, b, acc, 0, 0, 0);
                }
#pragma unroll
                for (int r = 0; r < 4; ++r)
                    gbuf[w >> 1][(l >> 4) * 4 + r][wt * 16 + lrow] = acc[r];
            }
            __syncthreads();

            // ---- gate nonlinearities ----
            if (role == 0) {
                const int b = tid >> 4, j = tid & 15, jg = j0 + j;
                const float* gxr = gx1 + ((size_t)(t * 16 + b)) * 2048;
                float g0 = gbuf[0][b][j * 4 + 0] + gxr[0 * 512 + jg];
                float g1 = gbuf[0][b][j * 4 + 1] + gxr[1 * 512 + jg];
                float g2 = gbuf[0][b][j * 4 + 2] + gxr[2 * 512 + jg];
                float g3 = gbuf[0][b][j * 4 + 3] + gxr[3 * 512 + jg];
                float i_ = sigm(g0), f_ = sigm(g1), c_ = tanhf(g2), o_ = sigm(g3);
                cv = f_ * cv + i_ * c_;
                float h = o_ * tanhf(cv);
                size_t obase = path ? 0 : 262144;
                out[obase + ((size_t)b * 16 + t) * 1024 + jg] = h;
                s1bf[(((size_t)((p + 1) & 1)) * 2 + path) * 8192 + b * 512 + jg] = f2bf(h);
            } else if (role == 1) {
                const int b = tid >> 4, j = tid & 15, jg = j0 + j;
                float g0 = gbuf[0][b][j * 4 + 0] + b2m_s[0 * 512 + jg];
                float g1 = gbuf[0][b][j * 4 + 1] + b2m_s[1 * 512 + jg];
                float g2 = gbuf[0][b][j * 4 + 2] + b2m_s[2 * 512 + jg];
                float g3 = gbuf[0][b][j * 4 + 3] + b2m_s[3 * 512 + jg];
                float i_ = sigm(g0), f_ = sigm(g1), c_ = tanhf(g2), o_ = sigm(g3);
                cv = f_ * cv + i_ * c_;
                float h = o_ * tanhf(cv);
                out[262144 + ((size_t)b * 16 + t) * 1024 + 512 + jg] = h;
            } else if (tid < 128) {
                const int b = tid >> 3, j = tid & 7, jg = j0 + j;
                float g0 = gbuf[0][b][j * 4 + 0] + gbuf[1][b][j * 4 + 0] + b2a_s[0 * 512 + jg];
                float g1 = gbuf[0][b][j * 4 + 1] + gbuf[1][b][j * 4 + 1] + b2a_s[1 * 512 + jg];
                float g2 = gbuf[0][b][j * 4 + 2] + gbuf[1][b][j * 4 + 2] + b2a_s[2 * 512 + jg];
                float g3 = gbuf[0][b][j * 4 + 3] + gbuf[1][b][j * 4 + 3] + b2a_s[3 * 512 + jg];
                float i_ = sigm(g0), f_ = sigm(g1), c_ = tanhf(g2), o_ = sigm(g3);
                cv = f_ * cv + i_ * c_;
                float h = o_ * tanhf(cv);
                out[((size_t)b * 16 + t) * 1024 + 512 + jg] = h;
                s2abf[(size_t)((t + 1) & 1) * 8192 + b * 512 + jg] = f2bf(h);
            }
        }
        if (p < 16) grid_barrier(bar, NBLK * (p + 1));
    }
}

// ---------------------------------------------------------------------------
extern "C" void kernel_launch(void* const* d_in, const int* in_sizes, int n_in,
                              void* d_out, int out_size, void* d_ws, size_t ws_size,
                              hipStream_t stream)
{
    (void)in_sizes; (void)n_in; (void)out_size; (void)ws_size;
    const float* f_t     = (const float*)d_in[0];
    const float* f_t_1   = (const float*)d_in[1];
    const float* att1    = (const float*)d_in[2];
    const float* att2    = (const float*)d_in[3];
    const float* conv1_w = (const float*)d_in[4];
    const float* conv1_b = (const float*)d_in[5];
    const float* conv2_w = (const float*)d_in[6];
    const float* conv2_b = (const float*)d_in[7];
    const float* l1a_wih = (const float*)d_in[8];
    const float* l1a_whh = (const float*)d_in[9];
    const float* l1a_bih = (const float*)d_in[10];
    const float* l1a_bhh = (const float*)d_in[11];
    const float* l2a_wih = (const float*)d_in[12];
    const float* l2a_whh = (const float*)d_in[13];
    const float* l2a_bih = (const float*)d_in[14];
    const float* l2a_bhh = (const float*)d_in[15];
    const float* l1m_wih = (const float*)d_in[16];
    const float* l1m_whh = (const float*)d_in[17];
    const float* l1m_bih = (const float*)d_in[18];
    const float* l1m_bhh = (const float*)d_in[19];
    const float* l2m_wih = (const float*)d_in[20];
    const float* l2m_whh = (const float*)d_in[21];
    const float* l2m_bih = (const float*)d_in[22];
    const float* l2m_bhh = (const float*)d_in[23];
    const float* fc1_w   = (const float*)d_in[24];
    const float* fc1_b   = (const float*)d_in[25];
    const float* fc2_w   = (const float*)d_in[26];
    const float* fc2_b   = (const float*)d_in[27];

    char* p = (char*)d_ws;
    uint16_t* in1_nhwc = (uint16_t*)p;             // 64MB [256][1024][128] bf16
    float*    part     = (float*)p;                // 32MB alias (after conv1 consumes nhwc)
    p += (size_t)64 << 20;
    uint16_t* c1out    = (uint16_t*)p; p += (size_t)32 << 20;
    uint16_t* mbuf16   = (uint16_t*)p; p += (size_t)32 << 20;
    uint16_t* ftflat16 = (uint16_t*)p; p += (size_t)32 << 20;
    uint16_t* wpack1   = (uint16_t*)p; p += 256 * 1024;
    uint16_t* wpack2   = (uint16_t*)p; p += 128 * 1024;
    float* hbuf = (float*)p; p += (size_t)2 << 20;
    float* inm  = (float*)p; p += (size_t)1 << 20;
    float* ina  = (float*)p; p += (size_t)1 << 20;
    float* gxm  = (float*)p; p += (size_t)2 << 20;
    float* gxa  = (float*)p; p += (size_t)2 << 20;
    uint16_t* pw1  = (uint16_t*)p; p += (size_t)2097152 * 2;   // 4MB
    uint16_t* pw2m = (uint16_t*)p; p += (size_t)1048576 * 2;   // 2MB
    uint16_t* pw2a = (uint16_t*)p; p += (size_t)2097152 * 2;   // 4MB
    float* b2m_s = (float*)p; p += 2048 * 4;
    float* b2a_s = (float*)p; p += 2048 * 4;
    uint16_t* s1bf  = (uint16_t*)p; p += 32768 * 2;            // [2][2][16][512]
    uint16_t* s2abf = (uint16_t*)p; p += 16384 * 2;            // [2][16][512]
    int* bar = (int*)p; p += 256;

    float* outp = (float*)d_out;
    float* alpha_out = outp + 524288;

    hipMemsetAsync(s1bf, 0, 32768 * 2, stream);
    hipMemsetAsync(s2abf, 0, 16384 * 2, stream);
    hipMemsetAsync(bar, 0, sizeof(int), stream);

    // prep
    cvt_flat_kernel<<<8192, 256, 0, stream>>>(f_t, ftflat16, 16777216);
    nhwc_kernel<<<dim3(16, 256), 256, 0, stream>>>(f_t, f_t_1, in1_nhwc);
    wpack_kernel<<<288, 256, 0, stream>>>(conv1_w, conv2_w, wpack1, wpack2);
    lstm_pack_kernel<<<2560, 256, 0, stream>>>(
        l1m_whh, l1a_whh, l2m_wih, l2m_whh, l2a_wih, l2a_whh,
        l2m_bih, l2m_bhh, l2a_bih, l2a_bhh,
        pw1, pw2m, pw2a, b2m_s, b2a_s);

    // convs
    conv_mfma_kernel<128, false><<<dim3(8, 256), 256, 0, stream>>>(
        in1_nhwc, wpack1, conv1_b, c1out);
    conv_mfma_kernel<64, true><<<dim3(8, 256), 256, 0, stream>>>(
        c1out, wpack2, conv2_b, mbuf16);

    // fc1 (split-K=16, XCD-swizzled)
    fc1_mfma_kernel<<<512, 256, 0, stream>>>(mbuf16, ftflat16, fc1_w, part);
    fc1_reduce_kernel<<<2048, 256, 0, stream>>>(part, fc1_b, hbuf);

    // fc2 + attention
    fc2_att_mfma_kernel<<<dim3(4, 4), 256, 0, stream>>>(hbuf, fc2_w, fc2_b, att1, att2,
                                                        alpha_out, inm, ina);

    // gates x-projection
    gx_mfma_kernel<<<dim3(2, 16, 2), 256, 0, stream>>>(inm, ina,
                                                       l1m_wih, l1m_bih, l1m_bhh,
                                                       l1a_wih, l1a_bih, l1a_bhh,
                                                       gxm, gxa);

    // persistent LSTM scan v2
    lstm_scan2_kernel<<<NBLK, 256, 0, stream>>>(
        gxm, gxa, pw1, pw2m, pw2a, b2m_s, b2a_s,
        s1bf, s2abf, bar, outp);
}

// Round 5
// 761.761 us; speedup vs baseline: 4.8040x; 1.0450x over previous
//
#include <hip/hip_runtime.h>
#include <math.h>
#include <stdint.h>

typedef __attribute__((ext_vector_type(8))) short    bf16x8;
typedef __attribute__((ext_vector_type(4))) float    f32x4;
typedef __attribute__((ext_vector_type(8))) uint16_t u16x8;

#define LSTR 40   // LDS row stride (bf16) for GEMM tiles: 80B rows -> 2-way banks (free)
#define NBLK 160  // persistent LSTM blocks

__device__ __forceinline__ uint16_t f2bf(float f) {
    union { float f; uint32_t u; } v; v.f = f;
    uint32_t r = v.u + 0x7FFFu + ((v.u >> 16) & 1u);
    return (uint16_t)(r >> 16);
}

__device__ __forceinline__ float sigm(float x) { return 1.f / (1.f + expf(-x)); }

// ---------------------------------------------------------------------------
// prep: f_t (fp32 flat NCHW) -> bf16 flat (fc1 A rows 256..511)
// ---------------------------------------------------------------------------
__global__ __launch_bounds__(256) void cvt_flat_kernel(
    const float* __restrict__ src, uint16_t* __restrict__ dst, int n)
{
    int i = (blockIdx.x * 256 + threadIdx.x) * 8;
    if (i >= n) return;
    float4 a = *(const float4*)(src + i);
    float4 b = *(const float4*)(src + i + 4);
    u16x8 o;
    o[0] = f2bf(a.x); o[1] = f2bf(a.y); o[2] = f2bf(a.z); o[3] = f2bf(a.w);
    o[4] = f2bf(b.x); o[5] = f2bf(b.y); o[6] = f2bf(b.z); o[7] = f2bf(b.w);
    *(u16x8*)(dst + i) = o;
}

// ---------------------------------------------------------------------------
// prep: concat(f_t, f_t_1) NCHW fp32 -> NHWC bf16 [bt][y][x][128]
// ---------------------------------------------------------------------------
__global__ __launch_bounds__(256) void nhwc_kernel(
    const float* __restrict__ f_t, const float* __restrict__ f_t_1,
    uint16_t* __restrict__ dst)
{
    __shared__ float lds[32][258];
    const int bt  = blockIdx.y;
    const int c0  = (blockIdx.x >> 2) * 32;
    const int px0 = (blockIdx.x & 3) * 256;
    const int t   = threadIdx.x;

    const int lc  = t & 31;
    const int lpx = (t >> 5) * 32;
    const int c   = c0 + lc;
    const float* src = (c < 64)
        ? (f_t   + ((size_t)bt * 64 + c) * 1024)
        : (f_t_1 + ((size_t)bt * 64 + (c - 64)) * 1024);
#pragma unroll
    for (int j = 0; j < 32; j += 4) {
        float4 v = *(const float4*)(src + px0 + lpx + j);
        lds[lc][lpx + j + 0] = v.x;
        lds[lc][lpx + j + 1] = v.y;
        lds[lc][lpx + j + 2] = v.z;
        lds[lc][lpx + j + 3] = v.w;
    }
    __syncthreads();
    uint16_t* op = dst + ((size_t)bt * 1024 + px0 + t) * 128 + c0;
#pragma unroll
    for (int u0 = 0; u0 < 32; u0 += 8) {
        u16x8 o;
#pragma unroll
        for (int u = 0; u < 8; ++u) o[u] = f2bf(lds[u0 + u][t]);
        *(u16x8*)(op + u0) = o;
    }
}

// ---------------------------------------------------------------------------
// prep: conv weights -> packed bf16 [oc][(ky*3+kx)*IC + c]
// ---------------------------------------------------------------------------
__global__ __launch_bounds__(256) void wpack_kernel(
    const float* __restrict__ w1, const float* __restrict__ w2,
    uint16_t* __restrict__ p1, uint16_t* __restrict__ p2)
{
    int i = blockIdx.x * 256 + threadIdx.x;
    if (i < 64 * 1152) {
        int oc = i / 1152, k = i - oc * 1152;
        int s = k >> 7, c = k & 127;
        int ky = s / 3, kx = s - ky * 3;
        p1[i] = f2bf(w1[((oc * 128 + c) * 3 + ky) * 3 + kx]);
    }
    if (i < 64 * 576) {
        int oc = i / 576, k = i - oc * 576;
        int s = k >> 6, c = k & 63;
        int ky = s / 3, kx = s - ky * 3;
        p2[i] = f2bf(w2[((oc * 64 + c) * 3 + ky) * 3 + kx]);
    }
}

// ---------------------------------------------------------------------------
// prep: LSTM weights -> bf16 tiles for the persistent scan.
// pw1 [path][tile32][r=(j&15)*4+g][512]   (whh of cell1)
// pw2m[tile32][r][512]                    (l2m wih+whh summed, x==h)
// pw2a[tile64][mat2][r=(j&7)*4+g][512]    (l2a wih, whh)
// ---------------------------------------------------------------------------
__global__ __launch_bounds__(256) void lstm_pack_kernel(
    const float* __restrict__ whh_m, const float* __restrict__ whh_a,
    const float* __restrict__ m_wih, const float* __restrict__ m_whh,
    const float* __restrict__ a_wih, const float* __restrict__ a_whh,
    const float* __restrict__ m_bih, const float* __restrict__ m_bhh,
    const float* __restrict__ a_bih, const float* __restrict__ a_bhh,
    uint16_t* __restrict__ pw1, uint16_t* __restrict__ pw2m,
    uint16_t* __restrict__ pw2a,
    float* __restrict__ b2m_s, float* __restrict__ b2a_s)
{
    int id = blockIdx.x * 256 + threadIdx.x;
    if (id < 2048) {
        b2m_s[id] = m_bih[id] + m_bhh[id];
        b2a_s[id] = a_bih[id] + a_bhh[id];
    }
    if (id < 262144) {                       // pw1
        int kc = id & 63, g = (id >> 6) & 3, j = (id >> 8) & 511, p = id >> 17;
        const float* src = (p ? whh_a : whh_m) + ((size_t)(g * 512 + j)) * 512 + kc * 8;
        uint16_t* dst = pw1 + ((((size_t)p * 32 + (j >> 4)) * 64 + (j & 15) * 4 + g) * 512) + kc * 8;
        float4 a = *(const float4*)src; float4 b = *(const float4*)(src + 4);
        u16x8 o;
        o[0]=f2bf(a.x); o[1]=f2bf(a.y); o[2]=f2bf(a.z); o[3]=f2bf(a.w);
        o[4]=f2bf(b.x); o[5]=f2bf(b.y); o[6]=f2bf(b.z); o[7]=f2bf(b.w);
        *(u16x8*)dst = o;
    } else if (id < 393216) {                // pw2m (sum)
        int id2 = id - 262144;
        int kc = id2 & 63, g = (id2 >> 6) & 3, j = id2 >> 8;
        size_t off = ((size_t)(g * 512 + j)) * 512 + kc * 8;
        const float* s1 = m_wih + off; const float* s2 = m_whh + off;
        uint16_t* dst = pw2m + (((size_t)(j >> 4)) * 64 + (j & 15) * 4 + g) * 512 + kc * 8;
        u16x8 o;
#pragma unroll
        for (int u = 0; u < 8; ++u) o[u] = f2bf(s1[u] + s2[u]);
        *(u16x8*)dst = o;
    } else if (id < 655360) {                // pw2a
        int id3 = id - 393216;
        int kc = id3 & 63, g = (id3 >> 6) & 3, j = (id3 >> 8) & 511, mat = id3 >> 17;
        const float* src = (mat ? a_whh : a_wih) + ((size_t)(g * 512 + j)) * 512 + kc * 8;
        uint16_t* dst = pw2a + ((((size_t)(j >> 3)) * 2 + mat) * 32 + (j & 7) * 4 + g) * 512 + kc * 8;
        float4 a = *(const float4*)src; float4 b = *(const float4*)(src + 4);
        u16x8 o;
        o[0]=f2bf(a.x); o[1]=f2bf(a.y); o[2]=f2bf(a.z); o[3]=f2bf(a.w);
        o[4]=f2bf(b.x); o[5]=f2bf(b.y); o[6]=f2bf(b.z); o[7]=f2bf(b.w);
        *(u16x8*)dst = o;
    }
}

// ---------------------------------------------------------------------------
// conv3x3 + bias + relu as implicit-GEMM MFMA (pad-40 LDS rows).
// ---------------------------------------------------------------------------
template<int IC, bool SWAP>
__global__ __launch_bounds__(256) void conv_mfma_kernel(
    const uint16_t* __restrict__ in_nhwc,
    const uint16_t* __restrict__ wpack,
    const float* __restrict__ bias,
    uint16_t* __restrict__ out)
{
    constexpr int KT  = 9 * IC;
    constexpr int CPS = IC / 32;
    constexpr int MF  = SWAP ? 4 : 2;
    constexpr int NF  = SWAP ? 2 : 4;

    __shared__ __align__(16) uint16_t Apx[128 * LSTR];
    __shared__ __align__(16) uint16_t Bw[64 * LSTR];

    const int bt  = blockIdx.y;
    const int px0 = blockIdx.x * 128;
    const int t   = threadIdx.x;
    const int w   = t >> 6, l = t & 63;

    const int m = t >> 1, chalf = (t & 1) * 16;
    const int y = (px0 + m) >> 5, x = m & 31;
    const int oc_s = t >> 2, kslot = t & 3;

    f32x4 acc[MF][NF] = {};

    for (int q = 0; q < 9 * CPS; ++q) {
        const int s  = q / CPS, cc = (q - s * CPS) * 32;
        const int ky = s / 3,  kx = s - ky * 3;
        const int yy = y + ky - 1, xx = x + kx - 1;
        const bool ok = (yy >= 0) & (yy < 32) & (xx >= 0) & (xx < 32);
        u16x8 a0 = {}, a1 = {};
        if (ok) {
            const uint16_t* sp = in_nhwc
                + (((size_t)bt * 1024) + yy * 32 + xx) * IC + cc + chalf;
            a0 = *(const u16x8*)sp;
            a1 = *(const u16x8*)(sp + 8);
        }
        u16x8 b0 = *(const u16x8*)(wpack + (size_t)oc_s * KT + q * 32 + kslot * 8);

        __syncthreads();
        *(u16x8*)(Apx + m * LSTR + chalf)      = a0;
        *(u16x8*)(Apx + m * LSTR + chalf + 8)  = a1;
        *(u16x8*)(Bw + oc_s * LSTR + kslot * 8) = b0;
        __syncthreads();

        const int row = l & 15, kg = (l >> 4) * 8;
        if (!SWAP) {
            bf16x8 af[2], bf[4];
#pragma unroll
            for (int i = 0; i < 2; ++i)
                af[i] = *(const bf16x8*)(Apx + (w * 32 + i * 16 + row) * LSTR + kg);
#pragma unroll
            for (int j = 0; j < 4; ++j)
                bf[j] = *(const bf16x8*)(Bw + (j * 16 + row) * LSTR + kg);
#pragma unroll
            for (int i = 0; i < MF; ++i)
#pragma unroll
                for (int j = 0; j < NF; ++j)
                    acc[i][j] = __builtin_amdgcn_mfma_f32_16x16x32_bf16(
                        af[i], bf[j], acc[i][j], 0, 0, 0);
        } else {
            bf16x8 af[4], bf[2];
#pragma unroll
            for (int i = 0; i < 4; ++i)
                af[i] = *(const bf16x8*)(Bw + (i * 16 + row) * LSTR + kg);
#pragma unroll
            for (int j = 0; j < 2; ++j)
                bf[j] = *(const bf16x8*)(Apx + (w * 32 + j * 16 + row) * LSTR + kg);
#pragma unroll
            for (int i = 0; i < MF; ++i)
#pragma unroll
                for (int j = 0; j < NF; ++j)
                    acc[i][j] = __builtin_amdgcn_mfma_f32_16x16x32_bf16(
                        af[i], bf[j], acc[i][j], 0, 0, 0);
        }
    }

    const int col = l & 15, rg = (l >> 4) * 4;
    if (!SWAP) {
#pragma unroll
        for (int i = 0; i < 2; ++i)
#pragma unroll
            for (int j = 0; j < 4; ++j) {
                const int ocb = j * 16 + col;
                const float bv = bias[ocb];
#pragma unroll
                for (int r = 0; r < 4; ++r) {
                    const int px = px0 + w * 32 + i * 16 + rg + r;
                    float v = acc[i][j][r] + bv; v = v > 0.f ? v : 0.f;
                    out[((size_t)bt * 1024 + px) * 64 + ocb] = f2bf(v);
                }
            }
    } else {
#pragma unroll
        for (int i = 0; i < 4; ++i)
#pragma unroll
            for (int j = 0; j < 2; ++j)
#pragma unroll
                for (int r = 0; r < 4; ++r) {
                    const int oc = i * 16 + rg + r;
                    const int px = px0 + w * 32 + j * 16 + col;
                    float v = acc[i][j][r] + bias[oc]; v = v > 0.f ? v : 0.f;
                    out[((size_t)bt * 64 + oc) * 1024 + px] = f2bf(v);
                }
    }
}

// ---------------------------------------------------------------------------
// fc1 MFMA split-K=32, 1024 blocks (4/CU), XCD-chunked swizzle, pad-40 LDS.
// ---------------------------------------------------------------------------
__global__ __launch_bounds__(256) void fc1_mfma_kernel(
    const uint16_t* __restrict__ Am, const uint16_t* __restrict__ Af,
    const float* __restrict__ Wf, float* __restrict__ part)
{
    __shared__ __align__(16) uint16_t Aa[128 * LSTR];
    __shared__ __align__(16) uint16_t Bb[128 * LSTR];

    // 128 consecutive virtual ids per XCD (1024 % 8 == 0 -> bijective)
    const int id  = blockIdx.x;
    const int swz = (id & 7) * 128 + (id >> 3);
    const int bx  = swz & 3;           // row tile (4)
    const int by  = (swz >> 2) & 7;    // col tile (8)
    const int ks  = swz >> 5;          // k split  (32)

    const int row0 = bx * 128;
    const int col0 = by * 128;
    const size_t kbase = (size_t)ks * 2048;
    const uint16_t* Abase = (row0 < 256) ? (Am + (size_t)row0 * 65536)
                                         : (Af + (size_t)(row0 - 256) * 65536);

    const int t = threadIdx.x;
    const int w = t >> 6, l = t & 63;
    const int wr = (w >> 1) * 64, wc = (w & 1) * 64;

    const int srow  = t >> 1;
    const int shalf = (t & 1) * 16;
    const uint16_t* ap = Abase + (size_t)srow * 65536 + kbase + shalf;
    const float*    bp = Wf + (size_t)(col0 + srow) * 65536 + kbase + shalf;
    uint16_t* awr = Aa + srow * LSTR + shalf;
    uint16_t* bwr = Bb + srow * LSTR + shalf;

    f32x4 acc[4][4] = {};

    for (int kk = 0; kk < 2048; kk += 32) {
        u16x8 a0 = *(const u16x8*)(ap + kk);
        u16x8 a1 = *(const u16x8*)(ap + kk + 8);
        float4 f0 = *(const float4*)(bp + kk);
        float4 f1 = *(const float4*)(bp + kk + 4);
        float4 f2 = *(const float4*)(bp + kk + 8);
        float4 f3 = *(const float4*)(bp + kk + 12);
        u16x8 b0, b1;
        b0[0] = f2bf(f0.x); b0[1] = f2bf(f0.y); b0[2] = f2bf(f0.z); b0[3] = f2bf(f0.w);
        b0[4] = f2bf(f1.x); b0[5] = f2bf(f1.y); b0[6] = f2bf(f1.z); b0[7] = f2bf(f1.w);
        b1[0] = f2bf(f2.x); b1[1] = f2bf(f2.y); b1[2] = f2bf(f2.z); b1[3] = f2bf(f2.w);
        b1[4] = f2bf(f3.x); b1[5] = f2bf(f3.y); b1[6] = f2bf(f3.z); b1[7] = f2bf(f3.w);

        __syncthreads();
        *(u16x8*)awr       = a0;
        *(u16x8*)(awr + 8) = a1;
        *(u16x8*)bwr       = b0;
        *(u16x8*)(bwr + 8) = b1;
        __syncthreads();

        const int row = l & 15, kg = (l >> 4) * 8;
        bf16x8 afr[4], bfr[4];
#pragma unroll
        for (int i = 0; i < 4; ++i)
            afr[i] = *(const bf16x8*)(Aa + (wr + i * 16 + row) * LSTR + kg);
#pragma unroll
        for (int j = 0; j < 4; ++j)
            bfr[j] = *(const bf16x8*)(Bb + (wc + j * 16 + row) * LSTR + kg);
#pragma unroll
        for (int i = 0; i < 4; ++i)
#pragma unroll
            for (int j = 0; j < 4; ++j)
                acc[i][j] = __builtin_amdgcn_mfma_f32_16x16x32_bf16(
                    afr[i], bfr[j], acc[i][j], 0, 0, 0);
    }

    const int col = l & 15, rg = (l >> 4) * 4;
#pragma unroll
    for (int i = 0; i < 4; ++i)
#pragma unroll
        for (int r = 0; r < 4; ++r) {
            const int grow = row0 + wr + i * 16 + rg + r;
            float* op = part + ((size_t)ks * 512 + grow) * 1024 + col0 + wc + col;
#pragma unroll
            for (int j = 0; j < 4; ++j) op[j * 16] = acc[i][j][r];
        }
}

__global__ __launch_bounds__(256) void fc1_reduce_kernel(
    const float* __restrict__ part, const float* __restrict__ bias,
    float* __restrict__ h)
{
    int idx = blockIdx.x * 256 + threadIdx.x;
    int j = idx & 1023;
    float s = bias[j];
#pragma unroll
    for (int ks = 0; ks < 32; ++ks) s += part[(size_t)ks * 524288 + idx];
    h[idx] = s > 0.f ? s : 0.f;
}

// ---------------------------------------------------------------------------
// fc2 MFMA + attention epilogue.
// ---------------------------------------------------------------------------
__global__ __launch_bounds__(256) void fc2_att_mfma_kernel(
    const float* __restrict__ h, const float* __restrict__ wf,
    const float* __restrict__ bias,
    const float* __restrict__ att1, const float* __restrict__ att2,
    float* __restrict__ alpha_out, float* __restrict__ inm, float* __restrict__ ina)
{
    __shared__ __align__(16) uint16_t Aa[128 * LSTR];
    __shared__ __align__(16) uint16_t Bb[128 * LSTR];

    const int row0 = blockIdx.x * 128;
    const int col0 = blockIdx.y * 128;

    const int t = threadIdx.x;
    const int w = t >> 6, l = t & 63;
    const int wr = (w >> 1) * 64, wc = (w & 1) * 64;

    const int srow  = t >> 1;
    const int shalf = (t & 1) * 16;
    const float* ap = h  + (size_t)(row0 + srow) * 1024 + shalf;
    const float* bp = wf + (size_t)(col0 + srow) * 1024 + shalf;
    uint16_t* awr = Aa + srow * LSTR + shalf;
    uint16_t* bwr = Bb + srow * LSTR + shalf;

    f32x4 acc[4][4] = {};

    for (int kk = 0; kk < 1024; kk += 32) {
        float4 a0 = *(const float4*)(ap + kk);
        float4 a1 = *(const float4*)(ap + kk + 4);
        float4 a2 = *(const float4*)(ap + kk + 8);
        float4 a3 = *(const float4*)(ap + kk + 12);
        float4 f0 = *(const float4*)(bp + kk);
        float4 f1 = *(const float4*)(bp + kk + 4);
        float4 f2 = *(const float4*)(bp + kk + 8);
        float4 f3 = *(const float4*)(bp + kk + 12);
        u16x8 av0, av1, b0, b1;
        av0[0]=f2bf(a0.x); av0[1]=f2bf(a0.y); av0[2]=f2bf(a0.z); av0[3]=f2bf(a0.w);
        av0[4]=f2bf(a1.x); av0[5]=f2bf(a1.y); av0[6]=f2bf(a1.z); av0[7]=f2bf(a1.w);
        av1[0]=f2bf(a2.x); av1[1]=f2bf(a2.y); av1[2]=f2bf(a2.z); av1[3]=f2bf(a2.w);
        av1[4]=f2bf(a3.x); av1[5]=f2bf(a3.y); av1[6]=f2bf(a3.z); av1[7]=f2bf(a3.w);
        b0[0]=f2bf(f0.x); b0[1]=f2bf(f0.y); b0[2]=f2bf(f0.z); b0[3]=f2bf(f0.w);
        b0[4]=f2bf(f1.x); b0[5]=f2bf(f1.y); b0[6]=f2bf(f1.z); b0[7]=f2bf(f1.w);
        b1[0]=f2bf(f2.x); b1[1]=f2bf(f2.y); b1[2]=f2bf(f2.z); b1[3]=f2bf(f2.w);
        b1[4]=f2bf(f3.x); b1[5]=f2bf(f3.y); b1[6]=f2bf(f3.z); b1[7]=f2bf(f3.w);

        __syncthreads();
        *(u16x8*)awr       = av0;
        *(u16x8*)(awr + 8) = av1;
        *(u16x8*)bwr       = b0;
        *(u16x8*)(bwr + 8) = b1;
        __syncthreads();

        const int row = l & 15, kg = (l >> 4) * 8;
        bf16x8 afr[4], bfr[4];
#pragma unroll
        for (int i = 0; i < 4; ++i)
            afr[i] = *(const bf16x8*)(Aa + (wr + i * 16 + row) * LSTR + kg);
#pragma unroll
        for (int j = 0; j < 4; ++j)
            bfr[j] = *(const bf16x8*)(Bb + (wc + j * 16 + row) * LSTR + kg);
#pragma unroll
        for (int i = 0; i < 4; ++i)
#pragma unroll
            for (int j = 0; j < 4; ++j)
                acc[i][j] = __builtin_amdgcn_mfma_f32_16x16x32_bf16(
                    afr[i], bfr[j], acc[i][j], 0, 0, 0);
    }

    const int col = l & 15, rg = (l >> 4) * 4;
#pragma unroll
    for (int i = 0; i < 4; ++i)
#pragma unroll
        for (int r = 0; r < 4; ++r) {
            const int row = row0 + wr + i * 16 + rg + r;
            const int bt  = row & 255;
            const int b = bt >> 4, tt = bt & 15;
            const size_t ibase = ((size_t)tt * 16 + b) * 1024;
#pragma unroll
            for (int j = 0; j < 4; ++j) {
                const int jj = col0 + wc + j * 16 + col;
                float v = acc[i][j][r] + bias[jj];
                if (row < 256) {
                    float al = sigm(att1[b * 512 + jj] * v);
                    alpha_out[(size_t)bt * 512 + jj] = al;
                    inm[ibase + jj]       = al * v;
                    inm[ibase + 512 + jj] = v;
                } else {
                    float be = sigm(att2[b * 512 + jj] * v);
                    ina[ibase + jj]       = be * v;
                    ina[ibase + 512 + jj] = v;
                }
            }
        }
}

// ---------------------------------------------------------------------------
// gx MFMA: gates x-projection, M=256, N=2048, K=1024, grid (2,16,2 paths).
// ---------------------------------------------------------------------------
__global__ __launch_bounds__(256) void gx_mfma_kernel(
    const float* __restrict__ inm, const float* __restrict__ ina,
    const float* __restrict__ wih_m, const float* __restrict__ bih_m, const float* __restrict__ bhh_m,
    const float* __restrict__ wih_a, const float* __restrict__ bih_a, const float* __restrict__ bhh_a,
    float* __restrict__ gxm, float* __restrict__ gxa)
{
    __shared__ __align__(16) uint16_t Aa[128 * LSTR];
    __shared__ __align__(16) uint16_t Bb[128 * LSTR];

    const int row0 = blockIdx.x * 128;
    const int col0 = blockIdx.y * 128;
    const int path = blockIdx.z;

    const float* A  = path ? ina : inm;
    const float* W  = path ? wih_a : wih_m;
    const float* bi = path ? bih_a : bih_m;
    const float* bh = path ? bhh_a : bhh_m;
    float* out = path ? gxa : gxm;

    const int t = threadIdx.x;
    const int w = t >> 6, l = t & 63;
    const int wr = (w >> 1) * 64, wc = (w & 1) * 64;

    const int srow  = t >> 1;
    const int shalf = (t & 1) * 16;
    const float* ap = A + (size_t)(row0 + srow) * 1024 + shalf;
    const float* bp = W + (size_t)(col0 + srow) * 1024 + shalf;
    uint16_t* awr = Aa + srow * LSTR + shalf;
    uint16_t* bwr = Bb + srow * LSTR + shalf;

    f32x4 acc[4][4] = {};

    for (int kk = 0; kk < 1024; kk += 32) {
        float4 a0 = *(const float4*)(ap + kk);
        float4 a1 = *(const float4*)(ap + kk + 4);
        float4 a2 = *(const float4*)(ap + kk + 8);
        float4 a3 = *(const float4*)(ap + kk + 12);
        float4 f0 = *(const float4*)(bp + kk);
        float4 f1 = *(const float4*)(bp + kk + 4);
        float4 f2 = *(const float4*)(bp + kk + 8);
        float4 f3 = *(const float4*)(bp + kk + 12);
        u16x8 av0, av1, b0, b1;
        av0[0]=f2bf(a0.x); av0[1]=f2bf(a0.y); av0[2]=f2bf(a0.z); av0[3]=f2bf(a0.w);
        av0[4]=f2bf(a1.x); av0[5]=f2bf(a1.y); av0[6]=f2bf(a1.z); av0[7]=f2bf(a1.w);
        av1[0]=f2bf(a2.x); av1[1]=f2bf(a2.y); av1[2]=f2bf(a2.z); av1[3]=f2bf(a2.w);
        av1[4]=f2bf(a3.x); av1[5]=f2bf(a3.y); av1[6]=f2bf(a3.z); av1[7]=f2bf(a3.w);
        b0[0]=f2bf(f0.x); b0[1]=f2bf(f0.y); b0[2]=f2bf(f0.z); b0[3]=f2bf(f0.w);
        b0[4]=f2bf(f1.x); b0[5]=f2bf(f1.y); b0[6]=f2bf(f1.z); b0[7]=f2bf(f1.w);
        b1[0]=f2bf(f2.x); b1[1]=f2bf(f2.y); b1[2]=f2bf(f2.z); b1[3]=f2bf(f2.w);
        b1[4]=f2bf(f3.x); b1[5]=f2bf(f3.y); b1[6]=f2bf(f3.z); b1[7]=f2bf(f3.w);

        __syncthreads();
        *(u16x8*)awr       = av0;
        *(u16x8*)(awr + 8) = av1;
        *(u16x8*)bwr       = b0;
        *(u16x8*)(bwr + 8) = b1;
        __syncthreads();

        const int row = l & 15, kg = (l >> 4) * 8;
        bf16x8 afr[4], bfr[4];
#pragma unroll
        for (int i = 0; i < 4; ++i)
            afr[i] = *(const bf16x8*)(Aa + (wr + i * 16 + row) * LSTR + kg);
#pragma unroll
        for (int j = 0; j < 4; ++j)
            bfr[j] = *(const bf16x8*)(Bb + (wc + j * 16 + row) * LSTR + kg);
#pragma unroll
        for (int i = 0; i < 4; ++i)
#pragma unroll
            for (int j = 0; j < 4; ++j)
                acc[i][j] = __builtin_amdgcn_mfma_f32_16x16x32_bf16(
                    afr[i], bfr[j], acc[i][j], 0, 0, 0);
    }

    const int col = l & 15, rg = (l >> 4) * 4;
#pragma unroll
    for (int i = 0; i < 4; ++i)
#pragma unroll
        for (int r = 0; r < 4; ++r) {
            const int grow = row0 + wr + i * 16 + rg + r;
#pragma unroll
            for (int j = 0; j < 4; ++j) {
                const int jj = col0 + wc + j * 16 + col;
                out[(size_t)grow * 2048 + jj] = acc[i][j][r] + bi[jj] + bh[jj];
            }
        }
}

// ---------------------------------------------------------------------------
// Persistent LSTM scan v3: fine-grained producer counters, no global barrier.
//   blocks [0,64):   stage1 (path = bk>>5), serial chain via s1cnt[path][t]
//   blocks [64,96):  stage2-m, trails s1cnt[0][t]
//   blocks [96,160): stage2-a, trails s1cnt[1][t] + own chain s2acnt[t]
// h-history: 17 slots (no ring reuse -> no overwrite hazard).
// ---------------------------------------------------------------------------
__device__ __forceinline__ void wait_cnt(int* cnt, int target) {
    if (threadIdx.x == 0) {
        while (__hip_atomic_load(cnt, __ATOMIC_ACQUIRE, __HIP_MEMORY_SCOPE_AGENT) < target)
            __builtin_amdgcn_s_sleep(1);
        __threadfence();
    }
    __syncthreads();
}

__device__ __forceinline__ void post_cnt(int* cnt) {
    __syncthreads();
    if (threadIdx.x == 0) {
        __threadfence();
        __hip_atomic_fetch_add(cnt, 1, __ATOMIC_ACQ_REL, __HIP_MEMORY_SCOPE_AGENT);
    }
}

__global__ __launch_bounds__(256, 1) void lstm_scan3_kernel(
    const float* __restrict__ gxm, const float* __restrict__ gxa,
    const uint16_t* __restrict__ pw1, const uint16_t* __restrict__ pw2m,
    const uint16_t* __restrict__ pw2a,
    const float* __restrict__ b2m_s, const float* __restrict__ b2a_s,
    uint16_t* __restrict__ s1bf,   // [17][path2][16][512] bf16, slot = t+1
    uint16_t* __restrict__ s2abf,  // [17][16][512] bf16, slot = t+1
    int* __restrict__ s1cnt,       // [2][16]
    int* __restrict__ s2acnt,      // [16]
    float* __restrict__ out)
{
    __shared__ __align__(16) uint16_t wlds[64 * 520];   // 65 KB
    __shared__ __align__(16) uint16_t xs[16 * 520];
    __shared__ __align__(16) uint16_t hs[16 * 520];
    __shared__ float gbuf[2][16][68];

    const int bk  = blockIdx.x;
    const int tid = threadIdx.x;
    const int w   = tid >> 6, l = tid & 63;
    const int lrow = l & 15, kg = (l >> 4) * 8;

    const int role = (bk < 64) ? 0 : (bk < 96) ? 1 : 2;   // S1, S2M, S2A
    const int path = (role == 0) ? (bk >> 5) : (role == 1 ? 0 : 1);
    const int tile = (role == 0) ? (bk & 31) : (role == 1 ? bk - 64 : bk - 96);
    const int j0   = tile * ((role == 2) ? 8 : 16);

    // ---- stage weights into LDS (once) ----
    const uint16_t* wsrc =
        (role == 0) ? pw1 + ((size_t)path * 32 + tile) * 64 * 512 :
        (role == 1) ? pw2m + (size_t)tile * 64 * 512
                    : pw2a + (size_t)tile * 64 * 512;
    for (int idx = tid; idx < 64 * 64; idx += 256) {
        int row = idx >> 6, c = idx & 63;
        *(u16x8*)(wlds + row * 520 + c * 8) = *(const u16x8*)(wsrc + row * 512 + c * 8);
    }

    float cv = 0.f;
    const float* gx1 = path ? gxa : gxm;

    if (role == 0) {
        const int b = tid >> 4, j = tid & 15, jg = j0 + j;
        const size_t obase = path ? 0 : 262144;
        for (int t = 0; t < 16; ++t) {
            // prefetch gx (independent of the wait)
            const float* gxr = gx1 + ((size_t)(t * 16 + b)) * 2048;
            float g0 = gxr[jg], g1 = gxr[512 + jg], g2 = gxr[1024 + jg], g3 = gxr[1536 + jg];
            if (t > 0) wait_cnt(&s1cnt[path * 16 + t - 1], 32);
            const uint16_t* xsrc = s1bf + ((size_t)t * 2 + path) * 8192;   // slot t = h(t-1)
            for (int idx = tid; idx < 1024; idx += 256) {
                int row = idx >> 6, c = idx & 63;
                *(u16x8*)(xs + row * 520 + c * 8) = *(const u16x8*)(xsrc + row * 512 + c * 8);
            }
            __syncthreads();
            f32x4 acc = {};
#pragma unroll
            for (int kk = 0; kk < 512; kk += 32) {
                bf16x8 a = *(const bf16x8*)(xs + lrow * 520 + kk + kg);
                bf16x8 bw = *(const bf16x8*)(wlds + (w * 16 + lrow) * 520 + kk + kg);
                acc = __builtin_amdgcn_mfma_f32_16x16x32_bf16(a, bw, acc, 0, 0, 0);
            }
#pragma unroll
            for (int r = 0; r < 4; ++r)
                gbuf[0][(l >> 4) * 4 + r][w * 16 + lrow] = acc[r];
            __syncthreads();

            float G0 = gbuf[0][b][j * 4 + 0] + g0;
            float G1 = gbuf[0][b][j * 4 + 1] + g1;
            float G2 = gbuf[0][b][j * 4 + 2] + g2;
            float G3 = gbuf[0][b][j * 4 + 3] + g3;
            cv = sigm(G1) * cv + sigm(G0) * tanhf(G2);
            float h = sigm(G3) * tanhf(cv);
            out[obase + ((size_t)b * 16 + t) * 1024 + jg] = h;
            s1bf[((size_t)(t + 1) * 2 + path) * 8192 + b * 512 + jg] = f2bf(h);
            post_cnt(&s1cnt[path * 16 + t]);
        }
    } else if (role == 1) {
        const int b = tid >> 4, j = tid & 15, jg = j0 + j;
        const float B0 = b2m_s[jg], B1 = b2m_s[512 + jg], B2 = b2m_s[1024 + jg], B3 = b2m_s[1536 + jg];
        for (int t = 0; t < 16; ++t) {
            wait_cnt(&s1cnt[t], 32);                      // path 0
            const uint16_t* xsrc = s1bf + ((size_t)(t + 1) * 2 + 0) * 8192; // slot t+1 = s1m(t)
            for (int idx = tid; idx < 1024; idx += 256) {
                int row = idx >> 6, c = idx & 63;
                *(u16x8*)(xs + row * 520 + c * 8) = *(const u16x8*)(xsrc + row * 512 + c * 8);
            }
            __syncthreads();
            f32x4 acc = {};
#pragma unroll
            for (int kk = 0; kk < 512; kk += 32) {
                bf16x8 a = *(const bf16x8*)(xs + lrow * 520 + kk + kg);
                bf16x8 bw = *(const bf16x8*)(wlds + (w * 16 + lrow) * 520 + kk + kg);
                acc = __builtin_amdgcn_mfma_f32_16x16x32_bf16(a, bw, acc, 0, 0, 0);
            }
#pragma unroll
            for (int r = 0; r < 4; ++r)
                gbuf[0][(l >> 4) * 4 + r][w * 16 + lrow] = acc[r];
            __syncthreads();

            float G0 = gbuf[0][b][j * 4 + 0] + B0;
            float G1 = gbuf[0][b][j * 4 + 1] + B1;
            float G2 = gbuf[0][b][j * 4 + 2] + B2;
            float G3 = gbuf[0][b][j * 4 + 3] + B3;
            cv = sigm(G1) * cv + sigm(G0) * tanhf(G2);
            float h = sigm(G3) * tanhf(cv);
            out[262144 + ((size_t)b * 16 + t) * 1024 + 512 + jg] = h;
            __syncthreads();           // xs protected before next stage
        }
    } else {
        const int b = tid >> 3, j = tid & 7, jg = j0 + j;   // epilogue: tid < 128
        float B0 = 0, B1 = 0, B2 = 0, B3 = 0;
        if (tid < 128) {
            B0 = b2a_s[jg]; B1 = b2a_s[512 + jg]; B2 = b2a_s[1024 + jg]; B3 = b2a_s[1536 + jg];
        }
        for (int t = 0; t < 16; ++t) {
            wait_cnt(&s1cnt[16 + t], 32);                 // path 1
            if (t > 0) wait_cnt(&s2acnt[t - 1], 64);
            const uint16_t* xsrc = s1bf + ((size_t)(t + 1) * 2 + 1) * 8192; // s1a(t)
            for (int idx = tid; idx < 1024; idx += 256) {
                int row = idx >> 6, c = idx & 63;
                *(u16x8*)(xs + row * 520 + c * 8) = *(const u16x8*)(xsrc + row * 512 + c * 8);
            }
            const uint16_t* hsrc = s2abf + (size_t)t * 8192;                // s2a(t-1)
            for (int idx = tid; idx < 1024; idx += 256) {
                int row = idx >> 6, c = idx & 63;
                *(u16x8*)(hs + row * 520 + c * 8) = *(const u16x8*)(hsrc + row * 512 + c * 8);
            }
            __syncthreads();
            const uint16_t* src = (w < 2) ? xs : hs;
            const int wt = (w < 2) ? w : w - 2;
            const int wb = (w < 2) ? 0 : 32 * 520;
            f32x4 acc = {};
#pragma unroll
            for (int kk = 0; kk < 512; kk += 32) {
                bf16x8 a = *(const bf16x8*)(src + lrow * 520 + kk + kg);
                bf16x8 bw = *(const bf16x8*)(wlds + wb + (wt * 16 + lrow) * 520 + kk + kg);
                acc = __builtin_amdgcn_mfma_f32_16x16x32_bf16(a, bw, acc, 0, 0, 0);
            }
#pragma unroll
            for (int r = 0; r < 4; ++r)
                gbuf[w >> 1][(l >> 4) * 4 + r][wt * 16 + lrow] = acc[r];
            __syncthreads();

            if (tid < 128) {
                float G0 = gbuf[0][b][j * 4 + 0] + gbuf[1][b][j * 4 + 0] + B0;
                float G1 = gbuf[0][b][j * 4 + 1] + gbuf[1][b][j * 4 + 1] + B1;
                float G2 = gbuf[0][b][j * 4 + 2] + gbuf[1][b][j * 4 + 2] + B2;
                float G3 = gbuf[0][b][j * 4 + 3] + gbuf[1][b][j * 4 + 3] + B3;
                cv = sigm(G1) * cv + sigm(G0) * tanhf(G2);
                float h = sigm(G3) * tanhf(cv);
                out[((size_t)b * 16 + t) * 1024 + 512 + jg] = h;
                s2abf[(size_t)(t + 1) * 8192 + b * 512 + jg] = f2bf(h);
            }
            post_cnt(&s2acnt[t]);
        }
    }
}

// ---------------------------------------------------------------------------
extern "C" void kernel_launch(void* const* d_in, const int* in_sizes, int n_in,
                              void* d_out, int out_size, void* d_ws, size_t ws_size,
                              hipStream_t stream)
{
    (void)in_sizes; (void)n_in; (void)out_size; (void)ws_size;
    const float* f_t     = (const float*)d_in[0];
    const float* f_t_1   = (const float*)d_in[1];
    const float* att1    = (const float*)d_in[2];
    const float* att2    = (const float*)d_in[3];
    const float* conv1_w = (const float*)d_in[4];
    const float* conv1_b = (const float*)d_in[5];
    const float* conv2_w = (const float*)d_in[6];
    const float* conv2_b = (const float*)d_in[7];
    const float* l1a_wih = (const float*)d_in[8];
    const float* l1a_whh = (const float*)d_in[9];
    const float* l1a_bih = (const float*)d_in[10];
    const float* l1a_bhh = (const float*)d_in[11];
    const float* l2a_wih = (const float*)d_in[12];
    const float* l2a_whh = (const float*)d_in[13];
    const float* l2a_bih = (const float*)d_in[14];
    const float* l2a_bhh = (const float*)d_in[15];
    const float* l1m_wih = (const float*)d_in[16];
    const float* l1m_whh = (const float*)d_in[17];
    const float* l1m_bih = (const float*)d_in[18];
    const float* l1m_bhh = (const float*)d_in[19];
    const float* l2m_wih = (const float*)d_in[20];
    const float* l2m_whh = (const float*)d_in[21];
    const float* l2m_bih = (const float*)d_in[22];
    const float* l2m_bhh = (const float*)d_in[23];
    const float* fc1_w   = (const float*)d_in[24];
    const float* fc1_b   = (const float*)d_in[25];
    const float* fc2_w   = (const float*)d_in[26];
    const float* fc2_b   = (const float*)d_in[27];

    char* p = (char*)d_ws;
    uint16_t* in1_nhwc = (uint16_t*)p;             // 64MB [256][1024][128] bf16
    float*    part     = (float*)p;                // 64MB alias (after conv1 consumes nhwc)
    p += (size_t)64 << 20;
    uint16_t* c1out    = (uint16_t*)p; p += (size_t)32 << 20;
    uint16_t* mbuf16   = (uint16_t*)p; p += (size_t)32 << 20;
    uint16_t* ftflat16 = (uint16_t*)p; p += (size_t)32 << 20;
    uint16_t* wpack1   = (uint16_t*)p; p += 256 * 1024;
    uint16_t* wpack2   = (uint16_t*)p; p += 128 * 1024;
    float* hbuf = (float*)p; p += (size_t)2 << 20;
    float* inm  = (float*)p; p += (size_t)1 << 20;
    float* ina  = (float*)p; p += (size_t)1 << 20;
    float* gxm  = (float*)p; p += (size_t)2 << 20;
    float* gxa  = (float*)p; p += (size_t)2 << 20;
    uint16_t* pw1  = (uint16_t*)p; p += (size_t)2097152 * 2;   // 4MB
    uint16_t* pw2m = (uint16_t*)p; p += (size_t)1048576 * 2;   // 2MB
    uint16_t* pw2a = (uint16_t*)p; p += (size_t)2097152 * 2;   // 4MB
    float* b2m_s = (float*)p; p += 2048 * 4;
    float* b2a_s = (float*)p; p += 2048 * 4;
    uint16_t* s1bf  = (uint16_t*)p; p += (size_t)17 * 2 * 8192 * 2;  // 17 slots
    uint16_t* s2abf = (uint16_t*)p; p += (size_t)17 * 8192 * 2;
    int* s1cnt  = (int*)p; p += 32 * 4;
    int* s2acnt = (int*)p; p += 16 * 4;

    float* outp = (float*)d_out;
    float* alpha_out = outp + 524288;

    // reset per-launch state (slot 0 = initial zeros, counters = 0)
    hipMemsetAsync(s1bf, 0, 2 * 8192 * 2, stream);
    hipMemsetAsync(s2abf, 0, 8192 * 2, stream);
    hipMemsetAsync(s1cnt, 0, 48 * 4, stream);

    // prep
    cvt_flat_kernel<<<8192, 256, 0, stream>>>(f_t, ftflat16, 16777216);
    nhwc_kernel<<<dim3(16, 256), 256, 0, stream>>>(f_t, f_t_1, in1_nhwc);
    wpack_kernel<<<288, 256, 0, stream>>>(conv1_w, conv2_w, wpack1, wpack2);
    lstm_pack_kernel<<<2560, 256, 0, stream>>>(
        l1m_whh, l1a_whh, l2m_wih, l2m_whh, l2a_wih, l2a_whh,
        l2m_bih, l2m_bhh, l2a_bih, l2a_bhh,
        pw1, pw2m, pw2a, b2m_s, b2a_s);

    // convs
    conv_mfma_kernel<128, false><<<dim3(8, 256), 256, 0, stream>>>(
        in1_nhwc, wpack1, conv1_b, c1out);
    conv_mfma_kernel<64, true><<<dim3(8, 256), 256, 0, stream>>>(
        c1out, wpack2, conv2_b, mbuf16);

    // fc1 (split-K=32, XCD-swizzled)
    fc1_mfma_kernel<<<1024, 256, 0, stream>>>(mbuf16, ftflat16, fc1_w, part);
    fc1_reduce_kernel<<<2048, 256, 0, stream>>>(part, fc1_b, hbuf);

    // fc2 + attention
    fc2_att_mfma_kernel<<<dim3(4, 4), 256, 0, stream>>>(hbuf, fc2_w, fc2_b, att1, att2,
                                                        alpha_out, inm, ina);

    // gates x-projection
    gx_mfma_kernel<<<dim3(2, 16, 2), 256, 0, stream>>>(inm, ina,
                                                       l1m_wih, l1m_bih, l1m_bhh,
                                                       l1a_wih, l1a_bih, l1a_bhh,
                                                       gxm, gxa);

    // persistent LSTM scan v3 (fine-grained flags)
    lstm_scan3_kernel<<<NBLK, 256, 0, stream>>>(
        gxm, gxa, pw1, pw2m, pw2a, b2m_s, b2a_s,
        s1bf, s2abf, s1cnt, s2acnt, outp);
}

// Round 6
// 683.077 us; speedup vs baseline: 5.3574x; 1.1152x over previous
//
#include <hip/hip_runtime.h>
#include <math.h>
#include <stdint.h>

typedef __attribute__((ext_vector_type(8))) short    bf16x8;
typedef __attribute__((ext_vector_type(4))) float    f32x4;
typedef __attribute__((ext_vector_type(8))) uint16_t u16x8;

#define LSTR 40   // LDS row stride (bf16) for GEMM tiles: 80B rows -> 2-way banks (free)
#define NBLK 160  // persistent LSTM blocks

__device__ __forceinline__ uint16_t f2bf(float f) {
    union { float f; uint32_t u; } v; v.f = f;
    uint32_t r = v.u + 0x7FFFu + ((v.u >> 16) & 1u);
    return (uint16_t)(r >> 16);
}
__device__ __forceinline__ float bf2f(uint16_t b) {
    union { uint32_t u; float f; } v; v.u = (uint32_t)b << 16; return v.f;
}

__device__ __forceinline__ float sigm(float x) { return 1.f / (1.f + expf(-x)); }

// ---------------------------------------------------------------------------
// prep: f_t (fp32 flat NCHW) -> bf16 flat (fc1 A rows 256..511)
// ---------------------------------------------------------------------------
__global__ __launch_bounds__(256) void cvt_flat_kernel(
    const float* __restrict__ src, uint16_t* __restrict__ dst, int n)
{
    int i = (blockIdx.x * 256 + threadIdx.x) * 8;
    if (i >= n) return;
    float4 a = *(const float4*)(src + i);
    float4 b = *(const float4*)(src + i + 4);
    u16x8 o;
    o[0] = f2bf(a.x); o[1] = f2bf(a.y); o[2] = f2bf(a.z); o[3] = f2bf(a.w);
    o[4] = f2bf(b.x); o[5] = f2bf(b.y); o[6] = f2bf(b.z); o[7] = f2bf(b.w);
    *(u16x8*)(dst + i) = o;
}

// ---------------------------------------------------------------------------
// prep: concat(f_t, f_t_1) NCHW fp32 -> NHWC bf16 [bt][y][x][128]
// ---------------------------------------------------------------------------
__global__ __launch_bounds__(256) void nhwc_kernel(
    const float* __restrict__ f_t, const float* __restrict__ f_t_1,
    uint16_t* __restrict__ dst)
{
    __shared__ float lds[32][258];
    const int bt  = blockIdx.y;
    const int c0  = (blockIdx.x >> 2) * 32;
    const int px0 = (blockIdx.x & 3) * 256;
    const int t   = threadIdx.x;

    const int lc  = t & 31;
    const int lpx = (t >> 5) * 32;
    const int c   = c0 + lc;
    const float* src = (c < 64)
        ? (f_t   + ((size_t)bt * 64 + c) * 1024)
        : (f_t_1 + ((size_t)bt * 64 + (c - 64)) * 1024);
#pragma unroll
    for (int j = 0; j < 32; j += 4) {
        float4 v = *(const float4*)(src + px0 + lpx + j);
        lds[lc][lpx + j + 0] = v.x;
        lds[lc][lpx + j + 1] = v.y;
        lds[lc][lpx + j + 2] = v.z;
        lds[lc][lpx + j + 3] = v.w;
    }
    __syncthreads();
    uint16_t* op = dst + ((size_t)bt * 1024 + px0 + t) * 128 + c0;
#pragma unroll
    for (int u0 = 0; u0 < 32; u0 += 8) {
        u16x8 o;
#pragma unroll
        for (int u = 0; u < 8; ++u) o[u] = f2bf(lds[u0 + u][t]);
        *(u16x8*)(op + u0) = o;
    }
}

// ---------------------------------------------------------------------------
// prep: conv weights -> packed bf16 [oc][(ky*3+kx)*IC + c]
// ---------------------------------------------------------------------------
__global__ __launch_bounds__(256) void wpack_kernel(
    const float* __restrict__ w1, const float* __restrict__ w2,
    uint16_t* __restrict__ p1, uint16_t* __restrict__ p2)
{
    int i = blockIdx.x * 256 + threadIdx.x;
    if (i < 64 * 1152) {
        int oc = i / 1152, k = i - oc * 1152;
        int s = k >> 7, c = k & 127;
        int ky = s / 3, kx = s - ky * 3;
        p1[i] = f2bf(w1[((oc * 128 + c) * 3 + ky) * 3 + kx]);
    }
    if (i < 64 * 576) {
        int oc = i / 576, k = i - oc * 576;
        int s = k >> 6, c = k & 63;
        int ky = s / 3, kx = s - ky * 3;
        p2[i] = f2bf(w2[((oc * 64 + c) * 3 + ky) * 3 + kx]);
    }
}

// ---------------------------------------------------------------------------
// prep: LSTM weights -> bf16 tiles for the persistent scan.
// ---------------------------------------------------------------------------
__global__ __launch_bounds__(256) void lstm_pack_kernel(
    const float* __restrict__ whh_m, const float* __restrict__ whh_a,
    const float* __restrict__ m_wih, const float* __restrict__ m_whh,
    const float* __restrict__ a_wih, const float* __restrict__ a_whh,
    const float* __restrict__ m_bih, const float* __restrict__ m_bhh,
    const float* __restrict__ a_bih, const float* __restrict__ a_bhh,
    uint16_t* __restrict__ pw1, uint16_t* __restrict__ pw2m,
    uint16_t* __restrict__ pw2a,
    float* __restrict__ b2m_s, float* __restrict__ b2a_s)
{
    int id = blockIdx.x * 256 + threadIdx.x;
    if (id < 2048) {
        b2m_s[id] = m_bih[id] + m_bhh[id];
        b2a_s[id] = a_bih[id] + a_bhh[id];
    }
    if (id < 262144) {                       // pw1
        int kc = id & 63, g = (id >> 6) & 3, j = (id >> 8) & 511, p = id >> 17;
        const float* src = (p ? whh_a : whh_m) + ((size_t)(g * 512 + j)) * 512 + kc * 8;
        uint16_t* dst = pw1 + ((((size_t)p * 32 + (j >> 4)) * 64 + (j & 15) * 4 + g) * 512) + kc * 8;
        float4 a = *(const float4*)src; float4 b = *(const float4*)(src + 4);
        u16x8 o;
        o[0]=f2bf(a.x); o[1]=f2bf(a.y); o[2]=f2bf(a.z); o[3]=f2bf(a.w);
        o[4]=f2bf(b.x); o[5]=f2bf(b.y); o[6]=f2bf(b.z); o[7]=f2bf(b.w);
        *(u16x8*)dst = o;
    } else if (id < 393216) {                // pw2m (sum)
        int id2 = id - 262144;
        int kc = id2 & 63, g = (id2 >> 6) & 3, j = id2 >> 8;
        size_t off = ((size_t)(g * 512 + j)) * 512 + kc * 8;
        const float* s1 = m_wih + off; const float* s2 = m_whh + off;
        uint16_t* dst = pw2m + (((size_t)(j >> 4)) * 64 + (j & 15) * 4 + g) * 512 + kc * 8;
        u16x8 o;
#pragma unroll
        for (int u = 0; u < 8; ++u) o[u] = f2bf(s1[u] + s2[u]);
        *(u16x8*)dst = o;
    } else if (id < 655360) {                // pw2a
        int id3 = id - 393216;
        int kc = id3 & 63, g = (id3 >> 6) & 3, j = (id3 >> 8) & 511, mat = id3 >> 17;
        const float* src = (mat ? a_whh : a_wih) + ((size_t)(g * 512 + j)) * 512 + kc * 8;
        uint16_t* dst = pw2a + ((((size_t)(j >> 3)) * 2 + mat) * 32 + (j & 7) * 4 + g) * 512 + kc * 8;
        float4 a = *(const float4*)src; float4 b = *(const float4*)(src + 4);
        u16x8 o;
        o[0]=f2bf(a.x); o[1]=f2bf(a.y); o[2]=f2bf(a.z); o[3]=f2bf(a.w);
        o[4]=f2bf(b.x); o[5]=f2bf(b.y); o[6]=f2bf(b.z); o[7]=f2bf(b.w);
        *(u16x8*)dst = o;
    }
}

// ---------------------------------------------------------------------------
// conv3x3 + bias + relu, implicit-GEMM MFMA, halo staged ONCE per block.
// Block: 128 pixels (4 rows), halo = 6 rows x 34 cols x IC (pad IC+8).
// Per tap: A-fragments are LDS offset reads; only B (64x32) restaged.
// ---------------------------------------------------------------------------
template<int IC, bool SWAP>
__global__ __launch_bounds__(256) void conv_mfma2_kernel(
    const uint16_t* __restrict__ in_nhwc,
    const uint16_t* __restrict__ wpack,
    const float* __restrict__ bias,
    uint16_t* __restrict__ out)
{
    constexpr int ICP = IC + 8;           // padded channel stride (272B/144B rows)
    constexpr int KT  = 9 * IC;
    constexpr int CPS = IC / 32;
    constexpr int C8  = IC / 8;
    constexpr int MF  = SWAP ? 4 : 2;
    constexpr int NF  = SWAP ? 2 : 4;

    __shared__ __align__(16) uint16_t Ah[6 * 34 * ICP];
    __shared__ __align__(16) uint16_t Bw[64 * LSTR];

    const int bt  = blockIdx.y;
    const int px0 = blockIdx.x * 128;
    const int y0  = blockIdx.x * 4;       // first pixel row of this block
    const int tid = threadIdx.x;
    const int w   = tid >> 6, l = tid & 63;
    const int lrow = l & 15, kg = (l >> 4) * 8;

    // ---- stage halo once ----
    for (int idx = tid; idx < 204 * C8; idx += 256) {
        int cpos = idx / C8;
        int c8   = (idx - cpos * C8) * 8;
        int hy = cpos / 34, hx = cpos - hy * 34;
        int gy = y0 - 1 + hy, gx = hx - 1;
        u16x8 v = {};
        if (gy >= 0 && gy < 32 && gx >= 0 && gx < 32)
            v = *(const u16x8*)(in_nhwc + (((size_t)bt * 1024) + gy * 32 + gx) * IC + c8);
        *(u16x8*)(Ah + (hy * 34 + hx) * ICP + c8) = v;
    }

    const int oc_s = tid >> 2, kslot = tid & 3;

    f32x4 acc[MF][NF] = {};

    // per-pixel LDS bases (lane-dependent), tap adds a uniform offset
    int abase[MF > NF ? MF : 2];
#pragma unroll
    for (int i = 0; i < (SWAP ? 2 : MF); ++i) {
        int m  = w * 32 + i * 16 + lrow;
        int py = m >> 5, px = m & 31;
        abase[i] = (py * 34 + px) * ICP;
    }

    for (int q = 0; q < 9 * CPS; ++q) {
        const int s  = q / CPS, cc = (q - s * CPS) * 32;
        const int ky = s / 3,  kx = s - ky * 3;
        const int aoff = (ky * 34 + kx) * ICP + cc + kg;

        u16x8 b0 = *(const u16x8*)(wpack + (size_t)oc_s * KT + q * 32 + kslot * 8);
        __syncthreads();                         // prior reads of Bw done (covers halo too @q0)
        *(u16x8*)(Bw + oc_s * LSTR + kslot * 8) = b0;
        __syncthreads();

        if (!SWAP) {
            bf16x8 af[2], bf[4];
#pragma unroll
            for (int i = 0; i < 2; ++i)
                af[i] = *(const bf16x8*)(Ah + abase[i] + aoff);
#pragma unroll
            for (int j = 0; j < 4; ++j)
                bf[j] = *(const bf16x8*)(Bw + (j * 16 + lrow) * LSTR + kg);
#pragma unroll
            for (int i = 0; i < MF; ++i)
#pragma unroll
                for (int j = 0; j < NF; ++j)
                    acc[i][j] = __builtin_amdgcn_mfma_f32_16x16x32_bf16(
                        af[i], bf[j], acc[i][j], 0, 0, 0);
        } else {
            bf16x8 af[4], bf[2];
#pragma unroll
            for (int i = 0; i < 4; ++i)
                af[i] = *(const bf16x8*)(Bw + (i * 16 + lrow) * LSTR + kg);
#pragma unroll
            for (int j = 0; j < 2; ++j)
                bf[j] = *(const bf16x8*)(Ah + abase[j] + aoff);
#pragma unroll
            for (int i = 0; i < MF; ++i)
#pragma unroll
                for (int j = 0; j < NF; ++j)
                    acc[i][j] = __builtin_amdgcn_mfma_f32_16x16x32_bf16(
                        af[i], bf[j], acc[i][j], 0, 0, 0);
        }
    }

    const int col = l & 15, rg = (l >> 4) * 4;
    if (!SWAP) {
#pragma unroll
        for (int i = 0; i < 2; ++i)
#pragma unroll
            for (int j = 0; j < 4; ++j) {
                const int ocb = j * 16 + col;
                const float bv = bias[ocb];
#pragma unroll
                for (int r = 0; r < 4; ++r) {
                    const int px = px0 + w * 32 + i * 16 + rg + r;
                    float v = acc[i][j][r] + bv; v = v > 0.f ? v : 0.f;
                    out[((size_t)bt * 1024 + px) * 64 + ocb] = f2bf(v);
                }
            }
    } else {
#pragma unroll
        for (int i = 0; i < 4; ++i)
#pragma unroll
            for (int j = 0; j < 2; ++j)
#pragma unroll
                for (int r = 0; r < 4; ++r) {
                    const int oc = i * 16 + rg + r;
                    const int px = px0 + w * 32 + j * 16 + col;
                    float v = acc[i][j][r] + bias[oc]; v = v > 0.f ? v : 0.f;
                    out[((size_t)bt * 64 + oc) * 1024 + px] = f2bf(v);
                }
    }
}

// ---------------------------------------------------------------------------
// fc1 MFMA: BM=256 (full A-source per block), BN=128, split-K=32.
// grid 512 (2 bx, 8 by, 32 ks), XCD swizzle; bx-pairs (ids 8 apart -> same
// XCD) share the W slice via L2 -> W fp32 read ~2x instead of 4x.
// ---------------------------------------------------------------------------
__global__ __launch_bounds__(256) void fc1_mfma_kernel(
    const uint16_t* __restrict__ Am, const uint16_t* __restrict__ Af,
    const float* __restrict__ Wf, float* __restrict__ part)
{
    __shared__ __align__(16) uint16_t Aa[256 * LSTR];
    __shared__ __align__(16) uint16_t Bb[128 * LSTR];

    const int id  = blockIdx.x;
    const int vid = (id & 7) * 64 + (id >> 3);   // 512 % 8 == 0 -> bijective
    const int bx  = vid & 1;
    const int by  = (vid >> 1) & 7;
    const int ks  = vid >> 4;

    const int row0 = bx * 256;
    const int col0 = by * 128;
    const size_t kbase = (size_t)ks * 2048;
    const uint16_t* Abase = bx ? Af : Am;

    const int tid = threadIdx.x;
    const int w = tid >> 6, l = tid & 63;
    const int lrow = l & 15, kg = (l >> 4) * 8;

    const uint16_t* ap = Abase + (size_t)tid * 65536 + kbase;
    const float*    bp = Wf + (size_t)(col0 + (tid >> 1)) * 65536 + kbase + (tid & 1) * 16;
    uint16_t* awr = Aa + tid * LSTR;
    uint16_t* bwr = Bb + (tid >> 1) * LSTR + (tid & 1) * 16;

    f32x4 acc[4][8] = {};

    for (int kk = 0; kk < 2048; kk += 32) {
        u16x8 a0 = *(const u16x8*)(ap + kk);
        u16x8 a1 = *(const u16x8*)(ap + kk + 8);
        u16x8 a2 = *(const u16x8*)(ap + kk + 16);
        u16x8 a3 = *(const u16x8*)(ap + kk + 24);
        float4 f0 = *(const float4*)(bp + kk);
        float4 f1 = *(const float4*)(bp + kk + 4);
        float4 f2 = *(const float4*)(bp + kk + 8);
        float4 f3 = *(const float4*)(bp + kk + 12);
        u16x8 b0, b1;
        b0[0] = f2bf(f0.x); b0[1] = f2bf(f0.y); b0[2] = f2bf(f0.z); b0[3] = f2bf(f0.w);
        b0[4] = f2bf(f1.x); b0[5] = f2bf(f1.y); b0[6] = f2bf(f1.z); b0[7] = f2bf(f1.w);
        b1[0] = f2bf(f2.x); b1[1] = f2bf(f2.y); b1[2] = f2bf(f2.z); b1[3] = f2bf(f2.w);
        b1[4] = f2bf(f3.x); b1[5] = f2bf(f3.y); b1[6] = f2bf(f3.z); b1[7] = f2bf(f3.w);

        __syncthreads();
        *(u16x8*)awr        = a0;
        *(u16x8*)(awr + 8)  = a1;
        *(u16x8*)(awr + 16) = a2;
        *(u16x8*)(awr + 24) = a3;
        *(u16x8*)bwr        = b0;
        *(u16x8*)(bwr + 8)  = b1;
        __syncthreads();

        bf16x8 afr[4], bfr[8];
#pragma unroll
        for (int i = 0; i < 4; ++i)
            afr[i] = *(const bf16x8*)(Aa + (w * 64 + i * 16 + lrow) * LSTR + kg);
#pragma unroll
        for (int j = 0; j < 8; ++j)
            bfr[j] = *(const bf16x8*)(Bb + (j * 16 + lrow) * LSTR + kg);
#pragma unroll
        for (int i = 0; i < 4; ++i)
#pragma unroll
            for (int j = 0; j < 8; ++j)
                acc[i][j] = __builtin_amdgcn_mfma_f32_16x16x32_bf16(
                    afr[i], bfr[j], acc[i][j], 0, 0, 0);
    }

    const int col = l & 15, rg = (l >> 4) * 4;
#pragma unroll
    for (int i = 0; i < 4; ++i)
#pragma unroll
        for (int r = 0; r < 4; ++r) {
            const int grow = row0 + w * 64 + i * 16 + rg + r;
            float* op = part + ((size_t)ks * 512 + grow) * 1024 + col0 + col;
#pragma unroll
            for (int j = 0; j < 8; ++j) op[j * 16] = acc[i][j][r];
        }
}

__global__ __launch_bounds__(256) void fc1_reduce_kernel(
    const float* __restrict__ part, const float* __restrict__ bias,
    float* __restrict__ h)
{
    int idx = blockIdx.x * 256 + threadIdx.x;
    int j = idx & 1023;
    float s = bias[j];
#pragma unroll
    for (int ks = 0; ks < 32; ++ks) s += part[(size_t)ks * 524288 + idx];
    h[idx] = s > 0.f ? s : 0.f;
}

// ---------------------------------------------------------------------------
// fc2 MFMA + attention epilogue.
// ---------------------------------------------------------------------------
__global__ __launch_bounds__(256) void fc2_att_mfma_kernel(
    const float* __restrict__ h, const float* __restrict__ wf,
    const float* __restrict__ bias,
    const float* __restrict__ att1, const float* __restrict__ att2,
    float* __restrict__ alpha_out, float* __restrict__ inm, float* __restrict__ ina)
{
    __shared__ __align__(16) uint16_t Aa[128 * LSTR];
    __shared__ __align__(16) uint16_t Bb[128 * LSTR];

    const int row0 = blockIdx.x * 128;
    const int col0 = blockIdx.y * 128;

    const int t = threadIdx.x;
    const int w = t >> 6, l = t & 63;
    const int wr = (w >> 1) * 64, wc = (w & 1) * 64;

    const int srow  = t >> 1;
    const int shalf = (t & 1) * 16;
    const float* ap = h  + (size_t)(row0 + srow) * 1024 + shalf;
    const float* bp = wf + (size_t)(col0 + srow) * 1024 + shalf;
    uint16_t* awr = Aa + srow * LSTR + shalf;
    uint16_t* bwr = Bb + srow * LSTR + shalf;

    f32x4 acc[4][4] = {};

    for (int kk = 0; kk < 1024; kk += 32) {
        float4 a0 = *(const float4*)(ap + kk);
        float4 a1 = *(const float4*)(ap + kk + 4);
        float4 a2 = *(const float4*)(ap + kk + 8);
        float4 a3 = *(const float4*)(ap + kk + 12);
        float4 f0 = *(const float4*)(bp + kk);
        float4 f1 = *(const float4*)(bp + kk + 4);
        float4 f2 = *(const float4*)(bp + kk + 8);
        float4 f3 = *(const float4*)(bp + kk + 12);
        u16x8 av0, av1, b0, b1;
        av0[0]=f2bf(a0.x); av0[1]=f2bf(a0.y); av0[2]=f2bf(a0.z); av0[3]=f2bf(a0.w);
        av0[4]=f2bf(a1.x); av0[5]=f2bf(a1.y); av0[6]=f2bf(a1.z); av0[7]=f2bf(a1.w);
        av1[0]=f2bf(a2.x); av1[1]=f2bf(a2.y); av1[2]=f2bf(a2.z); av1[3]=f2bf(a2.w);
        av1[4]=f2bf(a3.x); av1[5]=f2bf(a3.y); av1[6]=f2bf(a3.z); av1[7]=f2bf(a3.w);
        b0[0]=f2bf(f0.x); b0[1]=f2bf(f0.y); b0[2]=f2bf(f0.z); b0[3]=f2bf(f0.w);
        b0[4]=f2bf(f1.x); b0[5]=f2bf(f1.y); b0[6]=f2bf(f1.z); b0[7]=f2bf(f1.w);
        b1[0]=f2bf(f2.x); b1[1]=f2bf(f2.y); b1[2]=f2bf(f2.z); b1[3]=f2bf(f2.w);
        b1[4]=f2bf(f3.x); b1[5]=f2bf(f3.y); b1[6]=f2bf(f3.z); b1[7]=f2bf(f3.w);

        __syncthreads();
        *(u16x8*)awr       = av0;
        *(u16x8*)(awr + 8) = av1;
        *(u16x8*)bwr       = b0;
        *(u16x8*)(bwr + 8) = b1;
        __syncthreads();

        const int row = l & 15, kg = (l >> 4) * 8;
        bf16x8 afr[4], bfr[4];
#pragma unroll
        for (int i = 0; i < 4; ++i)
            afr[i] = *(const bf16x8*)(Aa + (wr + i * 16 + row) * LSTR + kg);
#pragma unroll
        for (int j = 0; j < 4; ++j)
            bfr[j] = *(const bf16x8*)(Bb + (wc + j * 16 + row) * LSTR + kg);
#pragma unroll
        for (int i = 0; i < 4; ++i)
#pragma unroll
            for (int j = 0; j < 4; ++j)
                acc[i][j] = __builtin_amdgcn_mfma_f32_16x16x32_bf16(
                    afr[i], bfr[j], acc[i][j], 0, 0, 0);
    }

    const int col = l & 15, rg = (l >> 4) * 4;
#pragma unroll
    for (int i = 0; i < 4; ++i)
#pragma unroll
        for (int r = 0; r < 4; ++r) {
            const int row = row0 + wr + i * 16 + rg + r;
            const int bt  = row & 255;
            const int b = bt >> 4, tt = bt & 15;
            const size_t ibase = ((size_t)tt * 16 + b) * 1024;
#pragma unroll
            for (int j = 0; j < 4; ++j) {
                const int jj = col0 + wc + j * 16 + col;
                float v = acc[i][j][r] + bias[jj];
                if (row < 256) {
                    float al = sigm(att1[b * 512 + jj] * v);
                    alpha_out[(size_t)bt * 512 + jj] = al;
                    inm[ibase + jj]       = al * v;
                    inm[ibase + 512 + jj] = v;
                } else {
                    float be = sigm(att2[b * 512 + jj] * v);
                    ina[ibase + jj]       = be * v;
                    ina[ibase + 512 + jj] = v;
                }
            }
        }
}

// ---------------------------------------------------------------------------
// gx MFMA: gates x-projection, M=256, N=2048, K=1024, grid (2,16,2 paths).
// ---------------------------------------------------------------------------
__global__ __launch_bounds__(256) void gx_mfma_kernel(
    const float* __restrict__ inm, const float* __restrict__ ina,
    const float* __restrict__ wih_m, const float* __restrict__ bih_m, const float* __restrict__ bhh_m,
    const float* __restrict__ wih_a, const float* __restrict__ bih_a, const float* __restrict__ bhh_a,
    float* __restrict__ gxm, float* __restrict__ gxa)
{
    __shared__ __align__(16) uint16_t Aa[128 * LSTR];
    __shared__ __align__(16) uint16_t Bb[128 * LSTR];

    const int row0 = blockIdx.x * 128;
    const int col0 = blockIdx.y * 128;
    const int path = blockIdx.z;

    const float* A  = path ? ina : inm;
    const float* W  = path ? wih_a : wih_m;
    const float* bi = path ? bih_a : bih_m;
    const float* bh = path ? bhh_a : bhh_m;
    float* out = path ? gxa : gxm;

    const int t = threadIdx.x;
    const int w = t >> 6, l = t & 63;
    const int wr = (w >> 1) * 64, wc = (w & 1) * 64;

    const int srow  = t >> 1;
    const int shalf = (t & 1) * 16;
    const float* ap = A + (size_t)(row0 + srow) * 1024 + shalf;
    const float* bp = W + (size_t)(col0 + srow) * 1024 + shalf;
    uint16_t* awr = Aa + srow * LSTR + shalf;
    uint16_t* bwr = Bb + srow * LSTR + shalf;

    f32x4 acc[4][4] = {};

    for (int kk = 0; kk < 1024; kk += 32) {
        float4 a0 = *(const float4*)(ap + kk);
        float4 a1 = *(const float4*)(ap + kk + 4);
        float4 a2 = *(const float4*)(ap + kk + 8);
        float4 a3 = *(const float4*)(ap + kk + 12);
        float4 f0 = *(const float4*)(bp + kk);
        float4 f1 = *(const float4*)(bp + kk + 4);
        float4 f2 = *(const float4*)(bp + kk + 8);
        float4 f3 = *(const float4*)(bp + kk + 12);
        u16x8 av0, av1, b0, b1;
        av0[0]=f2bf(a0.x); av0[1]=f2bf(a0.y); av0[2]=f2bf(a0.z); av0[3]=f2bf(a0.w);
        av0[4]=f2bf(a1.x); av0[5]=f2bf(a1.y); av0[6]=f2bf(a1.z); av0[7]=f2bf(a1.w);
        av1[0]=f2bf(a2.x); av1[1]=f2bf(a2.y); av1[2]=f2bf(a2.z); av1[3]=f2bf(a2.w);
        av1[4]=f2bf(a3.x); av1[5]=f2bf(a3.y); av1[6]=f2bf(a3.z); av1[7]=f2bf(a3.w);
        b0[0]=f2bf(f0.x); b0[1]=f2bf(f0.y); b0[2]=f2bf(f0.z); b0[3]=f2bf(f0.w);
        b0[4]=f2bf(f1.x); b0[5]=f2bf(f1.y); b0[6]=f2bf(f1.z); b0[7]=f2bf(f1.w);
        b1[0]=f2bf(f2.x); b1[1]=f2bf(f2.y); b1[2]=f2bf(f2.z); b1[3]=f2bf(f2.w);
        b1[4]=f2bf(f3.x); b1[5]=f2bf(f3.y); b1[6]=f2bf(f3.z); b1[7]=f2bf(f3.w);

        __syncthreads();
        *(u16x8*)awr       = av0;
        *(u16x8*)(awr + 8) = av1;
        *(u16x8*)bwr       = b0;
        *(u16x8*)(bwr + 8) = b1;
        __syncthreads();

        const int row = l & 15, kg = (l >> 4) * 8;
        bf16x8 afr[4], bfr[4];
#pragma unroll
        for (int i = 0; i < 4; ++i)
            afr[i] = *(const bf16x8*)(Aa + (wr + i * 16 + row) * LSTR + kg);
#pragma unroll
        for (int j = 0; j < 4; ++j)
            bfr[j] = *(const bf16x8*)(Bb + (wc + j * 16 + row) * LSTR + kg);
#pragma unroll
        for (int i = 0; i < 4; ++i)
#pragma unroll
            for (int j = 0; j < 4; ++j)
                acc[i][j] = __builtin_amdgcn_mfma_f32_16x16x32_bf16(
                    afr[i], bfr[j], acc[i][j], 0, 0, 0);
    }

    const int col = l & 15, rg = (l >> 4) * 4;
#pragma unroll
    for (int i = 0; i < 4; ++i)
#pragma unroll
        for (int r = 0; r < 4; ++r) {
            const int grow = row0 + wr + i * 16 + rg + r;
#pragma unroll
            for (int j = 0; j < 4; ++j) {
                const int jj = col0 + wc + j * 16 + col;
                out[(size_t)grow * 2048 + jj] = acc[i][j][r] + bi[jj] + bh[jj];
            }
        }
}

// ---------------------------------------------------------------------------
// Persistent LSTM scan v4: all cross-block traffic via relaxed agent-scope
// atomics (IC-coherent, no bulk L2 inv/wb per poll); h packed 2xbf16/u32.
// __syncthreads drains vmcnt(0) per wave -> posts are safe after one release
// fence by thread 0.
// ---------------------------------------------------------------------------
__device__ __forceinline__ void wait_cnt(int* cnt, int target) {
    if (threadIdx.x == 0) {
        while (__hip_atomic_load(cnt, __ATOMIC_RELAXED, __HIP_MEMORY_SCOPE_AGENT) < target)
            __builtin_amdgcn_s_sleep(1);
        __builtin_amdgcn_fence(__ATOMIC_ACQUIRE, "agent");
    }
    __syncthreads();
}

__device__ __forceinline__ void post_cnt(int* cnt) {
    __syncthreads();   // drains vmcnt(0): all waves' sc1 stores are at the coherence point
    if (threadIdx.x == 0) {
        __builtin_amdgcn_fence(__ATOMIC_RELEASE, "agent");
        __hip_atomic_fetch_add(cnt, 1, __ATOMIC_RELAXED, __HIP_MEMORY_SCOPE_AGENT);
    }
}

// stage packed h-state (16x512 bf16 as 4096 u32) into LDS rows of 520
__device__ __forceinline__ void stage_state(uint16_t* dst, const uint32_t* src, int tid) {
    for (int idx = tid; idx < 4096; idx += 256) {
        uint32_t v = __hip_atomic_load(src + idx, __ATOMIC_RELAXED, __HIP_MEMORY_SCOPE_AGENT);
        int flat = idx * 2;
        uint16_t* p = dst + (flat >> 9) * 520 + (flat & 511);
        p[0] = (uint16_t)(v & 0xffffu);
        p[1] = (uint16_t)(v >> 16);
    }
}

__global__ __launch_bounds__(256, 1) void lstm_scan4_kernel(
    const float* __restrict__ gxm, const float* __restrict__ gxa,
    const uint16_t* __restrict__ pw1, const uint16_t* __restrict__ pw2m,
    const uint16_t* __restrict__ pw2a,
    const float* __restrict__ b2m_s, const float* __restrict__ b2a_s,
    uint32_t* __restrict__ s1p,    // [17][path2][4096] packed bf16 pairs
    uint32_t* __restrict__ s2ap,   // [17][4096]
    int* __restrict__ s1cnt,       // [2][16]
    int* __restrict__ s2acnt,      // [16]
    float* __restrict__ out)
{
    __shared__ __align__(16) uint16_t wlds[64 * 520];
    __shared__ __align__(16) uint16_t xs[16 * 520];
    __shared__ __align__(16) uint16_t hs[16 * 520];
    __shared__ float gbuf[2][16][68];

    const int bk  = blockIdx.x;
    const int tid = threadIdx.x;
    const int w   = tid >> 6, l = tid & 63;
    const int lrow = l & 15, kg = (l >> 4) * 8;

    const int role = (bk < 64) ? 0 : (bk < 96) ? 1 : 2;   // S1, S2M, S2A
    const int path = (role == 0) ? (bk >> 5) : (role == 1 ? 0 : 1);
    const int tile = (role == 0) ? (bk & 31) : (role == 1 ? bk - 64 : bk - 96);
    const int j0   = tile * ((role == 2) ? 8 : 16);

    const uint16_t* wsrc =
        (role == 0) ? pw1 + ((size_t)path * 32 + tile) * 64 * 512 :
        (role == 1) ? pw2m + (size_t)tile * 64 * 512
                    : pw2a + (size_t)tile * 64 * 512;
    for (int idx = tid; idx < 64 * 64; idx += 256) {
        int row = idx >> 6, c = idx & 63;
        *(u16x8*)(wlds + row * 520 + c * 8) = *(const u16x8*)(wsrc + row * 512 + c * 8);
    }

    float cv = 0.f;
    const float* gx1 = path ? gxa : gxm;

    if (role == 0) {
        const int b = tid >> 4, j = tid & 15, jg = j0 + j;
        const size_t obase = path ? 0 : 262144;
        for (int t = 0; t < 16; ++t) {
            const float* gxr = gx1 + ((size_t)(t * 16 + b)) * 2048;
            float g0 = gxr[jg], g1 = gxr[512 + jg], g2 = gxr[1024 + jg], g3 = gxr[1536 + jg];
            if (t > 0) wait_cnt(&s1cnt[path * 16 + t - 1], 32);
            stage_state(xs, s1p + ((size_t)t * 2 + path) * 4096, tid);   // slot t = h(t-1)
            __syncthreads();
            f32x4 acc = {};
#pragma unroll
            for (int kk = 0; kk < 512; kk += 32) {
                bf16x8 a  = *(const bf16x8*)(xs + lrow * 520 + kk + kg);
                bf16x8 bw = *(const bf16x8*)(wlds + (w * 16 + lrow) * 520 + kk + kg);
                acc = __builtin_amdgcn_mfma_f32_16x16x32_bf16(a, bw, acc, 0, 0, 0);
            }
#pragma unroll
            for (int r = 0; r < 4; ++r)
                gbuf[0][(l >> 4) * 4 + r][w * 16 + lrow] = acc[r];
            __syncthreads();

            float G0 = gbuf[0][b][j * 4 + 0] + g0;
            float G1 = gbuf[0][b][j * 4 + 1] + g1;
            float G2 = gbuf[0][b][j * 4 + 2] + g2;
            float G3 = gbuf[0][b][j * 4 + 3] + g3;
            cv = sigm(G1) * cv + sigm(G0) * tanhf(G2);
            float h = sigm(G3) * tanhf(cv);
            out[obase + ((size_t)b * 16 + t) * 1024 + jg] = h;
            float hn = __shfl_xor(h, 1);
            if ((j & 1) == 0) {
                uint32_t pk = (uint32_t)f2bf(h) | ((uint32_t)f2bf(hn) << 16);
                __hip_atomic_store(s1p + ((size_t)(t + 1) * 2 + path) * 4096 + b * 256 + (jg >> 1),
                                   pk, __ATOMIC_RELAXED, __HIP_MEMORY_SCOPE_AGENT);
            }
            post_cnt(&s1cnt[path * 16 + t]);
        }
    } else if (role == 1) {
        const int b = tid >> 4, j = tid & 15, jg = j0 + j;
        const float B0 = b2m_s[jg], B1 = b2m_s[512 + jg], B2 = b2m_s[1024 + jg], B3 = b2m_s[1536 + jg];
        for (int t = 0; t < 16; ++t) {
            wait_cnt(&s1cnt[t], 32);                      // path 0
            stage_state(xs, s1p + ((size_t)(t + 1) * 2 + 0) * 4096, tid); // s1m(t)
            __syncthreads();
            f32x4 acc = {};
#pragma unroll
            for (int kk = 0; kk < 512; kk += 32) {
                bf16x8 a  = *(const bf16x8*)(xs + lrow * 520 + kk + kg);
                bf16x8 bw = *(const bf16x8*)(wlds + (w * 16 + lrow) * 520 + kk + kg);
                acc = __builtin_amdgcn_mfma_f32_16x16x32_bf16(a, bw, acc, 0, 0, 0);
            }
#pragma unroll
            for (int r = 0; r < 4; ++r)
                gbuf[0][(l >> 4) * 4 + r][w * 16 + lrow] = acc[r];
            __syncthreads();

            float G0 = gbuf[0][b][j * 4 + 0] + B0;
            float G1 = gbuf[0][b][j * 4 + 1] + B1;
            float G2 = gbuf[0][b][j * 4 + 2] + B2;
            float G3 = gbuf[0][b][j * 4 + 3] + B3;
            cv = sigm(G1) * cv + sigm(G0) * tanhf(G2);
            float h = sigm(G3) * tanhf(cv);
            out[262144 + ((size_t)b * 16 + t) * 1024 + 512 + jg] = h;
            __syncthreads();
        }
    } else {
        const int b = tid >> 3, j = tid & 7, jg = j0 + j;   // epilogue lanes: tid < 128
        float B0 = 0, B1 = 0, B2 = 0, B3 = 0;
        if (tid < 128) {
            B0 = b2a_s[jg]; B1 = b2a_s[512 + jg]; B2 = b2a_s[1024 + jg]; B3 = b2a_s[1536 + jg];
        }
        for (int t = 0; t < 16; ++t) {
            wait_cnt(&s1cnt[16 + t], 32);                 // path 1
            if (t > 0) wait_cnt(&s2acnt[t - 1], 64);
            stage_state(xs, s1p + ((size_t)(t + 1) * 2 + 1) * 4096, tid); // s1a(t)
            stage_state(hs, s2ap + (size_t)t * 4096, tid);                // s2a(t-1)
            __syncthreads();
            const uint16_t* src = (w < 2) ? xs : hs;
            const int wt = (w < 2) ? w : w - 2;
            const int wb = (w < 2) ? 0 : 32 * 520;
            f32x4 acc = {};
#pragma unroll
            for (int kk = 0; kk < 512; kk += 32) {
                bf16x8 a  = *(const bf16x8*)(src + lrow * 520 + kk + kg);
                bf16x8 bw = *(const bf16x8*)(wlds + wb + (wt * 16 + lrow) * 520 + kk + kg);
                acc = __builtin_amdgcn_mfma_f32_16x16x32_bf16(a, bw, acc, 0, 0, 0);
            }
#pragma unroll
            for (int r = 0; r < 4; ++r)
                gbuf[w >> 1][(l >> 4) * 4 + r][wt * 16 + lrow] = acc[r];
            __syncthreads();

            if (tid < 128) {
                float G0 = gbuf[0][b][j * 4 + 0] + gbuf[1][b][j * 4 + 0] + B0;
                float G1 = gbuf[0][b][j * 4 + 1] + gbuf[1][b][j * 4 + 1] + B1;
                float G2 = gbuf[0][b][j * 4 + 2] + gbuf[1][b][j * 4 + 2] + B2;
                float G3 = gbuf[0][b][j * 4 + 3] + gbuf[1][b][j * 4 + 3] + B3;
                cv = sigm(G1) * cv + sigm(G0) * tanhf(G2);
                float h = sigm(G3) * tanhf(cv);
                out[((size_t)b * 16 + t) * 1024 + 512 + jg] = h;
                float hn = __shfl_xor(h, 1);
                if ((j & 1) == 0) {
                    uint32_t pk = (uint32_t)f2bf(h) | ((uint32_t)f2bf(hn) << 16);
                    __hip_atomic_store(s2ap + (size_t)(t + 1) * 4096 + b * 256 + (jg >> 1),
                                       pk, __ATOMIC_RELAXED, __HIP_MEMORY_SCOPE_AGENT);
                }
            }
            post_cnt(&s2acnt[t]);
        }
    }
}

// ---------------------------------------------------------------------------
extern "C" void kernel_launch(void* const* d_in, const int* in_sizes, int n_in,
                              void* d_out, int out_size, void* d_ws, size_t ws_size,
                              hipStream_t stream)
{
    (void)in_sizes; (void)n_in; (void)out_size; (void)ws_size;
    const float* f_t     = (const float*)d_in[0];
    const float* f_t_1   = (const float*)d_in[1];
    const float* att1    = (const float*)d_in[2];
    const float* att2    = (const float*)d_in[3];
    const float* conv1_w = (const float*)d_in[4];
    const float* conv1_b = (const float*)d_in[5];
    const float* conv2_w = (const float*)d_in[6];
    const float* conv2_b = (const float*)d_in[7];
    const float* l1a_wih = (const float*)d_in[8];
    const float* l1a_whh = (const float*)d_in[9];
    const float* l1a_bih = (const float*)d_in[10];
    const float* l1a_bhh = (const float*)d_in[11];
    const float* l2a_wih = (const float*)d_in[12];
    const float* l2a_whh = (const float*)d_in[13];
    const float* l2a_bih = (const float*)d_in[14];
    const float* l2a_bhh = (const float*)d_in[15];
    const float* l1m_wih = (const float*)d_in[16];
    const float* l1m_whh = (const float*)d_in[17];
    const float* l1m_bih = (const float*)d_in[18];
    const float* l1m_bhh = (const float*)d_in[19];
    const float* l2m_wih = (const float*)d_in[20];
    const float* l2m_whh = (const float*)d_in[21];
    const float* l2m_bih = (const float*)d_in[22];
    const float* l2m_bhh = (const float*)d_in[23];
    const float* fc1_w   = (const float*)d_in[24];
    const float* fc1_b   = (const float*)d_in[25];
    const float* fc2_w   = (const float*)d_in[26];
    const float* fc2_b   = (const float*)d_in[27];

    char* p = (char*)d_ws;
    uint16_t* in1_nhwc = (uint16_t*)p;             // 64MB [256][1024][128] bf16
    float*    part     = (float*)p;                // 64MB alias (after conv1 consumes nhwc)
    p += (size_t)64 << 20;
    uint16_t* c1out    = (uint16_t*)p; p += (size_t)32 << 20;
    uint16_t* mbuf16   = (uint16_t*)p; p += (size_t)32 << 20;
    uint16_t* ftflat16 = (uint16_t*)p; p += (size_t)32 << 20;
    uint16_t* wpack1   = (uint16_t*)p; p += 256 * 1024;
    uint16_t* wpack2   = (uint16_t*)p; p += 128 * 1024;
    float* hbuf = (float*)p; p += (size_t)2 << 20;
    float* inm  = (float*)p; p += (size_t)1 << 20;
    float* ina  = (float*)p; p += (size_t)1 << 20;
    float* gxm  = (float*)p; p += (size_t)2 << 20;
    float* gxa  = (float*)p; p += (size_t)2 << 20;
    uint16_t* pw1  = (uint16_t*)p; p += (size_t)2097152 * 2;   // 4MB
    uint16_t* pw2m = (uint16_t*)p; p += (size_t)1048576 * 2;   // 2MB
    uint16_t* pw2a = (uint16_t*)p; p += (size_t)2097152 * 2;   // 4MB
    float* b2m_s = (float*)p; p += 2048 * 4;
    float* b2a_s = (float*)p; p += 2048 * 4;
    uint32_t* s1p  = (uint32_t*)p; p += (size_t)17 * 2 * 4096 * 4;  // packed h, 17 slots
    uint32_t* s2ap = (uint32_t*)p; p += (size_t)17 * 4096 * 4;
    int* s1cnt  = (int*)p; p += 32 * 4;
    int* s2acnt = (int*)p; p += 16 * 4;

    float* outp = (float*)d_out;
    float* alpha_out = outp + 524288;

    // reset per-launch state (slot 0 = initial zeros, counters = 0)
    hipMemsetAsync(s1p, 0, 2 * 4096 * 4, stream);
    hipMemsetAsync(s2ap, 0, 4096 * 4, stream);
    hipMemsetAsync(s1cnt, 0, 48 * 4, stream);

    // prep
    cvt_flat_kernel<<<8192, 256, 0, stream>>>(f_t, ftflat16, 16777216);
    nhwc_kernel<<<dim3(16, 256), 256, 0, stream>>>(f_t, f_t_1, in1_nhwc);
    wpack_kernel<<<288, 256, 0, stream>>>(conv1_w, conv2_w, wpack1, wpack2);
    lstm_pack_kernel<<<2560, 256, 0, stream>>>(
        l1m_whh, l1a_whh, l2m_wih, l2m_whh, l2a_wih, l2a_whh,
        l2m_bih, l2m_bhh, l2a_bih, l2a_bhh,
        pw1, pw2m, pw2a, b2m_s, b2a_s);

    // convs (halo staged once)
    conv_mfma2_kernel<128, false><<<dim3(8, 256), 256, 0, stream>>>(
        in1_nhwc, wpack1, conv1_b, c1out);
    conv_mfma2_kernel<64, true><<<dim3(8, 256), 256, 0, stream>>>(
        c1out, wpack2, conv2_b, mbuf16);

    // fc1 (BM=256, split-K=32, XCD-swizzled)
    fc1_mfma_kernel<<<512, 256, 0, stream>>>(mbuf16, ftflat16, fc1_w, part);
    fc1_reduce_kernel<<<2048, 256, 0, stream>>>(part, fc1_b, hbuf);

    // fc2 + attention
    fc2_att_mfma_kernel<<<dim3(4, 4), 256, 0, stream>>>(hbuf, fc2_w, fc2_b, att1, att2,
                                                        alpha_out, inm, ina);

    // gates x-projection
    gx_mfma_kernel<<<dim3(2, 16, 2), 256, 0, stream>>>(inm, ina,
                                                       l1m_wih, l1m_bih, l1m_bhh,
                                                       l1a_wih, l1a_bih, l1a_bhh,
                                                       gxm, gxa);

    // persistent LSTM scan v4 (IC-coherent point-to-point sync)
    lstm_scan4_kernel<<<NBLK, 256, 0, stream>>>(
        gxm, gxa, pw1, pw2m, pw2a, b2m_s, b2a_s,
        s1p, s2ap, s1cnt, s2acnt, outp);
}

// Round 7
// 627.951 us; speedup vs baseline: 5.8277x; 1.0878x over previous
//
#include <hip/hip_runtime.h>
#include <math.h>
#include <stdint.h>

typedef __attribute__((ext_vector_type(8))) short    bf16x8;
typedef __attribute__((ext_vector_type(4))) float    f32x4;
typedef __attribute__((ext_vector_type(8))) uint16_t u16x8;

#define LSTR 40   // LDS row stride (bf16) for GEMM tiles: 80B rows -> 2-way banks (free)
#define NBLK 160  // persistent LSTM blocks

__device__ __forceinline__ uint16_t f2bf(float f) {
    union { float f; uint32_t u; } v; v.f = f;
    uint32_t r = v.u + 0x7FFFu + ((v.u >> 16) & 1u);
    return (uint16_t)(r >> 16);
}

__device__ __forceinline__ float sigm(float x) { return 1.f / (1.f + expf(-x)); }

// ---------------------------------------------------------------------------
// prep (fused): blocks [0,8192) cvt_flat, [8192,12288) nhwc,
// [12288,12576) wpack, [12576,15136) lstm_pack.
// ---------------------------------------------------------------------------
__global__ __launch_bounds__(256) void prep_all_kernel(
    const float* __restrict__ f_t, const float* __restrict__ f_t_1,
    const float* __restrict__ w1, const float* __restrict__ w2,
    const float* __restrict__ whh_m, const float* __restrict__ whh_a,
    const float* __restrict__ m_wih, const float* __restrict__ m_whh,
    const float* __restrict__ a_wih, const float* __restrict__ a_whh,
    const float* __restrict__ m_bih, const float* __restrict__ m_bhh,
    const float* __restrict__ a_bih, const float* __restrict__ a_bhh,
    uint16_t* __restrict__ ftflat16, uint16_t* __restrict__ in1_nhwc,
    uint16_t* __restrict__ p1, uint16_t* __restrict__ p2,
    uint16_t* __restrict__ pw1, uint16_t* __restrict__ pw2m,
    uint16_t* __restrict__ pw2a,
    float* __restrict__ b2m_s, float* __restrict__ b2a_s)
{
    __shared__ float lds[32][258];
    const int bid = blockIdx.x;
    const int tid = threadIdx.x;

    if (bid < 8192) {
        // ---- cvt_flat: f_t fp32 -> bf16 flat ----
        int i = (bid * 256 + tid) * 8;
        float4 a = *(const float4*)(f_t + i);
        float4 b = *(const float4*)(f_t + i + 4);
        u16x8 o;
        o[0] = f2bf(a.x); o[1] = f2bf(a.y); o[2] = f2bf(a.z); o[3] = f2bf(a.w);
        o[4] = f2bf(b.x); o[5] = f2bf(b.y); o[6] = f2bf(b.z); o[7] = f2bf(b.w);
        *(u16x8*)(ftflat16 + i) = o;
    } else if (bid < 12288) {
        // ---- nhwc: concat(f_t, f_t_1) -> [bt][px][128] bf16 ----
        const int v   = bid - 8192;
        const int bt  = v >> 4;
        const int c0  = ((v & 15) >> 2) * 32;
        const int px0 = (v & 3) * 256;
        const int lc  = tid & 31;
        const int lpx = (tid >> 5) * 32;
        const int c   = c0 + lc;
        const float* src = (c < 64)
            ? (f_t   + ((size_t)bt * 64 + c) * 1024)
            : (f_t_1 + ((size_t)bt * 64 + (c - 64)) * 1024);
#pragma unroll
        for (int j = 0; j < 32; j += 4) {
            float4 vv = *(const float4*)(src + px0 + lpx + j);
            lds[lc][lpx + j + 0] = vv.x;
            lds[lc][lpx + j + 1] = vv.y;
            lds[lc][lpx + j + 2] = vv.z;
            lds[lc][lpx + j + 3] = vv.w;
        }
        __syncthreads();
        uint16_t* op = in1_nhwc + ((size_t)bt * 1024 + px0 + tid) * 128 + c0;
#pragma unroll
        for (int u0 = 0; u0 < 32; u0 += 8) {
            u16x8 o;
#pragma unroll
            for (int u = 0; u < 8; ++u) o[u] = f2bf(lds[u0 + u][tid]);
            *(u16x8*)(op + u0) = o;
        }
    } else if (bid < 12576) {
        // ---- wpack ----
        int i = (bid - 12288) * 256 + tid;
        if (i < 64 * 1152) {
            int oc = i / 1152, k = i - oc * 1152;
            int s = k >> 7, c = k & 127;
            int ky = s / 3, kx = s - ky * 3;
            p1[i] = f2bf(w1[((oc * 128 + c) * 3 + ky) * 3 + kx]);
        }
        if (i < 64 * 576) {
            int oc = i / 576, k = i - oc * 576;
            int s = k >> 6, c = k & 63;
            int ky = s / 3, kx = s - ky * 3;
            p2[i] = f2bf(w2[((oc * 64 + c) * 3 + ky) * 3 + kx]);
        }
    } else {
        // ---- lstm_pack ----
        int id = (bid - 12576) * 256 + tid;
        if (id < 2048) {
            b2m_s[id] = m_bih[id] + m_bhh[id];
            b2a_s[id] = a_bih[id] + a_bhh[id];
        }
        if (id < 262144) {                       // pw1
            int kc = id & 63, g = (id >> 6) & 3, j = (id >> 8) & 511, pp = id >> 17;
            const float* src = (pp ? whh_a : whh_m) + ((size_t)(g * 512 + j)) * 512 + kc * 8;
            uint16_t* dst = pw1 + ((((size_t)pp * 32 + (j >> 4)) * 64 + (j & 15) * 4 + g) * 512) + kc * 8;
            float4 a = *(const float4*)src; float4 b = *(const float4*)(src + 4);
            u16x8 o;
            o[0]=f2bf(a.x); o[1]=f2bf(a.y); o[2]=f2bf(a.z); o[3]=f2bf(a.w);
            o[4]=f2bf(b.x); o[5]=f2bf(b.y); o[6]=f2bf(b.z); o[7]=f2bf(b.w);
            *(u16x8*)dst = o;
        } else if (id < 393216) {                // pw2m (sum)
            int id2 = id - 262144;
            int kc = id2 & 63, g = (id2 >> 6) & 3, j = id2 >> 8;
            size_t off = ((size_t)(g * 512 + j)) * 512 + kc * 8;
            const float* s1 = m_wih + off; const float* s2 = m_whh + off;
            uint16_t* dst = pw2m + (((size_t)(j >> 4)) * 64 + (j & 15) * 4 + g) * 512 + kc * 8;
            u16x8 o;
#pragma unroll
            for (int u = 0; u < 8; ++u) o[u] = f2bf(s1[u] + s2[u]);
            *(u16x8*)dst = o;
        } else if (id < 655360) {                // pw2a
            int id3 = id - 393216;
            int kc = id3 & 63, g = (id3 >> 6) & 3, j = (id3 >> 8) & 511, mat = id3 >> 17;
            const float* src = (mat ? a_whh : a_wih) + ((size_t)(g * 512 + j)) * 512 + kc * 8;
            uint16_t* dst = pw2a + ((((size_t)(j >> 3)) * 2 + mat) * 32 + (j & 7) * 4 + g) * 512 + kc * 8;
            float4 a = *(const float4*)src; float4 b = *(const float4*)(src + 4);
            u16x8 o;
            o[0]=f2bf(a.x); o[1]=f2bf(a.y); o[2]=f2bf(a.z); o[3]=f2bf(a.w);
            o[4]=f2bf(b.x); o[5]=f2bf(b.y); o[6]=f2bf(b.z); o[7]=f2bf(b.w);
            *(u16x8*)dst = o;
        }
    }
}

// ---------------------------------------------------------------------------
// conv3x3 + bias + relu, implicit-GEMM MFMA, halo staged ONCE per block.
// ---------------------------------------------------------------------------
template<int IC, bool SWAP>
__global__ __launch_bounds__(256) void conv_mfma2_kernel(
    const uint16_t* __restrict__ in_nhwc,
    const uint16_t* __restrict__ wpack,
    const float* __restrict__ bias,
    uint16_t* __restrict__ out)
{
    constexpr int ICP = IC + 8;
    constexpr int KT  = 9 * IC;
    constexpr int CPS = IC / 32;
    constexpr int C8  = IC / 8;
    constexpr int MF  = SWAP ? 4 : 2;
    constexpr int NF  = SWAP ? 2 : 4;

    __shared__ __align__(16) uint16_t Ah[6 * 34 * ICP];
    __shared__ __align__(16) uint16_t Bw[64 * LSTR];

    const int bt  = blockIdx.y;
    const int px0 = blockIdx.x * 128;
    const int y0  = blockIdx.x * 4;
    const int tid = threadIdx.x;
    const int w   = tid >> 6, l = tid & 63;
    const int lrow = l & 15, kg = (l >> 4) * 8;

    for (int idx = tid; idx < 204 * C8; idx += 256) {
        int cpos = idx / C8;
        int c8   = (idx - cpos * C8) * 8;
        int hy = cpos / 34, hx = cpos - hy * 34;
        int gy = y0 - 1 + hy, gx = hx - 1;
        u16x8 v = {};
        if (gy >= 0 && gy < 32 && gx >= 0 && gx < 32)
            v = *(const u16x8*)(in_nhwc + (((size_t)bt * 1024) + gy * 32 + gx) * IC + c8);
        *(u16x8*)(Ah + (hy * 34 + hx) * ICP + c8) = v;
    }

    const int oc_s = tid >> 2, kslot = tid & 3;

    f32x4 acc[MF][NF] = {};

    int abase[MF > NF ? MF : 2];
#pragma unroll
    for (int i = 0; i < (SWAP ? 2 : MF); ++i) {
        int m  = w * 32 + i * 16 + lrow;
        int py = m >> 5, px = m & 31;
        abase[i] = (py * 34 + px) * ICP;
    }

    for (int q = 0; q < 9 * CPS; ++q) {
        const int s  = q / CPS, cc = (q - s * CPS) * 32;
        const int ky = s / 3,  kx = s - ky * 3;
        const int aoff = (ky * 34 + kx) * ICP + cc + kg;

        u16x8 b0 = *(const u16x8*)(wpack + (size_t)oc_s * KT + q * 32 + kslot * 8);
        __syncthreads();
        *(u16x8*)(Bw + oc_s * LSTR + kslot * 8) = b0;
        __syncthreads();

        if (!SWAP) {
            bf16x8 af[2], bf[4];
#pragma unroll
            for (int i = 0; i < 2; ++i)
                af[i] = *(const bf16x8*)(Ah + abase[i] + aoff);
#pragma unroll
            for (int j = 0; j < 4; ++j)
                bf[j] = *(const bf16x8*)(Bw + (j * 16 + lrow) * LSTR + kg);
#pragma unroll
            for (int i = 0; i < MF; ++i)
#pragma unroll
                for (int j = 0; j < NF; ++j)
                    acc[i][j] = __builtin_amdgcn_mfma_f32_16x16x32_bf16(
                        af[i], bf[j], acc[i][j], 0, 0, 0);
        } else {
            bf16x8 af[4], bf[2];
#pragma unroll
            for (int i = 0; i < 4; ++i)
                af[i] = *(const bf16x8*)(Bw + (i * 16 + lrow) * LSTR + kg);
#pragma unroll
            for (int j = 0; j < 2; ++j)
                bf[j] = *(const bf16x8*)(Ah + abase[j] + aoff);
#pragma unroll
            for (int i = 0; i < MF; ++i)
#pragma unroll
                for (int j = 0; j < NF; ++j)
                    acc[i][j] = __builtin_amdgcn_mfma_f32_16x16x32_bf16(
                        af[i], bf[j], acc[i][j], 0, 0, 0);
        }
    }

    const int col = l & 15, rg = (l >> 4) * 4;
    if (!SWAP) {
#pragma unroll
        for (int i = 0; i < 2; ++i)
#pragma unroll
            for (int j = 0; j < 4; ++j) {
                const int ocb = j * 16 + col;
                const float bv = bias[ocb];
#pragma unroll
                for (int r = 0; r < 4; ++r) {
                    const int px = px0 + w * 32 + i * 16 + rg + r;
                    float v = acc[i][j][r] + bv; v = v > 0.f ? v : 0.f;
                    out[((size_t)bt * 1024 + px) * 64 + ocb] = f2bf(v);
                }
            }
    } else {
#pragma unroll
        for (int i = 0; i < 4; ++i)
#pragma unroll
            for (int j = 0; j < 2; ++j)
#pragma unroll
                for (int r = 0; r < 4; ++r) {
                    const int oc = i * 16 + rg + r;
                    const int px = px0 + w * 32 + j * 16 + col;
                    float v = acc[i][j][r] + bias[oc]; v = v > 0.f ? v : 0.f;
                    out[((size_t)bt * 64 + oc) * 1024 + px] = f2bf(v);
                }
    }
}

// ---------------------------------------------------------------------------
// fc1 MFMA: BM=256, BN=128, split-K=32, XCD swizzle.
// ---------------------------------------------------------------------------
__global__ __launch_bounds__(256) void fc1_mfma_kernel(
    const uint16_t* __restrict__ Am, const uint16_t* __restrict__ Af,
    const float* __restrict__ Wf, float* __restrict__ part)
{
    __shared__ __align__(16) uint16_t Aa[256 * LSTR];
    __shared__ __align__(16) uint16_t Bb[128 * LSTR];

    const int id  = blockIdx.x;
    const int vid = (id & 7) * 64 + (id >> 3);
    const int bx  = vid & 1;
    const int by  = (vid >> 1) & 7;
    const int ks  = vid >> 4;

    const int row0 = bx * 256;
    const int col0 = by * 128;
    const size_t kbase = (size_t)ks * 2048;
    const uint16_t* Abase = bx ? Af : Am;

    const int tid = threadIdx.x;
    const int w = tid >> 6, l = tid & 63;
    const int lrow = l & 15, kg = (l >> 4) * 8;

    const uint16_t* ap = Abase + (size_t)tid * 65536 + kbase;
    const float*    bp = Wf + (size_t)(col0 + (tid >> 1)) * 65536 + kbase + (tid & 1) * 16;
    uint16_t* awr = Aa + tid * LSTR;
    uint16_t* bwr = Bb + (tid >> 1) * LSTR + (tid & 1) * 16;

    f32x4 acc[4][8] = {};

    for (int kk = 0; kk < 2048; kk += 32) {
        u16x8 a0 = *(const u16x8*)(ap + kk);
        u16x8 a1 = *(const u16x8*)(ap + kk + 8);
        u16x8 a2 = *(const u16x8*)(ap + kk + 16);
        u16x8 a3 = *(const u16x8*)(ap + kk + 24);
        float4 f0 = *(const float4*)(bp + kk);
        float4 f1 = *(const float4*)(bp + kk + 4);
        float4 f2 = *(const float4*)(bp + kk + 8);
        float4 f3 = *(const float4*)(bp + kk + 12);
        u16x8 b0, b1;
        b0[0] = f2bf(f0.x); b0[1] = f2bf(f0.y); b0[2] = f2bf(f0.z); b0[3] = f2bf(f0.w);
        b0[4] = f2bf(f1.x); b0[5] = f2bf(f1.y); b0[6] = f2bf(f1.z); b0[7] = f2bf(f1.w);
        b1[0] = f2bf(f2.x); b1[1] = f2bf(f2.y); b1[2] = f2bf(f2.z); b1[3] = f2bf(f2.w);
        b1[4] = f2bf(f3.x); b1[5] = f2bf(f3.y); b1[6] = f2bf(f3.z); b1[7] = f2bf(f3.w);

        __syncthreads();
        *(u16x8*)awr        = a0;
        *(u16x8*)(awr + 8)  = a1;
        *(u16x8*)(awr + 16) = a2;
        *(u16x8*)(awr + 24) = a3;
        *(u16x8*)bwr        = b0;
        *(u16x8*)(bwr + 8)  = b1;
        __syncthreads();

        bf16x8 afr[4], bfr[8];
#pragma unroll
        for (int i = 0; i < 4; ++i)
            afr[i] = *(const bf16x8*)(Aa + (w * 64 + i * 16 + lrow) * LSTR + kg);
#pragma unroll
        for (int j = 0; j < 8; ++j)
            bfr[j] = *(const bf16x8*)(Bb + (j * 16 + lrow) * LSTR + kg);
#pragma unroll
        for (int i = 0; i < 4; ++i)
#pragma unroll
            for (int j = 0; j < 8; ++j)
                acc[i][j] = __builtin_amdgcn_mfma_f32_16x16x32_bf16(
                    afr[i], bfr[j], acc[i][j], 0, 0, 0);
    }

    const int col = l & 15, rg = (l >> 4) * 4;
#pragma unroll
    for (int i = 0; i < 4; ++i)
#pragma unroll
        for (int r = 0; r < 4; ++r) {
            const int grow = row0 + w * 64 + i * 16 + rg + r;
            float* op = part + ((size_t)ks * 512 + grow) * 1024 + col0 + col;
#pragma unroll
            for (int j = 0; j < 8; ++j) op[j * 16] = acc[i][j][r];
        }
}

__global__ __launch_bounds__(256) void fc1_reduce_kernel(
    const float* __restrict__ part, const float* __restrict__ bias,
    float* __restrict__ h)
{
    int idx = blockIdx.x * 256 + threadIdx.x;
    int j = idx & 1023;
    float s = bias[j];
#pragma unroll
    for (int ks = 0; ks < 32; ++ks) s += part[(size_t)ks * 524288 + idx];
    h[idx] = s > 0.f ? s : 0.f;
}

// ---------------------------------------------------------------------------
// fc2 MFMA + attention epilogue.
// ---------------------------------------------------------------------------
__global__ __launch_bounds__(256) void fc2_att_mfma_kernel(
    const float* __restrict__ h, const float* __restrict__ wf,
    const float* __restrict__ bias,
    const float* __restrict__ att1, const float* __restrict__ att2,
    float* __restrict__ alpha_out, float* __restrict__ inm, float* __restrict__ ina)
{
    __shared__ __align__(16) uint16_t Aa[128 * LSTR];
    __shared__ __align__(16) uint16_t Bb[128 * LSTR];

    const int row0 = blockIdx.x * 128;
    const int col0 = blockIdx.y * 128;

    const int t = threadIdx.x;
    const int w = t >> 6, l = t & 63;
    const int wr = (w >> 1) * 64, wc = (w & 1) * 64;

    const int srow  = t >> 1;
    const int shalf = (t & 1) * 16;
    const float* ap = h  + (size_t)(row0 + srow) * 1024 + shalf;
    const float* bp = wf + (size_t)(col0 + srow) * 1024 + shalf;
    uint16_t* awr = Aa + srow * LSTR + shalf;
    uint16_t* bwr = Bb + srow * LSTR + shalf;

    f32x4 acc[4][4] = {};

    for (int kk = 0; kk < 1024; kk += 32) {
        float4 a0 = *(const float4*)(ap + kk);
        float4 a1 = *(const float4*)(ap + kk + 4);
        float4 a2 = *(const float4*)(ap + kk + 8);
        float4 a3 = *(const float4*)(ap + kk + 12);
        float4 f0 = *(const float4*)(bp + kk);
        float4 f1 = *(const float4*)(bp + kk + 4);
        float4 f2 = *(const float4*)(bp + kk + 8);
        float4 f3 = *(const float4*)(bp + kk + 12);
        u16x8 av0, av1, b0, b1;
        av0[0]=f2bf(a0.x); av0[1]=f2bf(a0.y); av0[2]=f2bf(a0.z); av0[3]=f2bf(a0.w);
        av0[4]=f2bf(a1.x); av0[5]=f2bf(a1.y); av0[6]=f2bf(a1.z); av0[7]=f2bf(a1.w);
        av1[0]=f2bf(a2.x); av1[1]=f2bf(a2.y); av1[2]=f2bf(a2.z); av1[3]=f2bf(a2.w);
        av1[4]=f2bf(a3.x); av1[5]=f2bf(a3.y); av1[6]=f2bf(a3.z); av1[7]=f2bf(a3.w);
        b0[0]=f2bf(f0.x); b0[1]=f2bf(f0.y); b0[2]=f2bf(f0.z); b0[3]=f2bf(f0.w);
        b0[4]=f2bf(f1.x); b0[5]=f2bf(f1.y); b0[6]=f2bf(f1.z); b0[7]=f2bf(f1.w);
        b1[0]=f2bf(f2.x); b1[1]=f2bf(f2.y); b1[2]=f2bf(f2.z); b1[3]=f2bf(f2.w);
        b1[4]=f2bf(f3.x); b1[5]=f2bf(f3.y); b1[6]=f2bf(f3.z); b1[7]=f2bf(f3.w);

        __syncthreads();
        *(u16x8*)awr       = av0;
        *(u16x8*)(awr + 8) = av1;
        *(u16x8*)bwr       = b0;
        *(u16x8*)(bwr + 8) = b1;
        __syncthreads();

        const int row = l & 15, kg = (l >> 4) * 8;
        bf16x8 afr[4], bfr[4];
#pragma unroll
        for (int i = 0; i < 4; ++i)
            afr[i] = *(const bf16x8*)(Aa + (wr + i * 16 + row) * LSTR + kg);
#pragma unroll
        for (int j = 0; j < 4; ++j)
            bfr[j] = *(const bf16x8*)(Bb + (wc + j * 16 + row) * LSTR + kg);
#pragma unroll
        for (int i = 0; i < 4; ++i)
#pragma unroll
            for (int j = 0; j < 4; ++j)
                acc[i][j] = __builtin_amdgcn_mfma_f32_16x16x32_bf16(
                    afr[i], bfr[j], acc[i][j], 0, 0, 0);
    }

    const int col = l & 15, rg = (l >> 4) * 4;
#pragma unroll
    for (int i = 0; i < 4; ++i)
#pragma unroll
        for (int r = 0; r < 4; ++r) {
            const int row = row0 + wr + i * 16 + rg + r;
            const int bt  = row & 255;
            const int b = bt >> 4, tt = bt & 15;
            const size_t ibase = ((size_t)tt * 16 + b) * 1024;
#pragma unroll
            for (int j = 0; j < 4; ++j) {
                const int jj = col0 + wc + j * 16 + col;
                float v = acc[i][j][r] + bias[jj];
                if (row < 256) {
                    float al = sigm(att1[b * 512 + jj] * v);
                    alpha_out[(size_t)bt * 512 + jj] = al;
                    inm[ibase + jj]       = al * v;
                    inm[ibase + 512 + jj] = v;
                } else {
                    float be = sigm(att2[b * 512 + jj] * v);
                    ina[ibase + jj]       = be * v;
                    ina[ibase + 512 + jj] = v;
                }
            }
        }
}

// ---------------------------------------------------------------------------
// gx MFMA: gates x-projection, M=256, N=2048, K=1024, grid (2,16,2 paths).
// ---------------------------------------------------------------------------
__global__ __launch_bounds__(256) void gx_mfma_kernel(
    const float* __restrict__ inm, const float* __restrict__ ina,
    const float* __restrict__ wih_m, const float* __restrict__ bih_m, const float* __restrict__ bhh_m,
    const float* __restrict__ wih_a, const float* __restrict__ bih_a, const float* __restrict__ bhh_a,
    float* __restrict__ gxm, float* __restrict__ gxa)
{
    __shared__ __align__(16) uint16_t Aa[128 * LSTR];
    __shared__ __align__(16) uint16_t Bb[128 * LSTR];

    const int row0 = blockIdx.x * 128;
    const int col0 = blockIdx.y * 128;
    const int path = blockIdx.z;

    const float* A  = path ? ina : inm;
    const float* W  = path ? wih_a : wih_m;
    const float* bi = path ? bih_a : bih_m;
    const float* bh = path ? bhh_a : bhh_m;
    float* out = path ? gxa : gxm;

    const int t = threadIdx.x;
    const int w = t >> 6, l = t & 63;
    const int wr = (w >> 1) * 64, wc = (w & 1) * 64;

    const int srow  = t >> 1;
    const int shalf = (t & 1) * 16;
    const float* ap = A + (size_t)(row0 + srow) * 1024 + shalf;
    const float* bp = W + (size_t)(col0 + srow) * 1024 + shalf;
    uint16_t* awr = Aa + srow * LSTR + shalf;
    uint16_t* bwr = Bb + srow * LSTR + shalf;

    f32x4 acc[4][4] = {};

    for (int kk = 0; kk < 1024; kk += 32) {
        float4 a0 = *(const float4*)(ap + kk);
        float4 a1 = *(const float4*)(ap + kk + 4);
        float4 a2 = *(const float4*)(ap + kk + 8);
        float4 a3 = *(const float4*)(ap + kk + 12);
        float4 f0 = *(const float4*)(bp + kk);
        float4 f1 = *(const float4*)(bp + kk + 4);
        float4 f2 = *(const float4*)(bp + kk + 8);
        float4 f3 = *(const float4*)(bp + kk + 12);
        u16x8 av0, av1, b0, b1;
        av0[0]=f2bf(a0.x); av0[1]=f2bf(a0.y); av0[2]=f2bf(a0.z); av0[3]=f2bf(a0.w);
        av0[4]=f2bf(a1.x); av0[5]=f2bf(a1.y); av0[6]=f2bf(a1.z); av0[7]=f2bf(a1.w);
        av1[0]=f2bf(a2.x); av1[1]=f2bf(a2.y); av1[2]=f2bf(a2.z); av1[3]=f2bf(a2.w);
        av1[4]=f2bf(a3.x); av1[5]=f2bf(a3.y); av1[6]=f2bf(a3.z); av1[7]=f2bf(a3.w);
        b0[0]=f2bf(f0.x); b0[1]=f2bf(f0.y); b0[2]=f2bf(f0.z); b0[3]=f2bf(f0.w);
        b0[4]=f2bf(f1.x); b0[5]=f2bf(f1.y); b0[6]=f2bf(f1.z); b0[7]=f2bf(f1.w);
        b1[0]=f2bf(f2.x); b1[1]=f2bf(f2.y); b1[2]=f2bf(f2.z); b1[3]=f2bf(f2.w);
        b1[4]=f2bf(f3.x); b1[5]=f2bf(f3.y); b1[6]=f2bf(f3.z); b1[7]=f2bf(f3.w);

        __syncthreads();
        *(u16x8*)awr       = av0;
        *(u16x8*)(awr + 8) = av1;
        *(u16x8*)bwr       = b0;
        *(u16x8*)(bwr + 8) = b1;
        __syncthreads();

        const int row = l & 15, kg = (l >> 4) * 8;
        bf16x8 afr[4], bfr[4];
#pragma unroll
        for (int i = 0; i < 4; ++i)
            afr[i] = *(const bf16x8*)(Aa + (wr + i * 16 + row) * LSTR + kg);
#pragma unroll
        for (int j = 0; j < 4; ++j)
            bfr[j] = *(const bf16x8*)(Bb + (wc + j * 16 + row) * LSTR + kg);
#pragma unroll
        for (int i = 0; i < 4; ++i)
#pragma unroll
            for (int j = 0; j < 4; ++j)
                acc[i][j] = __builtin_amdgcn_mfma_f32_16x16x32_bf16(
                    afr[i], bfr[j], acc[i][j], 0, 0, 0);
    }

    const int col = l & 15, rg = (l >> 4) * 4;
#pragma unroll
    for (int i = 0; i < 4; ++i)
#pragma unroll
        for (int r = 0; r < 4; ++r) {
            const int grow = row0 + wr + i * 16 + rg + r;
#pragma unroll
            for (int j = 0; j < 4; ++j) {
                const int jj = col0 + wc + j * 16 + col;
                out[(size_t)grow * 2048 + jj] = acc[i][j][r] + bi[jj] + bh[jj];
            }
        }
}

// ---------------------------------------------------------------------------
// Persistent LSTM scan v5: fence-free point-to-point sync.
// All cross-block data moves via RELAXED agent-scope atomics (sc1 -> IC,
// bypasses non-coherent L2). Producer: data stores drain at __syncthreads
// (vmcnt(0)) BEFORE the flag add -> no release fence needed. Consumer: data
// loads issue after the flag is observed (post-barrier) and read IC -> no
// acquire fence needed. Zero bulk L2 maintenance ops.
// ---------------------------------------------------------------------------
__device__ __forceinline__ void wait_cnt(int* cnt, int target) {
    if (threadIdx.x == 0) {
        while (__hip_atomic_load(cnt, __ATOMIC_RELAXED, __HIP_MEMORY_SCOPE_AGENT) < target)
            __builtin_amdgcn_s_sleep(1);
    }
    __syncthreads();
}

__device__ __forceinline__ void post_cnt(int* cnt) {
    __syncthreads();   // drains vmcnt(0): all waves' sc1 stores reached the IC
    if (threadIdx.x == 0)
        __hip_atomic_fetch_add(cnt, 1, __ATOMIC_RELAXED, __HIP_MEMORY_SCOPE_AGENT);
}

// stage packed h-state (16x512 bf16 as 4096 u32) into LDS rows of 520
__device__ __forceinline__ void stage_state(uint16_t* dst, const uint32_t* src, int tid) {
    for (int idx = tid; idx < 4096; idx += 256) {
        uint32_t v = __hip_atomic_load(src + idx, __ATOMIC_RELAXED, __HIP_MEMORY_SCOPE_AGENT);
        int flat = idx * 2;
        uint16_t* p = dst + (flat >> 9) * 520 + (flat & 511);
        p[0] = (uint16_t)(v & 0xffffu);
        p[1] = (uint16_t)(v >> 16);
    }
}

__global__ __launch_bounds__(256, 1) void lstm_scan5_kernel(
    const float* __restrict__ gxm, const float* __restrict__ gxa,
    const uint16_t* __restrict__ pw1, const uint16_t* __restrict__ pw2m,
    const uint16_t* __restrict__ pw2a,
    const float* __restrict__ b2m_s, const float* __restrict__ b2a_s,
    uint32_t* __restrict__ s1p,    // [17][path2][4096] packed bf16 pairs
    uint32_t* __restrict__ s2ap,   // [17][4096]
    int* __restrict__ s1cnt,       // [2][16]
    int* __restrict__ s2acnt,      // [16]
    float* __restrict__ out)
{
    __shared__ __align__(16) uint16_t wlds[64 * 520];
    __shared__ __align__(16) uint16_t xs[16 * 520];
    __shared__ __align__(16) uint16_t hs[16 * 520];
    __shared__ float gbuf[2][16][68];

    const int bk  = blockIdx.x;
    const int tid = threadIdx.x;
    const int w   = tid >> 6, l = tid & 63;
    const int lrow = l & 15, kg = (l >> 4) * 8;

    const int role = (bk < 64) ? 0 : (bk < 96) ? 1 : 2;   // S1, S2M, S2A
    const int path = (role == 0) ? (bk >> 5) : (role == 1 ? 0 : 1);
    const int tile = (role == 0) ? (bk & 31) : (role == 1 ? bk - 64 : bk - 96);
    const int j0   = tile * ((role == 2) ? 8 : 16);

    const uint16_t* wsrc =
        (role == 0) ? pw1 + ((size_t)path * 32 + tile) * 64 * 512 :
        (role == 1) ? pw2m + (size_t)tile * 64 * 512
                    : pw2a + (size_t)tile * 64 * 512;
    for (int idx = tid; idx < 64 * 64; idx += 256) {
        int row = idx >> 6, c = idx & 63;
        *(u16x8*)(wlds + row * 520 + c * 8) = *(const u16x8*)(wsrc + row * 512 + c * 8);
    }

    float cv = 0.f;
    const float* gx1 = path ? gxa : gxm;

    if (role == 0) {
        const int b = tid >> 4, j = tid & 15, jg = j0 + j;
        const size_t obase = path ? 0 : 262144;
        for (int t = 0; t < 16; ++t) {
            const float* gxr = gx1 + ((size_t)(t * 16 + b)) * 2048;
            float g0 = gxr[jg], g1 = gxr[512 + jg], g2 = gxr[1024 + jg], g3 = gxr[1536 + jg];
            if (t > 0) wait_cnt(&s1cnt[path * 16 + t - 1], 32);
            stage_state(xs, s1p + ((size_t)t * 2 + path) * 4096, tid);   // slot t = h(t-1)
            __syncthreads();
            f32x4 acc = {};
#pragma unroll
            for (int kk = 0; kk < 512; kk += 32) {
                bf16x8 a  = *(const bf16x8*)(xs + lrow * 520 + kk + kg);
                bf16x8 bw = *(const bf16x8*)(wlds + (w * 16 + lrow) * 520 + kk + kg);
                acc = __builtin_amdgcn_mfma_f32_16x16x32_bf16(a, bw, acc, 0, 0, 0);
            }
#pragma unroll
            for (int r = 0; r < 4; ++r)
                gbuf[0][(l >> 4) * 4 + r][w * 16 + lrow] = acc[r];
            __syncthreads();

            float G0 = gbuf[0][b][j * 4 + 0] + g0;
            float G1 = gbuf[0][b][j * 4 + 1] + g1;
            float G2 = gbuf[0][b][j * 4 + 2] + g2;
            float G3 = gbuf[0][b][j * 4 + 3] + g3;
            cv = sigm(G1) * cv + sigm(G0) * tanhf(G2);
            float h = sigm(G3) * tanhf(cv);
            out[obase + ((size_t)b * 16 + t) * 1024 + jg] = h;
            float hn = __shfl_xor(h, 1);
            if ((j & 1) == 0) {
                uint32_t pk = (uint32_t)f2bf(h) | ((uint32_t)f2bf(hn) << 16);
                __hip_atomic_store(s1p + ((size_t)(t + 1) * 2 + path) * 4096 + b * 256 + (jg >> 1),
                                   pk, __ATOMIC_RELAXED, __HIP_MEMORY_SCOPE_AGENT);
            }
            post_cnt(&s1cnt[path * 16 + t]);
        }
    } else if (role == 1) {
        const int b = tid >> 4, j = tid & 15, jg = j0 + j;
        const float B0 = b2m_s[jg], B1 = b2m_s[512 + jg], B2 = b2m_s[1024 + jg], B3 = b2m_s[1536 + jg];
        for (int t = 0; t < 16; ++t) {
            wait_cnt(&s1cnt[t], 32);                      // path 0
            stage_state(xs, s1p + ((size_t)(t + 1) * 2 + 0) * 4096, tid); // s1m(t)
            __syncthreads();
            f32x4 acc = {};
#pragma unroll
            for (int kk = 0; kk < 512; kk += 32) {
                bf16x8 a  = *(const bf16x8*)(xs + lrow * 520 + kk + kg);
                bf16x8 bw = *(const bf16x8*)(wlds + (w * 16 + lrow) * 520 + kk + kg);
                acc = __builtin_amdgcn_mfma_f32_16x16x32_bf16(a, bw, acc, 0, 0, 0);
            }
#pragma unroll
            for (int r = 0; r < 4; ++r)
                gbuf[0][(l >> 4) * 4 + r][w * 16 + lrow] = acc[r];
            __syncthreads();

            float G0 = gbuf[0][b][j * 4 + 0] + B0;
            float G1 = gbuf[0][b][j * 4 + 1] + B1;
            float G2 = gbuf[0][b][j * 4 + 2] + B2;
            float G3 = gbuf[0][b][j * 4 + 3] + B3;
            cv = sigm(G1) * cv + sigm(G0) * tanhf(G2);
            float h = sigm(G3) * tanhf(cv);
            out[262144 + ((size_t)b * 16 + t) * 1024 + 512 + jg] = h;
        }
    } else {
        const int b = tid >> 3, j = tid & 7, jg = j0 + j;   // epilogue lanes: tid < 128
        float B0 = 0, B1 = 0, B2 = 0, B3 = 0;
        if (tid < 128) {
            B0 = b2a_s[jg]; B1 = b2a_s[512 + jg]; B2 = b2a_s[1024 + jg]; B3 = b2a_s[1536 + jg];
        }
        for (int t = 0; t < 16; ++t) {
            wait_cnt(&s1cnt[16 + t], 32);                 // path 1
            if (t > 0) wait_cnt(&s2acnt[t - 1], 64);
            stage_state(xs, s1p + ((size_t)(t + 1) * 2 + 1) * 4096, tid); // s1a(t)
            stage_state(hs, s2ap + (size_t)t * 4096, tid);                // s2a(t-1)
            __syncthreads();
            const uint16_t* src = (w < 2) ? xs : hs;
            const int wt = (w < 2) ? w : w - 2;
            const int wb = (w < 2) ? 0 : 32 * 520;
            f32x4 acc = {};
#pragma unroll
            for (int kk = 0; kk < 512; kk += 32) {
                bf16x8 a  = *(const bf16x8*)(src + lrow * 520 + kk + kg);
                bf16x8 bw = *(const bf16x8*)(wlds + wb + (wt * 16 + lrow) * 520 + kk + kg);
                acc = __builtin_amdgcn_mfma_f32_16x16x32_bf16(a, bw, acc, 0, 0, 0);
            }
#pragma unroll
            for (int r = 0; r < 4; ++r)
                gbuf[w >> 1][(l >> 4) * 4 + r][wt * 16 + lrow] = acc[r];
            __syncthreads();

            if (tid < 128) {
                float G0 = gbuf[0][b][j * 4 + 0] + gbuf[1][b][j * 4 + 0] + B0;
                float G1 = gbuf[0][b][j * 4 + 1] + gbuf[1][b][j * 4 + 1] + B1;
                float G2 = gbuf[0][b][j * 4 + 2] + gbuf[1][b][j * 4 + 2] + B2;
                float G3 = gbuf[0][b][j * 4 + 3] + gbuf[1][b][j * 4 + 3] + B3;
                cv = sigm(G1) * cv + sigm(G0) * tanhf(G2);
                float h = sigm(G3) * tanhf(cv);
                out[((size_t)b * 16 + t) * 1024 + 512 + jg] = h;
                float hn = __shfl_xor(h, 1);
                if ((j & 1) == 0) {
                    uint32_t pk = (uint32_t)f2bf(h) | ((uint32_t)f2bf(hn) << 16);
                    __hip_atomic_store(s2ap + (size_t)(t + 1) * 4096 + b * 256 + (jg >> 1),
                                       pk, __ATOMIC_RELAXED, __HIP_MEMORY_SCOPE_AGENT);
                }
            }
            post_cnt(&s2acnt[t]);
        }
    }
}

// ---------------------------------------------------------------------------
extern "C" void kernel_launch(void* const* d_in, const int* in_sizes, int n_in,
                              void* d_out, int out_size, void* d_ws, size_t ws_size,
                              hipStream_t stream)
{
    (void)in_sizes; (void)n_in; (void)out_size; (void)ws_size;
    const float* f_t     = (const float*)d_in[0];
    const float* f_t_1   = (const float*)d_in[1];
    const float* att1    = (const float*)d_in[2];
    const float* att2    = (const float*)d_in[3];
    const float* conv1_w = (const float*)d_in[4];
    const float* conv1_b = (const float*)d_in[5];
    const float* conv2_w = (const float*)d_in[6];
    const float* conv2_b = (const float*)d_in[7];
    const float* l1a_wih = (const float*)d_in[8];
    const float* l1a_whh = (const float*)d_in[9];
    const float* l1a_bih = (const float*)d_in[10];
    const float* l1a_bhh = (const float*)d_in[11];
    const float* l2a_wih = (const float*)d_in[12];
    const float* l2a_whh = (const float*)d_in[13];
    const float* l2a_bih = (const float*)d_in[14];
    const float* l2a_bhh = (const float*)d_in[15];
    const float* l1m_wih = (const float*)d_in[16];
    const float* l1m_whh = (const float*)d_in[17];
    const float* l1m_bih = (const float*)d_in[18];
    const float* l1m_bhh = (const float*)d_in[19];
    const float* l2m_wih = (const float*)d_in[20];
    const float* l2m_whh = (const float*)d_in[21];
    const float* l2m_bih = (const float*)d_in[22];
    const float* l2m_bhh = (const float*)d_in[23];
    const float* fc1_w   = (const float*)d_in[24];
    const float* fc1_b   = (const float*)d_in[25];
    const float* fc2_w   = (const float*)d_in[26];
    const float* fc2_b   = (const float*)d_in[27];

    char* p = (char*)d_ws;
    uint16_t* in1_nhwc = (uint16_t*)p;             // 64MB [256][1024][128] bf16
    float*    part     = (float*)p;                // 64MB alias (after conv1 consumes nhwc)
    p += (size_t)64 << 20;
    uint16_t* c1out    = (uint16_t*)p; p += (size_t)32 << 20;
    uint16_t* mbuf16   = (uint16_t*)p; p += (size_t)32 << 20;
    uint16_t* ftflat16 = (uint16_t*)p; p += (size_t)32 << 20;
    uint16_t* wpack1   = (uint16_t*)p; p += 256 * 1024;
    uint16_t* wpack2   = (uint16_t*)p; p += 128 * 1024;
    float* hbuf = (float*)p; p += (size_t)2 << 20;
    float* inm  = (float*)p; p += (size_t)1 << 20;
    float* ina  = (float*)p; p += (size_t)1 << 20;
    float* gxm  = (float*)p; p += (size_t)2 << 20;
    float* gxa  = (float*)p; p += (size_t)2 << 20;
    uint16_t* pw1  = (uint16_t*)p; p += (size_t)2097152 * 2;   // 4MB
    uint16_t* pw2m = (uint16_t*)p; p += (size_t)1048576 * 2;   // 2MB
    uint16_t* pw2a = (uint16_t*)p; p += (size_t)2097152 * 2;   // 4MB
    float* b2m_s = (float*)p; p += 2048 * 4;
    float* b2a_s = (float*)p; p += 2048 * 4;
    uint32_t* s1p  = (uint32_t*)p; p += (size_t)17 * 2 * 4096 * 4;  // packed h, 17 slots
    uint32_t* s2ap = (uint32_t*)p; p += (size_t)17 * 4096 * 4;
    int* s1cnt  = (int*)p; p += 32 * 4;
    int* s2acnt = (int*)p; p += 16 * 4;

    float* outp = (float*)d_out;
    float* alpha_out = outp + 524288;

    // reset per-launch state (slot 0 = initial zeros, counters = 0)
    hipMemsetAsync(s1p, 0, 2 * 4096 * 4, stream);
    hipMemsetAsync(s2ap, 0, 4096 * 4, stream);
    hipMemsetAsync(s1cnt, 0, 48 * 4, stream);

    // prep (fused)
    prep_all_kernel<<<15136, 256, 0, stream>>>(
        f_t, f_t_1, conv1_w, conv2_w,
        l1m_whh, l1a_whh, l2m_wih, l2m_whh, l2a_wih, l2a_whh,
        l2m_bih, l2m_bhh, l2a_bih, l2a_bhh,
        ftflat16, in1_nhwc, wpack1, wpack2,
        pw1, pw2m, pw2a, b2m_s, b2a_s);

    // convs (halo staged once)
    conv_mfma2_kernel<128, false><<<dim3(8, 256), 256, 0, stream>>>(
        in1_nhwc, wpack1, conv1_b, c1out);
    conv_mfma2_kernel<64, true><<<dim3(8, 256), 256, 0, stream>>>(
        c1out, wpack2, conv2_b, mbuf16);

    // fc1 (BM=256, split-K=32, XCD-swizzled)
    fc1_mfma_kernel<<<512, 256, 0, stream>>>(mbuf16, ftflat16, fc1_w, part);
    fc1_reduce_kernel<<<2048, 256, 0, stream>>>(part, fc1_b, hbuf);

    // fc2 + attention
    fc2_att_mfma_kernel<<<dim3(4, 4), 256, 0, stream>>>(hbuf, fc2_w, fc2_b, att1, att2,
                                                        alpha_out, inm, ina);

    // gates x-projection
    gx_mfma_kernel<<<dim3(2, 16, 2), 256, 0, stream>>>(inm, ina,
                                                       l1m_wih, l1m_bih, l1m_bhh,
                                                       l1a_wih, l1a_bih, l1a_bhh,
                                                       gxm, gxa);

    // persistent LSTM scan v5 (fence-free)
    lstm_scan5_kernel<<<NBLK, 256, 0, stream>>>(
        gxm, gxa, pw1, pw2m, pw2a, b2m_s, b2a_s,
        s1p, s2ap, s1cnt, s2acnt, outp);
}